// Round 9
// baseline (989.524 us; speedup 1.0000x reference)
//
#include <hip/hip_runtime.h>

// Encoder: L=6 layers of (rel-pos attention + channel-LN + K=3 conv FFN + LN)
// B=4, C=256, T=1024, H=4, KC=64, FC=1024, W=10, fp32 I/O.
// ROUND 9: (a) mfma_gemm2 launch_bounds(256,3) -> VGPR<=170, 3 blocks/CU:
// qkv's 768-block grid becomes fully co-resident (kills the 1.5-round
// half-idle tail + cross-block latency overlap); (b) mask_in folded into
// tpack (reads x+mask, writes xb AND packed hi/lo; same double-mask as
// before, bit-identical). 46 -> 45 dispatches. R8 calibration: dispatch
// overhead ~2.3us each; ~860us is in-kernel.
// attn: S 2-pass, PV 1-pass, fixed-max, j-split x4. Convs: 64m x 128t,
// 4 t-strip waves, tap-shared B staging, halo-predicated, reg-prefetch.
// wo-GEMM stages B directly from attn partials (fused combine).

#define Lz 6
#define Cz 256
#define FCz 1024
#define Hz 4
#define Wz 10
#define Bz 4
#define Tz 1024
#define KCz 64
#define NR 21
#define TS 1032
#define PADF 4
#define PROWS 1026
#define MFIX 8.0f

typedef unsigned short u16;
typedef unsigned int u32;
typedef __attribute__((ext_vector_type(8))) short bf8v;
typedef __attribute__((ext_vector_type(4))) float f4v;

#define MFMA(a, b, c) __builtin_amdgcn_mfma_f32_16x16x32_bf16(a, b, c, 0, 0, 0)

__device__ inline void bf_split(float v, u16& hi, u16& lo) {
  unsigned u = __float_as_uint(v);
  unsigned hr = (u + 0x7FFFu + ((u >> 16) & 1u)) >> 16;
  float rem = v - __uint_as_float(hr << 16);
  unsigned u2 = __float_as_uint(rem);
  unsigned lr = (u2 + 0x7FFFu + ((u2 >> 16) & 1u)) >> 16;
  hi = (u16)hr;
  lo = (u16)lr;
}

__device__ inline u16 bf_rne(float v) {
  u32 u = __float_as_uint(v);
  return (u16)((u + 0x7FFFu + ((u >> 16) & 1u)) >> 16);
}

// ---------------------------------------------------------------------------
__global__ __launch_bounds__(256) void mask_out(const float* __restrict__ xp,
                                                const float* __restrict__ m,
                                                float* __restrict__ out) {
  int id = blockIdx.x * 256 + threadIdx.x;
  if (id < Bz * Cz * Tz) {
    int t = id & (Tz - 1), row = id >> 10, b = id >> 18;
    out[id] = xp[(size_t)row * TS + PADF + t] * m[b * Tz + t];
  }
}

// ---------------------------------------------------------------------------
// Fused mask_in + transpose-pack: reads x [b][c][Tz] + mask, writes
// xb = x*m (TS-padded layout) AND packed hi/lo [b][1026][Cd] of (x*m)*m.
// (Same double-mask as the old mask_in->tpack chain; bit-identical.)
// ---------------------------------------------------------------------------
__global__ __launch_bounds__(256) void tpack(const float* __restrict__ xsrc,
                                             const float* __restrict__ mask,
                                             float* __restrict__ xb,
                                             u16* __restrict__ dhi,
                                             u16* __restrict__ dlo, int Cd) {
  __shared__ float L[64 * 68];
  const int tid = threadIdx.x;
  const int t0 = blockIdx.x * 64, c0 = blockIdx.y * 64, b = blockIdx.z;
#pragma unroll
  for (int i = 0; i < 16; i++) {
    int id = tid + 256 * i;
    int cc = id >> 6, tt = id & 63;
    float mv = mask[(size_t)b * Tz + t0 + tt];
    float v = xsrc[((size_t)(b * Cz + c0 + cc)) * Tz + t0 + tt] * mv;
    xb[((size_t)(b * Cz + c0 + cc)) * TS + PADF + t0 + tt] = v;
    L[cc * 68 + tt] = v;
  }
  __syncthreads();
  const int tt = tid >> 2, p = tid & 3;
  float mv = mask[(size_t)b * Tz + t0 + tt];
  u16 hs[16], ls[16];
#pragma unroll
  for (int j = 0; j < 16; j++) {
    float v = L[(p * 16 + j) * 68 + tt] * mv;
    bf_split(v, hs[j], ls[j]);
  }
  size_t da = ((size_t)b * PROWS + t0 + tt + 1) * Cd + c0 + p * 16;
  *(uint4*)&dhi[da] = *(uint4*)&hs[0];
  *(uint4*)&dhi[da + 8] = *(uint4*)&hs[8];
  *(uint4*)&dlo[da] = *(uint4*)&ls[0];
  *(uint4*)&dlo[da + 8] = *(uint4*)&ls[8];
}

// ---------------------------------------------------------------------------
// Pack ALL layers' weights in one launch. grid = 6 * 7184 blocks.
// ---------------------------------------------------------------------------
__global__ __launch_bounds__(256) void pack_all(
    const float* __restrict__ wq, const float* __restrict__ wk,
    const float* __restrict__ wv, const float* __restrict__ wo_,
    const float* __restrict__ bq, const float* __restrict__ bk,
    const float* __restrict__ bv, const float* __restrict__ bo,
    const float* __restrict__ erk, const float* __restrict__ erv,
    const float* __restrict__ fw1, const float* __restrict__ fw2,
    u16* __restrict__ qwAll, float* __restrict__ pbAll,
    u16* __restrict__ ekAll, u16* __restrict__ evAll,
    u16* __restrict__ w1All, u16* __restrict__ w2All) {
  const int blk = blockIdx.x, tid = threadIdx.x;
  const int layer = blk / 7184;
  const int bl = blk % 7184;
  if (bl < 1024) {
    int id = bl * 256 + tid;
    int o = id >> 8, c = id & 255;
    int sel = o >> 8;
    const size_t wof = (size_t)layer * Cz * Cz;
    const float* w = sel == 0 ? wq + wof
                              : (sel == 1 ? wk + wof
                                          : (sel == 2 ? wv + wof : wo_ + wof));
    qwAll[(size_t)layer * 262144 + id] = bf_rne(w[((o & 255) << 8) + c]);
    if (id < 1024) {
      int s2 = id >> 8;
      const float* bs = s2 == 0 ? bq : (s2 == 1 ? bk : (s2 == 2 ? bv : bo));
      pbAll[layer * 1024 + id] = bs[layer * Cz + (id & 255)];
    }
  } else if (bl < 1040) {
    int id = (bl - 1024) * 256 + tid;
    if (id < 2048) {
      int rr = id >> 6, d = id & 63;
      ekAll[layer * 2048 + id] =
          bf_rne((rr < NR) ? erk[(size_t)layer * NR * KCz + rr * KCz + d]
                           : 0.f);
    } else {
      int id2 = id - 2048;
      int d = id2 >> 5, rr = id2 & 31;
      evAll[layer * 2048 + id2] =
          bf_rne((rr < NR) ? erv[(size_t)layer * NR * KCz + rr * KCz + d]
                           : 0.f);
    }
  } else if (bl < 4112) {
    int id = (bl - 1040) * 256 + tid;
    int c = id % Cz;
    int rest = id / Cz;
    int o = rest % FCz, tap = rest / FCz;
    w1All[(size_t)layer * 786432 + id] =
        bf_rne(fw1[(size_t)layer * FCz * Cz * 3 + ((size_t)o * Cz + c) * 3 +
                   tap]);
  } else {
    int id = (bl - 4112) * 256 + tid;
    int c = id % FCz;
    int rest = id / FCz;
    int o = rest % Cz, tap = rest / Cz;
    w2All[(size_t)layer * 786432 + id] =
        bf_rne(fw2[(size_t)layer * Cz * FCz * 3 + ((size_t)o * FCz + c) * 3 +
                   tap]);
  }
}

// ---------------------------------------------------------------------------
// 2-pass MFMA GEMM (A = single bf16 weights). Tile 64x64.
// launch_bounds(256,3): 3 blocks/CU so qkv's 768-block grid is co-resident.
// EPI 0: B = hi/lo packed acts; qkv -> Q hi/lo (x0.125), K hi, V hi.
// EPI 3: wo, K-split-2; B staged from attn partials O0..O3 (fused combine).
// ---------------------------------------------------------------------------
template <int EPI>
__global__ __launch_bounds__(256, 3) void mfma_gemm2(
    const u16* __restrict__ Ah, const u16* __restrict__ Bh,
    const u16* __restrict__ Bl, const float* __restrict__ bias,
    float* __restrict__ out, float* __restrict__ out2,
    u16* __restrict__ pqh, u16* __restrict__ pql, u16* __restrict__ pkh,
    u16* __restrict__ pvh, const float* __restrict__ Ox0,
    const float* __restrict__ Ox1, const float* __restrict__ Ox2,
    const float* __restrict__ Ox3, const float* __restrict__ sl0,
    const float* __restrict__ sl1, const float* __restrict__ sl2,
    const float* __restrict__ sl3, int M, int Kc, int m_base) {
  __shared__ __align__(16) char smraw[17408];
  u16* Ash = (u16*)smraw;
  u16* Bsh = Ash + 2560;
  u16* Bsl = Bsh + 2560;
  const int tid = threadIdx.x;
  const int lane = tid & 63, wid = tid >> 6;
  const int wm = wid & 1, wn = wid >> 1;
  const int r = lane & 15, qd = lane >> 4;
  const int t0 = blockIdx.x * 64;
  const int b = blockIdx.z;
  const int srow = tid >> 2, sseg = (tid & 3) * 8;

  int m0, kc0, kcN;
  float* outp = out;
  if constexpr (EPI == 3) {
    m0 = m_base + (blockIdx.y >> 1) * 64;
    kc0 = (blockIdx.y & 1) * (Kc / 2);
    kcN = Kc / 2;
    outp = (blockIdx.y & 1) ? out2 : out;
  } else {
    m0 = blockIdx.y * 64 + m_base;
    kc0 = 0;
    kcN = Kc;
  }

  f4v acc[2][2];
#pragma unroll
  for (int i = 0; i < 2; i++)
#pragma unroll
    for (int j = 0; j < 2; j++) acc[i][j] = (f4v)(0.f);

  const size_t arow = (size_t)(m0 + srow) * Kc + kc0;
  const size_t brow = ((size_t)b * PROWS + t0 + 1 + srow) * Kc + kc0;
  for (int kc = 0; kc < kcN; kc += 32) {
    *(uint4*)&Ash[srow * 40 + sseg] = *(const uint4*)&Ah[arow + kc + sseg];
    if constexpr (EPI == 3) {
      // fused attn_combine: B row t = t0+srow, cols cc..cc+7 (one head blk)
      const int cc = kc0 + kc + sseg;
      const int hh = cc >> 6, dd = cc & 63;
      const size_t lbi = (size_t)(b * Hz + hh) * Tz + t0 + srow;
      const size_t ob = lbi * KCz + dd;
      float4 qa = *(const float4*)&Ox0[ob];
      float4 qb = *(const float4*)&Ox0[ob + 4];
      float4 ra = *(const float4*)&Ox1[ob];
      float4 rb = *(const float4*)&Ox1[ob + 4];
      float4 sa = *(const float4*)&Ox2[ob];
      float4 sb = *(const float4*)&Ox2[ob + 4];
      float4 ta = *(const float4*)&Ox3[ob];
      float4 tb = *(const float4*)&Ox3[ob + 4];
      const float li = 1.f / (sl0[lbi] + sl1[lbi] + sl2[lbi] + sl3[lbi]);
      float v[8] = {(qa.x + ra.x + sa.x + ta.x) * li,
                    (qa.y + ra.y + sa.y + ta.y) * li,
                    (qa.z + ra.z + sa.z + ta.z) * li,
                    (qa.w + ra.w + sa.w + ta.w) * li,
                    (qb.x + rb.x + sb.x + tb.x) * li,
                    (qb.y + rb.y + sb.y + tb.y) * li,
                    (qb.z + rb.z + sb.z + tb.z) * li,
                    (qb.w + rb.w + sb.w + tb.w) * li};
      u16 hhs[8], lls[8];
#pragma unroll
      for (int e = 0; e < 8; e++) bf_split(v[e], hhs[e], lls[e]);
      *(uint4*)&Bsh[srow * 40 + sseg] = *(uint4*)&hhs[0];
      *(uint4*)&Bsl[srow * 40 + sseg] = *(uint4*)&lls[0];
    } else {
      *(uint4*)&Bsh[srow * 40 + sseg] = *(const uint4*)&Bh[brow + kc + sseg];
      *(uint4*)&Bsl[srow * 40 + sseg] = *(const uint4*)&Bl[brow + kc + sseg];
    }
    __syncthreads();
    bf8v ah[2], bh2[2], bl2[2];
#pragma unroll
    for (int f = 0; f < 2; f++) {
      int ar = (wm * 32 + f * 16 + r) * 40 + qd * 8;
      int br = (wn * 32 + f * 16 + r) * 40 + qd * 8;
      ah[f] = *(bf8v*)&Ash[ar];
      bh2[f] = *(bf8v*)&Bsh[br];
      bl2[f] = *(bf8v*)&Bsl[br];
    }
#pragma unroll
    for (int mf = 0; mf < 2; mf++)
#pragma unroll
      for (int nf = 0; nf < 2; nf++) {
        acc[mf][nf] = MFMA(ah[mf], bh2[nf], acc[mf][nf]);
        acc[mf][nf] = MFMA(ah[mf], bl2[nf], acc[mf][nf]);
      }
    __syncthreads();
  }

  float* Ds = (float*)smraw;
  if constexpr (EPI == 0) {
    const int sel = m0 >> 8;
    const int h = (m0 >> 6) & 3;
    const int bhI = b * Hz + h;
    if (sel < 2) {
#pragma unroll
      for (int mf = 0; mf < 2; mf++)
#pragma unroll
        for (int nf = 0; nf < 2; nf++) {
          int nl = wn * 32 + nf * 16 + r;
          int ml = wm * 32 + mf * 16 + qd * 4;
          *(f4v*)&Ds[nl * 68 + ml] = acc[mf][nf];
        }
      __syncthreads();
      const int row = tid >> 2, p = tid & 3;
      size_t da = ((size_t)bhI * Tz + t0 + row) * KCz + p * 16;
      if (sel == 0) {
        u16 hs[16], ls[16];
#pragma unroll
        for (int jj = 0; jj < 4; jj++) {
          float4 dv = *(float4*)&Ds[row * 68 + p * 16 + jj * 4];
          float4 bb = *(const float4*)&bias[m0 + p * 16 + jj * 4];
          float vv[4] = {(dv.x + bb.x) * 0.125f, (dv.y + bb.y) * 0.125f,
                         (dv.z + bb.z) * 0.125f, (dv.w + bb.w) * 0.125f};
#pragma unroll
          for (int e = 0; e < 4; e++)
            bf_split(vv[e], hs[jj * 4 + e], ls[jj * 4 + e]);
        }
        *(uint4*)&pqh[da] = *(uint4*)&hs[0];
        *(uint4*)&pqh[da + 8] = *(uint4*)&hs[8];
        *(uint4*)&pql[da] = *(uint4*)&ls[0];
        *(uint4*)&pql[da + 8] = *(uint4*)&ls[8];
      } else {
        u16 hs[16];
#pragma unroll
        for (int jj = 0; jj < 4; jj++) {
          float4 dv = *(float4*)&Ds[row * 68 + p * 16 + jj * 4];
          float4 bb = *(const float4*)&bias[m0 + p * 16 + jj * 4];
          hs[jj * 4 + 0] = bf_rne(dv.x + bb.x);
          hs[jj * 4 + 1] = bf_rne(dv.y + bb.y);
          hs[jj * 4 + 2] = bf_rne(dv.z + bb.z);
          hs[jj * 4 + 3] = bf_rne(dv.w + bb.w);
        }
        *(uint4*)&pkh[da] = *(uint4*)&hs[0];
        *(uint4*)&pkh[da + 8] = *(uint4*)&hs[8];
      }
    } else {
#pragma unroll
      for (int mf = 0; mf < 2; mf++)
#pragma unroll
        for (int nf = 0; nf < 2; nf++) {
          int ml = wm * 32 + mf * 16 + qd * 4;
          int nl = wn * 32 + nf * 16 + r;
#pragma unroll
          for (int e = 0; e < 4; e++) Ds[(ml + e) * 68 + nl] = acc[mf][nf][e];
        }
      __syncthreads();
      const int row = tid >> 2, p = tid & 3;
      const float bb = bias[m0 + row];
      u16 hs[16];
#pragma unroll
      for (int jj = 0; jj < 16; jj++)
        hs[jj] = bf_rne(Ds[row * 68 + p * 16 + jj] + bb);
      size_t da = ((size_t)bhI * KCz + row) * Tz + t0 + p * 16;
      *(uint4*)&pvh[da] = *(uint4*)&hs[0];
      *(uint4*)&pvh[da + 8] = *(uint4*)&hs[8];
    }
  } else {
#pragma unroll
    for (int mf = 0; mf < 2; mf++)
#pragma unroll
      for (int nf = 0; nf < 2; nf++) {
        int ml = wm * 32 + mf * 16 + qd * 4;
        int nl = wn * 32 + nf * 16 + r;
#pragma unroll
        for (int e = 0; e < 4; e++) Ds[(ml + e) * 68 + nl] = acc[mf][nf][e];
      }
    __syncthreads();
    const int row = tid >> 2, p = tid & 3;
    size_t oa = ((size_t)b * Cz + (m0 - m_base) + row) * Tz + t0 + p * 16;
#pragma unroll
    for (int jj = 0; jj < 4; jj++)
      *(float4*)&outp[oa + jj * 4] = *(float4*)&Ds[row * 68 + p * 16 + jj * 4];
  }
}

// ---------------------------------------------------------------------------
// Conv (K=3) as 2-pass MFMA GEMM, 64m x 128t tile, 4 waves = 4 t-strips.
// Tap-shared B staging (130 rows once per 32-k chunk); reg-prefetch.
// Halo rows (prow 0 / 1025) zero-predicated in staging.
// EPI 1: conv1: +bias, relu, mask, pack hi/lo rows+1. grid (8, M/64, B).
// EPI 3: conv2: K-split x4 -> fp32 partials o0..o3. grid (8, 4*4, B).
// ---------------------------------------------------------------------------
template <int EPI>
__global__ __launch_bounds__(256, 2) void conv_mfma(
    const u16* __restrict__ Ah, const u16* __restrict__ Bh,
    const u16* __restrict__ Bl, const float* __restrict__ bias,
    const float* __restrict__ mask, u16* __restrict__ ph,
    u16* __restrict__ pl, float* __restrict__ o0, float* __restrict__ o1,
    float* __restrict__ o2, float* __restrict__ o3, int M, int Kc) {
  __shared__ __align__(16) char smraw[36480];
  u16* Ash = (u16*)smraw;        // [3][64][40]
  u16* Bsh = Ash + 3 * 64 * 40;  // [132][40] (130 rows used)
  u16* Bsl = Bsh + 132 * 40;
  const int tid = threadIdx.x;
  const int lane = tid & 63, wn = tid >> 6;  // 4 waves: t-strip wn*32
  const int r = lane & 15, qd = lane >> 4;
  const int t0 = blockIdx.x * 128;
  const int b = blockIdx.z;

  int m0, kc0, kcN;
  float* outp = nullptr;
  if constexpr (EPI == 3) {
    int mt = blockIdx.y >> 2, sp = blockIdx.y & 3;
    m0 = mt * 64;
    kc0 = sp * (Kc / 4);
    kcN = Kc / 4;
    outp = sp == 0 ? o0 : (sp == 1 ? o1 : (sp == 2 ? o2 : o3));
  } else {
    m0 = blockIdx.y * 64;
    kc0 = 0;
    kcN = Kc;
  }

  const int srow = tid >> 2, sseg = (tid & 3) * 8;  // rows 0..63
  const bool btail = tid < 8;                       // B rows 128..129
  const int brow2 = 128 + (tid >> 2);
  const bool h0 = (t0 + srow == 0);
  const bool hT = btail && (t0 + brow2 == PROWS - 1);
  const uint4 z4 = {0u, 0u, 0u, 0u};

  f4v acc[4][2];
#pragma unroll
  for (int i = 0; i < 4; i++)
#pragma unroll
    for (int j = 0; j < 2; j++) acc[i][j] = (f4v)(0.f);

  const size_t abase = (size_t)(m0 + srow) * Kc + kc0 + sseg;
  const size_t bbase = ((size_t)b * PROWS + t0 + srow) * Kc + kc0 + sseg;
  const size_t bbase64 = bbase + (size_t)64 * Kc;
  const size_t bbaseT = ((size_t)b * PROWS + t0 + brow2) * Kc + kc0 + sseg;

  uint4 ar[3], bh0, bh1, bl0, bl1, bht, blt;
  auto LOADR = [&](int kc) {
#pragma unroll
    for (int tp = 0; tp < 3; tp++)
      ar[tp] = *(const uint4*)&Ah[(size_t)tp * M * Kc + abase + kc];
    bh0 = *(const uint4*)&Bh[bbase + kc];
    bl0 = *(const uint4*)&Bl[bbase + kc];
    if (h0) {
      bh0 = z4;
      bl0 = z4;
    }
    bh1 = *(const uint4*)&Bh[bbase64 + kc];
    bl1 = *(const uint4*)&Bl[bbase64 + kc];
    if (btail) {
      bht = *(const uint4*)&Bh[bbaseT + kc];
      blt = *(const uint4*)&Bl[bbaseT + kc];
      if (hT) {
        bht = z4;
        blt = z4;
      }
    }
  };

  LOADR(0);
  for (int kc = 0; kc < kcN; kc += 32) {
#pragma unroll
    for (int tp = 0; tp < 3; tp++)
      *(uint4*)&Ash[(tp * 64 + srow) * 40 + sseg] = ar[tp];
    *(uint4*)&Bsh[srow * 40 + sseg] = bh0;
    *(uint4*)&Bsh[(srow + 64) * 40 + sseg] = bh1;
    *(uint4*)&Bsl[srow * 40 + sseg] = bl0;
    *(uint4*)&Bsl[(srow + 64) * 40 + sseg] = bl1;
    if (btail) {
      *(uint4*)&Bsh[brow2 * 40 + sseg] = bht;
      *(uint4*)&Bsl[brow2 * 40 + sseg] = blt;
    }
    __syncthreads();
    if (kc + 32 < kcN) LOADR(kc + 32);  // prefetch next chunk
#pragma unroll
    for (int tap = 0; tap < 3; tap++) {
      bf8v ah[4], bh2[2], bl2[2];
#pragma unroll
      for (int mf = 0; mf < 4; mf++)
        ah[mf] = *(bf8v*)&Ash[(tap * 64 + mf * 16 + r) * 40 + qd * 8];
#pragma unroll
      for (int nf = 0; nf < 2; nf++) {
        int br = (wn * 32 + nf * 16 + r + tap) * 40 + qd * 8;
        bh2[nf] = *(bf8v*)&Bsh[br];
        bl2[nf] = *(bf8v*)&Bsl[br];
      }
#pragma unroll
      for (int mf = 0; mf < 4; mf++)
#pragma unroll
        for (int nf = 0; nf < 2; nf++) {
          acc[mf][nf] = MFMA(ah[mf], bh2[nf], acc[mf][nf]);
          acc[mf][nf] = MFMA(ah[mf], bl2[nf], acc[mf][nf]);
        }
    }
    __syncthreads();
  }

  // acc[mf][nf][e]: m = mf*16 + qd*4 + e, t = wn*32 + nf*16 + r
  if constexpr (EPI == 1) {
    float* Ds = (float*)smraw;  // [t 128][m 68]
#pragma unroll
    for (int mf = 0; mf < 4; mf++)
#pragma unroll
      for (int nf = 0; nf < 2; nf++) {
        int tl = wn * 32 + nf * 16 + r;
        int ml = mf * 16 + qd * 4;
        *(f4v*)&Ds[tl * 68 + ml] = acc[mf][nf];
      }
    __syncthreads();
    const int row = tid >> 1, half = (tid & 1) * 32;
    const int t = t0 + row;
    const float mv = mask[(size_t)b * Tz + t];
    u16 hs[32], ls[32];
#pragma unroll
    for (int j = 0; j < 32; j += 4) {
      float4 dv = *(float4*)&Ds[row * 68 + half + j];
      float4 bb = *(const float4*)&bias[m0 + half + j];
      float vv[4] = {dv.x + bb.x, dv.y + bb.y, dv.z + bb.z, dv.w + bb.w};
#pragma unroll
      for (int e = 0; e < 4; e++) {
        float v = fmaxf(vv[e], 0.f) * mv;
        bf_split(v, hs[j + e], ls[j + e]);
      }
    }
    size_t da = ((size_t)b * PROWS + t + 1) * M + m0 + half;
#pragma unroll
    for (int j = 0; j < 32; j += 8) {
      *(uint4*)&ph[da + j] = *(uint4*)&hs[j];
      *(uint4*)&pl[da + j] = *(uint4*)&ls[j];
    }
  } else {
    float* Ds = (float*)smraw;  // [m 64][t 132]
#pragma unroll
    for (int mf = 0; mf < 4; mf++)
#pragma unroll
      for (int nf = 0; nf < 2; nf++) {
        int ml = mf * 16 + qd * 4;
        int nl = wn * 32 + nf * 16 + r;
#pragma unroll
        for (int e = 0; e < 4; e++) Ds[(ml + e) * 132 + nl] = acc[mf][nf][e];
      }
    __syncthreads();
    const int row = tid >> 2, seg = (tid & 3) * 32;
    size_t oa = ((size_t)b * Cz + m0 + row) * Tz + t0 + seg;
#pragma unroll
    for (int j = 0; j < 8; j++)
      *(float4*)&outp[oa + j * 4] = *(float4*)&Ds[row * 132 + seg + j * 4];
  }
}

// ---------------------------------------------------------------------------
// Barrier-free MFMA flash attention, fixed-max softmax, 32 q-rows/wave,
// j-split x4. Q hi/lo; K,V,er single bf16: S 2-pass, PV 1-pass.
// grid 1024 = 16 bh x 4 splits x 16 i-blocks(64); 128 thr (2 waves).
// ---------------------------------------------------------------------------
__global__ __launch_bounds__(128, 2) void attn_mfma(
    const u16* __restrict__ Qh_, const u16* __restrict__ Ql_,
    const u16* __restrict__ Kh_, const u16* __restrict__ Vh_,
    const float* __restrict__ mask, const u16* __restrict__ erkH,
    const u16* __restrict__ ervH, float* __restrict__ O0,
    float* __restrict__ O1, float* __restrict__ O2, float* __restrict__ O3,
    float* __restrict__ lp0, float* __restrict__ lp1,
    float* __restrict__ lp2, float* __restrict__ lp3) {
  __shared__ __align__(16) char smraw[2][14336];
  const int tid = threadIdx.x;
  const int lane = tid & 63, wid = tid >> 6;
  const int r = lane & 15, qd = lane >> 4;
  const int idx = blockIdx.x;
  const int bh = idx & 15;
  const int split = (idx >> 4) & 3;
  const int i0w = (idx >> 6) * 64 + wid * 32;
  const int b = bh >> 2, h = bh & 3;
  const float* mb = mask + (size_t)b * Tz;
  const size_t qkbase = (size_t)bh * Tz * KCz;
  const size_t vbase = (size_t)bh * KCz * Tz;
  float* Op = split == 0 ? O0 : (split == 1 ? O1 : (split == 2 ? O2 : O3));
  float* lp = split == 0 ? lp0 : (split == 1 ? lp1 : (split == 2 ? lp2 : lp3));
  const int j0beg = split * 256;

  float* rqs = (float*)(smraw[wid]);      // [32][22]
  float* bands = rqs + 704;               // [32][22]
  u16* Pp = (u16*)(smraw[wid] + 5632);    // [32][72]; reused as Os f32

  bf8v qh[2][2], ql[2][2];
#pragma unroll
  for (int rs = 0; rs < 2; rs++) {
    const size_t qrow = qkbase + (size_t)(i0w + rs * 16 + r) * KCz;
#pragma unroll
    for (int ks = 0; ks < 2; ks++) {
      qh[rs][ks] = *(const bf8v*)&Qh_[qrow + ks * 32 + qd * 8];
      ql[rs][ks] = *(const bf8v*)&Ql_[qrow + ks * 32 + qd * 8];
    }
  }
  for (int t = lane; t < 704; t += 64) bands[t] = -1e30f;

#pragma unroll
  for (int rs = 0; rs < 2; rs++) {
    f4v rc[2] = {(f4v)(0.f), (f4v)(0.f)};
#pragma unroll
    for (int nf = 0; nf < 2; nf++)
#pragma unroll
      for (int ks = 0; ks < 2; ks++) {
        bf8v eh = *(const bf8v*)&erkH[(16 * nf + r) * 64 + ks * 32 + qd * 8];
        rc[nf] = MFMA(qh[rs][ks], eh, rc[nf]);
        rc[nf] = MFMA(ql[rs][ks], eh, rc[nf]);
      }
#pragma unroll
    for (int nf = 0; nf < 2; nf++) {
      int rr = 16 * nf + r;
      if (rr < NR) {
#pragma unroll
        for (int e = 0; e < 4; e++)
          rqs[(rs * 16 + 4 * qd + e) * 22 + rr] = rc[nf][e];
      }
    }
  }

  float qm[2][4];
#pragma unroll
  for (int rs = 0; rs < 2; rs++)
#pragma unroll
    for (int e = 0; e < 4; e++) qm[rs][e] = mb[i0w + rs * 16 + 4 * qd + e];

  float lacc[2][4] = {};
  f4v oacc[2][4];
#pragma unroll
  for (int rs = 0; rs < 2; rs++)
#pragma unroll
    for (int nf = 0; nf < 4; nf++) oacc[rs][nf] = (f4v)(0.f);

#pragma unroll 2
  for (int jt = 0; jt < 4; jt++) {
    const int j0 = j0beg + jt * 64;
    bf8v kh[4][2], vh[4][2];
#pragma unroll
    for (int nf = 0; nf < 4; nf++) {
      const size_t kr = qkbase + (size_t)(j0 + 16 * nf + r) * KCz;
      const size_t vr = vbase + (size_t)(16 * nf + r) * Tz + j0;
#pragma unroll
      for (int ks = 0; ks < 2; ks++) {
        kh[nf][ks] = *(const bf8v*)&Kh_[kr + ks * 32 + qd * 8];
        vh[nf][ks] = *(const bf8v*)&Vh_[vr + ks * 32 + qd * 8];
      }
    }
    float km4[4];
#pragma unroll
    for (int nf = 0; nf < 4; nf++) km4[nf] = mb[j0 + 16 * nf + r];

#pragma unroll
    for (int rs = 0; rs < 2; rs++) {
      f4v sa[4];
#pragma unroll
      for (int nf = 0; nf < 4; nf++) sa[nf] = (f4v)(0.f);
#pragma unroll
      for (int nf = 0; nf < 4; nf++)
#pragma unroll
        for (int ks = 0; ks < 2; ks++) {
          sa[nf] = MFMA(qh[rs][ks], kh[nf][ks], sa[nf]);
          sa[nf] = MFMA(ql[rs][ks], kh[nf][ks], sa[nf]);
        }
      const int ibase = i0w + rs * 16;
      const bool diag = (j0 + 63 >= ibase - Wz) && (j0 <= ibase + 15 + Wz);
#pragma unroll
      for (int nf = 0; nf < 4; nf++)
#pragma unroll
        for (int e = 0; e < 4; e++) {
          const int iloc = rs * 16 + 4 * qd + e;
          float s = sa[nf][e];
          if (diag) {
            int dl = (j0 + 16 * nf + r) - (i0w + iloc);
            bool inb = (unsigned)(dl + Wz) <= 2u * Wz;
            if (inb) s += rqs[iloc * 22 + dl + Wz];
            if (qm[rs][e] * km4[nf] == 0.f) s = -1e4f;
            if (inb) bands[iloc * 22 + dl + Wz] = s;
          } else {
            if (qm[rs][e] * km4[nf] == 0.f) s = -1e4f;
          }
          float p = __expf(s - MFIX);
          lacc[rs][e] += p;
          Pp[iloc * 72 + 16 * nf + r] = bf_rne(p);
        }
    }
#pragma unroll
    for (int rs = 0; rs < 2; rs++)
#pragma unroll
      for (int ks = 0; ks < 2; ks++) {
        bf8v Ph = *(bf8v*)&Pp[(rs * 16 + r) * 72 + ks * 32 + qd * 8];
#pragma unroll
        for (int nf = 0; nf < 4; nf++)
          oacc[rs][nf] = MFMA(Ph, vh[nf][ks], oacc[rs][nf]);
      }
  }

  for (int t = lane; t < 32 * 32; t += 64) {
    int i = t >> 5, rr = t & 31;
    float p = (rr < NR) ? __expf(bands[i * 22 + rr] - MFIX) : 0.f;
    Pp[i * 72 + rr] = bf_rne(p);
  }
#pragma unroll
  for (int rs = 0; rs < 2; rs++) {
    bf8v Ph = *(bf8v*)&Pp[(rs * 16 + r) * 72 + qd * 8];
#pragma unroll
    for (int nf = 0; nf < 4; nf++) {
      bf8v eh = *(const bf8v*)&ervH[(16 * nf + r) * 32 + qd * 8];
      oacc[rs][nf] = MFMA(Ph, eh, oacc[rs][nf]);
    }
  }

#pragma unroll
  for (int off = 1; off < 16; off <<= 1)
#pragma unroll
    for (int rs = 0; rs < 2; rs++)
#pragma unroll
      for (int e = 0; e < 4; e++)
        lacc[rs][e] += __shfl_xor(lacc[rs][e], off, 16);
  if (r == 0) {
#pragma unroll
    for (int rs = 0; rs < 2; rs++)
#pragma unroll
      for (int e = 0; e < 4; e++)
        lp[(size_t)bh * Tz + i0w + rs * 16 + 4 * qd + e] = lacc[rs][e];
  }

  float* Os = (float*)Pp;  // [32][68]
#pragma unroll
  for (int rs = 0; rs < 2; rs++)
#pragma unroll
    for (int nf = 0; nf < 4; nf++)
#pragma unroll
      for (int e = 0; e < 4; e++)
        Os[(rs * 16 + 4 * qd + e) * 68 + 16 * nf + r] = oacc[rs][nf][e];
#pragma unroll
  for (int rs = 0; rs < 2; rs++) {
    const float* src = &Os[(rs * 16 + r) * 68 + qd * 16];
    size_t oa = ((size_t)bh * Tz + i0w + rs * 16 + r) * KCz + qd * 16;
#pragma unroll
    for (int jj = 0; jj < 4; jj++)
      *(float4*)&Op[oa + jj * 4] = *(const float4*)&src[jj * 4];
  }
}

// ---------------------------------------------------------------------------
// Fused residual + channel LayerNorm + transpose-pack.
// 8 t-cols/block, grid (128, B) = 512 blocks (2/CU); wave-0 shfl reduce.
// VAR 1 (NP partials, mask): x = LN(x + (sum(parts) + cbias)*mask)  [conv2]
// VAR 2 (NP partials, no mask): x = LN(x + sum(parts) + cbias)      [wo]
// ---------------------------------------------------------------------------
template <int VAR, int NP>
__global__ __launch_bounds__(256) void fused_ln(
    float* __restrict__ x, const float* __restrict__ y,
    const float* __restrict__ p1, const float* __restrict__ p2,
    const float* __restrict__ p3, const float* __restrict__ cbias,
    const float* __restrict__ g, const float* __restrict__ bb,
    const float* __restrict__ mask, u16* __restrict__ dhi,
    u16* __restrict__ dlo) {
  __shared__ float L[256 * 9];
  __shared__ float red[32][8], red2[32][8];
  __shared__ float ms[8], rs[8];
  const int tid = threadIdx.x;
  const int t0 = blockIdx.x * 8, b = blockIdx.y;
  const int tl = tid & 7, grp = tid >> 3;  // 32 c-groups of 8 t-cols
  const size_t bx = (size_t)b * Cz * TS + PADF + t0 + tl;
  const size_t by = (size_t)b * Cz * Tz + t0 + tl;
  const float mv = mask[(size_t)b * Tz + t0 + tl];
  float s = 0.f, sq = 0.f;
#pragma unroll
  for (int i = 0; i < 8; i++) {
    int c = grp + i * 32;
    float add = y[by + (size_t)c * Tz] + p1[by + (size_t)c * Tz] + cbias[c];
    if constexpr (NP == 4)
      add += p2[by + (size_t)c * Tz] + p3[by + (size_t)c * Tz];
    if constexpr (VAR == 1) add *= mv;
    float v = x[bx + (size_t)c * TS] + add;
    L[c * 9 + tl] = v;
    s += v;
    sq += v * v;
  }
  red[grp][tl] = s;
  red2[grp][tl] = sq;
  __syncthreads();
  if (tid < 64) {
    const int j = tid >> 3, tt = tid & 7;
    float su = red[j][tt] + red[j + 8][tt] + red[j + 16][tt] + red[j + 24][tt];
    float sqq =
        red2[j][tt] + red2[j + 8][tt] + red2[j + 16][tt] + red2[j + 24][tt];
    su += __shfl_xor(su, 8);
    su += __shfl_xor(su, 16);
    su += __shfl_xor(su, 32);
    sqq += __shfl_xor(sqq, 8);
    sqq += __shfl_xor(sqq, 16);
    sqq += __shfl_xor(sqq, 32);
    if (j == 0) {
      float m = su * (1.f / Cz);
      ms[tt] = m;
      rs[tt] = rsqrtf(sqq * (1.f / Cz) - m * m + 1e-5f);
    }
  }
  __syncthreads();
  const float m = ms[tl], r = rs[tl];
#pragma unroll
  for (int i = 0; i < 8; i++) {
    int c = grp + i * 32;
    float v = (L[c * 9 + tl] - m) * r * g[c] + bb[c];
    x[bx + (size_t)c * TS] = v;
    L[c * 9 + tl] = v * mv;
  }
  __syncthreads();
  const int tt = tid & 7, p = tid >> 3;  // 32 segs of 8 channels
  u16 hs[8], ls[8];
#pragma unroll
  for (int j = 0; j < 8; j++)
    bf_split(L[(p * 8 + j) * 9 + tt], hs[j], ls[j]);
  size_t da = ((size_t)b * PROWS + t0 + tt + 1) * Cz + p * 8;
  *(uint4*)&dhi[da] = *(uint4*)&hs[0];
  *(uint4*)&dlo[da] = *(uint4*)&ls[0];
}

// ---------------------------------------------------------------------------
extern "C" void kernel_launch(void* const* d_in, const int* in_sizes, int n_in,
                              void* d_out, int out_size, void* d_ws,
                              size_t ws_size, hipStream_t stream) {
  const float* x = (const float*)d_in[0];
  const float* xm = (const float*)d_in[1];
  const float* wq = (const float*)d_in[2];
  const float* bq = (const float*)d_in[3];
  const float* wk = (const float*)d_in[4];
  const float* bk = (const float*)d_in[5];
  const float* wv = (const float*)d_in[6];
  const float* bv = (const float*)d_in[7];
  const float* wo = (const float*)d_in[8];
  const float* bo = (const float*)d_in[9];
  const float* erk = (const float*)d_in[10];
  const float* erv = (const float*)d_in[11];
  const float* g1 = (const float*)d_in[12];
  const float* b1 = (const float*)d_in[13];
  const float* fw1 = (const float*)d_in[14];
  const float* fb1 = (const float*)d_in[15];
  const float* fw2 = (const float*)d_in[16];
  const float* fb2 = (const float*)d_in[17];
  const float* g2 = (const float*)d_in[18];
  const float* b2 = (const float*)d_in[19];

  const size_t NBC = (size_t)Bz * Cz * Tz;       // 1,048,576
  const size_t XBN = (size_t)Bz * Cz * TS;       // 1,056,768
  const size_t HP = (size_t)Bz * PROWS * FCz;    // 4,202,496 u16/array
  const size_t XP = (size_t)Bz * PROWS * Cz;     // 1,050,624 u16/array
  const size_t QS = (size_t)Bz * Hz * Tz * KCz;  // 1,048,576 u16/array

  float* ws = (float*)d_ws;
  float* xb = ws;
  float* yb = xb + XBN;   // attn partial O0
  float* p1 = yb + NBC;   // O1
  float* p2 = p1 + NBC;   // O2
  float* p3 = p2 + NBC;   // O3
  float* unf = p3 + NBC;  // union: Q/K/V packed OR wo outputs OR FFN hidden
  u16* hpH = (u16*)unf;
  u16* hpL = hpH + HP;
  u16* Qh = (u16*)unf;
  u16* Ql = Qh + QS;
  u16* Kh = Ql + QS;
  u16* Vh = Kh + QS;
  float* wo0 = unf;        // wo k-half 0 output (over dead Q/Ql, 4 MB)
  float* wo1 = unf + NBC;  // wo k-half 1 output (over dead Kh/Vh, 4 MB)
  float* xpf = unf + HP;
  u16* xpH = (u16*)xpf;
  u16* xpL = xpH + XP;
  float* qwf = xpf + XP;
  u16* qwAll = (u16*)qwf;  // 6 x 262144 u16
  float* w1f = qwf + 786432;
  u16* w1All = (u16*)w1f;  // 6 x 786432 u16
  float* w2f = w1f + 2359296;
  u16* w2All = (u16*)w2f;  // 6 x 786432 u16
  float* erf = w2f + 2359296;
  u16* ekAll = (u16*)erf;      // 6 x 2048 u16
  u16* evAll = ekAll + 12288;  // 6 x 2048 u16
  float* pbAll = erf + 12288;  // 6 x 1024 f32
  float* lb0 = pbAll + 6144;
  float* lb1 = lb0 + 16384;
  float* lb2 = lb1 + 16384;
  float* lb3 = lb2 + 16384;

  const int ntot = (int)NBC;
  pack_all<<<dim3(6 * 7184), 256, 0, stream>>>(
      wq, wk, wv, wo, bq, bk, bv, bo, erk, erv, fw1, fw2, qwAll, pbAll, ekAll,
      evAll, w1All, w2All);
  tpack<<<dim3(16, 4, 4), 256, 0, stream>>>(x, xm, xb, xpH, xpL, Cz);

  for (int l = 0; l < Lz; l++) {
    mfma_gemm2<0><<<dim3(16, 12, 4), 256, 0, stream>>>(
        qwAll + (size_t)l * 262144, xpH, xpL, pbAll + l * 1024, nullptr,
        nullptr, Qh, Ql, Kh, Vh, nullptr, nullptr, nullptr, nullptr, nullptr,
        nullptr, nullptr, nullptr, 1024, Cz, 0);
    attn_mfma<<<dim3(1024), 128, 0, stream>>>(
        Qh, Ql, Kh, Vh, xm, ekAll + l * 2048, evAll + l * 2048, yb, p1, p2,
        p3, lb0, lb1, lb2, lb3);
    // wo GEMM with fused combine: B staged from O0..3 + l0..3 (Q/K/V dead).
    mfma_gemm2<3><<<dim3(16, 8, 4), 256, 0, stream>>>(
        qwAll + (size_t)l * 262144, xpH, xpL, pbAll + l * 1024, wo0, wo1,
        nullptr, nullptr, nullptr, nullptr, yb, p1, p2, p3, lb0, lb1, lb2,
        lb3, 1024, Cz, 768);
    fused_ln<2, 2><<<dim3(128, 4), 256, 0, stream>>>(
        xb, wo0, wo1, nullptr, nullptr, bo + l * Cz, g1 + l * Cz, b1 + l * Cz,
        xm, xpH, xpL);
    conv_mfma<1><<<dim3(8, 16, 4), 256, 0, stream>>>(
        w1All + (size_t)l * 786432, xpH, xpL, fb1 + l * FCz, xm, hpH, hpL,
        nullptr, nullptr, nullptr, nullptr, FCz, Cz);
    conv_mfma<3><<<dim3(8, 16, 4), 256, 0, stream>>>(
        w2All + (size_t)l * 786432, hpH, hpL, nullptr, xm, nullptr, nullptr,
        yb, p1, p2, p3, Cz, FCz);
    fused_ln<1, 4><<<dim3(128, 4), 256, 0, stream>>>(
        xb, yb, p1, p2, p3, fb2 + l * Cz, g2 + l * Cz, b2 + l * Cz, xm, xpH,
        xpL);
  }
  mask_out<<<dim3((ntot + 255) / 256), 256, 0, stream>>>(xb, xm,
                                                         (float*)d_out);
}

// Round 10
// 969.250 us; speedup vs baseline: 1.0209x; 1.0209x over previous
//
#include <hip/hip_runtime.h>

// Encoder: L=6 layers of (rel-pos attention + channel-LN + K=3 conv FFN + LN)
// B=4, C=256, T=1024, H=4, KC=64, FC=1024, W=10, fp32 I/O.
// ROUND 10: de-confound R9 -- GEMM split into two wrappers over one body:
// qkv keeps launch_bounds(256,3) (768 blocks co-resident, no half-tail);
// wo reverts to unconstrained (fused-combine epilogue is register-heavy;
// R9's cap on it likely spilled). tpack keeps the mask_in fusion.
// attn: S 2-pass, PV 1-pass, fixed-max, j-split x4. Convs: 64m x 128t,
// 4 t-strip waves, tap-shared B staging, halo-predicated, reg-prefetch.
// wo-GEMM stages B directly from attn partials (fused combine).

#define Lz 6
#define Cz 256
#define FCz 1024
#define Hz 4
#define Wz 10
#define Bz 4
#define Tz 1024
#define KCz 64
#define NR 21
#define TS 1032
#define PADF 4
#define PROWS 1026
#define MFIX 8.0f

typedef unsigned short u16;
typedef unsigned int u32;
typedef __attribute__((ext_vector_type(8))) short bf8v;
typedef __attribute__((ext_vector_type(4))) float f4v;

#define MFMA(a, b, c) __builtin_amdgcn_mfma_f32_16x16x32_bf16(a, b, c, 0, 0, 0)

__device__ inline void bf_split(float v, u16& hi, u16& lo) {
  unsigned u = __float_as_uint(v);
  unsigned hr = (u + 0x7FFFu + ((u >> 16) & 1u)) >> 16;
  float rem = v - __uint_as_float(hr << 16);
  unsigned u2 = __float_as_uint(rem);
  unsigned lr = (u2 + 0x7FFFu + ((u2 >> 16) & 1u)) >> 16;
  hi = (u16)hr;
  lo = (u16)lr;
}

__device__ inline u16 bf_rne(float v) {
  u32 u = __float_as_uint(v);
  return (u16)((u + 0x7FFFu + ((u >> 16) & 1u)) >> 16);
}

// ---------------------------------------------------------------------------
__global__ __launch_bounds__(256) void mask_out(const float* __restrict__ xp,
                                                const float* __restrict__ m,
                                                float* __restrict__ out) {
  int id = blockIdx.x * 256 + threadIdx.x;
  if (id < Bz * Cz * Tz) {
    int t = id & (Tz - 1), row = id >> 10, b = id >> 18;
    out[id] = xp[(size_t)row * TS + PADF + t] * m[b * Tz + t];
  }
}

// ---------------------------------------------------------------------------
// Fused mask_in + transpose-pack: reads x [b][c][Tz] + mask, writes
// xb = x*m (TS-padded layout) AND packed hi/lo [b][1026][Cd] of (x*m)*m.
// ---------------------------------------------------------------------------
__global__ __launch_bounds__(256) void tpack(const float* __restrict__ xsrc,
                                             const float* __restrict__ mask,
                                             float* __restrict__ xb,
                                             u16* __restrict__ dhi,
                                             u16* __restrict__ dlo, int Cd) {
  __shared__ float L[64 * 68];
  const int tid = threadIdx.x;
  const int t0 = blockIdx.x * 64, c0 = blockIdx.y * 64, b = blockIdx.z;
#pragma unroll
  for (int i = 0; i < 16; i++) {
    int id = tid + 256 * i;
    int cc = id >> 6, tt = id & 63;
    float mv = mask[(size_t)b * Tz + t0 + tt];
    float v = xsrc[((size_t)(b * Cz + c0 + cc)) * Tz + t0 + tt] * mv;
    xb[((size_t)(b * Cz + c0 + cc)) * TS + PADF + t0 + tt] = v;
    L[cc * 68 + tt] = v;
  }
  __syncthreads();
  const int tt = tid >> 2, p = tid & 3;
  float mv = mask[(size_t)b * Tz + t0 + tt];
  u16 hs[16], ls[16];
#pragma unroll
  for (int j = 0; j < 16; j++) {
    float v = L[(p * 16 + j) * 68 + tt] * mv;
    bf_split(v, hs[j], ls[j]);
  }
  size_t da = ((size_t)b * PROWS + t0 + tt + 1) * Cd + c0 + p * 16;
  *(uint4*)&dhi[da] = *(uint4*)&hs[0];
  *(uint4*)&dhi[da + 8] = *(uint4*)&hs[8];
  *(uint4*)&dlo[da] = *(uint4*)&ls[0];
  *(uint4*)&dlo[da + 8] = *(uint4*)&ls[8];
}

// ---------------------------------------------------------------------------
// Pack ALL layers' weights in one launch. grid = 6 * 7184 blocks.
// ---------------------------------------------------------------------------
__global__ __launch_bounds__(256) void pack_all(
    const float* __restrict__ wq, const float* __restrict__ wk,
    const float* __restrict__ wv, const float* __restrict__ wo_,
    const float* __restrict__ bq, const float* __restrict__ bk,
    const float* __restrict__ bv, const float* __restrict__ bo,
    const float* __restrict__ erk, const float* __restrict__ erv,
    const float* __restrict__ fw1, const float* __restrict__ fw2,
    u16* __restrict__ qwAll, float* __restrict__ pbAll,
    u16* __restrict__ ekAll, u16* __restrict__ evAll,
    u16* __restrict__ w1All, u16* __restrict__ w2All) {
  const int blk = blockIdx.x, tid = threadIdx.x;
  const int layer = blk / 7184;
  const int bl = blk % 7184;
  if (bl < 1024) {
    int id = bl * 256 + tid;
    int o = id >> 8, c = id & 255;
    int sel = o >> 8;
    const size_t wof = (size_t)layer * Cz * Cz;
    const float* w = sel == 0 ? wq + wof
                              : (sel == 1 ? wk + wof
                                          : (sel == 2 ? wv + wof : wo_ + wof));
    qwAll[(size_t)layer * 262144 + id] = bf_rne(w[((o & 255) << 8) + c]);
    if (id < 1024) {
      int s2 = id >> 8;
      const float* bs = s2 == 0 ? bq : (s2 == 1 ? bk : (s2 == 2 ? bv : bo));
      pbAll[layer * 1024 + id] = bs[layer * Cz + (id & 255)];
    }
  } else if (bl < 1040) {
    int id = (bl - 1024) * 256 + tid;
    if (id < 2048) {
      int rr = id >> 6, d = id & 63;
      ekAll[layer * 2048 + id] =
          bf_rne((rr < NR) ? erk[(size_t)layer * NR * KCz + rr * KCz + d]
                           : 0.f);
    } else {
      int id2 = id - 2048;
      int d = id2 >> 5, rr = id2 & 31;
      evAll[layer * 2048 + id2] =
          bf_rne((rr < NR) ? erv[(size_t)layer * NR * KCz + rr * KCz + d]
                           : 0.f);
    }
  } else if (bl < 4112) {
    int id = (bl - 1040) * 256 + tid;
    int c = id % Cz;
    int rest = id / Cz;
    int o = rest % FCz, tap = rest / FCz;
    w1All[(size_t)layer * 786432 + id] =
        bf_rne(fw1[(size_t)layer * FCz * Cz * 3 + ((size_t)o * Cz + c) * 3 +
                   tap]);
  } else {
    int id = (bl - 4112) * 256 + tid;
    int c = id % FCz;
    int rest = id / FCz;
    int o = rest % Cz, tap = rest / Cz;
    w2All[(size_t)layer * 786432 + id] =
        bf_rne(fw2[(size_t)layer * Cz * FCz * 3 + ((size_t)o * FCz + c) * 3 +
                   tap]);
  }
}

// ---------------------------------------------------------------------------
// 2-pass MFMA GEMM body (A = single bf16 weights). Tile 64x64.
// EPI 0: B = hi/lo packed acts; qkv -> Q hi/lo (x0.125), K hi, V hi.
// EPI 3: wo, K-split-2; B staged from attn partials O0..O3 (fused combine).
// ---------------------------------------------------------------------------
template <int EPI>
static __device__ __forceinline__ void gemm_body(
    const u16* __restrict__ Ah, const u16* __restrict__ Bh,
    const u16* __restrict__ Bl, const float* __restrict__ bias,
    float* __restrict__ out, float* __restrict__ out2,
    u16* __restrict__ pqh, u16* __restrict__ pql, u16* __restrict__ pkh,
    u16* __restrict__ pvh, const float* __restrict__ Ox0,
    const float* __restrict__ Ox1, const float* __restrict__ Ox2,
    const float* __restrict__ Ox3, const float* __restrict__ sl0,
    const float* __restrict__ sl1, const float* __restrict__ sl2,
    const float* __restrict__ sl3, int M, int Kc, int m_base, char* smraw) {
  u16* Ash = (u16*)smraw;
  u16* Bsh = Ash + 2560;
  u16* Bsl = Bsh + 2560;
  const int tid = threadIdx.x;
  const int lane = tid & 63, wid = tid >> 6;
  const int wm = wid & 1, wn = wid >> 1;
  const int r = lane & 15, qd = lane >> 4;
  const int t0 = blockIdx.x * 64;
  const int b = blockIdx.z;
  const int srow = tid >> 2, sseg = (tid & 3) * 8;

  int m0, kc0, kcN;
  float* outp = out;
  if constexpr (EPI == 3) {
    m0 = m_base + (blockIdx.y >> 1) * 64;
    kc0 = (blockIdx.y & 1) * (Kc / 2);
    kcN = Kc / 2;
    outp = (blockIdx.y & 1) ? out2 : out;
  } else {
    m0 = blockIdx.y * 64 + m_base;
    kc0 = 0;
    kcN = Kc;
  }

  f4v acc[2][2];
#pragma unroll
  for (int i = 0; i < 2; i++)
#pragma unroll
    for (int j = 0; j < 2; j++) acc[i][j] = (f4v)(0.f);

  const size_t arow = (size_t)(m0 + srow) * Kc + kc0;
  const size_t brow = ((size_t)b * PROWS + t0 + 1 + srow) * Kc + kc0;
  for (int kc = 0; kc < kcN; kc += 32) {
    *(uint4*)&Ash[srow * 40 + sseg] = *(const uint4*)&Ah[arow + kc + sseg];
    if constexpr (EPI == 3) {
      // fused attn_combine: B row t = t0+srow, cols cc..cc+7 (one head blk)
      const int cc = kc0 + kc + sseg;
      const int hh = cc >> 6, dd = cc & 63;
      const size_t lbi = (size_t)(b * Hz + hh) * Tz + t0 + srow;
      const size_t ob = lbi * KCz + dd;
      float4 qa = *(const float4*)&Ox0[ob];
      float4 qb = *(const float4*)&Ox0[ob + 4];
      float4 ra = *(const float4*)&Ox1[ob];
      float4 rb = *(const float4*)&Ox1[ob + 4];
      float4 sa = *(const float4*)&Ox2[ob];
      float4 sb = *(const float4*)&Ox2[ob + 4];
      float4 ta = *(const float4*)&Ox3[ob];
      float4 tb = *(const float4*)&Ox3[ob + 4];
      const float li = 1.f / (sl0[lbi] + sl1[lbi] + sl2[lbi] + sl3[lbi]);
      float v[8] = {(qa.x + ra.x + sa.x + ta.x) * li,
                    (qa.y + ra.y + sa.y + ta.y) * li,
                    (qa.z + ra.z + sa.z + ta.z) * li,
                    (qa.w + ra.w + sa.w + ta.w) * li,
                    (qb.x + rb.x + sb.x + tb.x) * li,
                    (qb.y + rb.y + sb.y + tb.y) * li,
                    (qb.z + rb.z + sb.z + tb.z) * li,
                    (qb.w + rb.w + sb.w + tb.w) * li};
      u16 hhs[8], lls[8];
#pragma unroll
      for (int e = 0; e < 8; e++) bf_split(v[e], hhs[e], lls[e]);
      *(uint4*)&Bsh[srow * 40 + sseg] = *(uint4*)&hhs[0];
      *(uint4*)&Bsl[srow * 40 + sseg] = *(uint4*)&lls[0];
    } else {
      *(uint4*)&Bsh[srow * 40 + sseg] = *(const uint4*)&Bh[brow + kc + sseg];
      *(uint4*)&Bsl[srow * 40 + sseg] = *(const uint4*)&Bl[brow + kc + sseg];
    }
    __syncthreads();
    bf8v ah[2], bh2[2], bl2[2];
#pragma unroll
    for (int f = 0; f < 2; f++) {
      int ar = (wm * 32 + f * 16 + r) * 40 + qd * 8;
      int br = (wn * 32 + f * 16 + r) * 40 + qd * 8;
      ah[f] = *(bf8v*)&Ash[ar];
      bh2[f] = *(bf8v*)&Bsh[br];
      bl2[f] = *(bf8v*)&Bsl[br];
    }
#pragma unroll
    for (int mf = 0; mf < 2; mf++)
#pragma unroll
      for (int nf = 0; nf < 2; nf++) {
        acc[mf][nf] = MFMA(ah[mf], bh2[nf], acc[mf][nf]);
        acc[mf][nf] = MFMA(ah[mf], bl2[nf], acc[mf][nf]);
      }
    __syncthreads();
  }

  float* Ds = (float*)smraw;
  if constexpr (EPI == 0) {
    const int sel = m0 >> 8;
    const int h = (m0 >> 6) & 3;
    const int bhI = b * Hz + h;
    if (sel < 2) {
#pragma unroll
      for (int mf = 0; mf < 2; mf++)
#pragma unroll
        for (int nf = 0; nf < 2; nf++) {
          int nl = wn * 32 + nf * 16 + r;
          int ml = wm * 32 + mf * 16 + qd * 4;
          *(f4v*)&Ds[nl * 68 + ml] = acc[mf][nf];
        }
      __syncthreads();
      const int row = tid >> 2, p = tid & 3;
      size_t da = ((size_t)bhI * Tz + t0 + row) * KCz + p * 16;
      if (sel == 0) {
        u16 hs[16], ls[16];
#pragma unroll
        for (int jj = 0; jj < 4; jj++) {
          float4 dv = *(float4*)&Ds[row * 68 + p * 16 + jj * 4];
          float4 bb = *(const float4*)&bias[m0 + p * 16 + jj * 4];
          float vv[4] = {(dv.x + bb.x) * 0.125f, (dv.y + bb.y) * 0.125f,
                         (dv.z + bb.z) * 0.125f, (dv.w + bb.w) * 0.125f};
#pragma unroll
          for (int e = 0; e < 4; e++)
            bf_split(vv[e], hs[jj * 4 + e], ls[jj * 4 + e]);
        }
        *(uint4*)&pqh[da] = *(uint4*)&hs[0];
        *(uint4*)&pqh[da + 8] = *(uint4*)&hs[8];
        *(uint4*)&pql[da] = *(uint4*)&ls[0];
        *(uint4*)&pql[da + 8] = *(uint4*)&ls[8];
      } else {
        u16 hs[16];
#pragma unroll
        for (int jj = 0; jj < 4; jj++) {
          float4 dv = *(float4*)&Ds[row * 68 + p * 16 + jj * 4];
          float4 bb = *(const float4*)&bias[m0 + p * 16 + jj * 4];
          hs[jj * 4 + 0] = bf_rne(dv.x + bb.x);
          hs[jj * 4 + 1] = bf_rne(dv.y + bb.y);
          hs[jj * 4 + 2] = bf_rne(dv.z + bb.z);
          hs[jj * 4 + 3] = bf_rne(dv.w + bb.w);
        }
        *(uint4*)&pkh[da] = *(uint4*)&hs[0];
        *(uint4*)&pkh[da + 8] = *(uint4*)&hs[8];
      }
    } else {
#pragma unroll
      for (int mf = 0; mf < 2; mf++)
#pragma unroll
        for (int nf = 0; nf < 2; nf++) {
          int ml = wm * 32 + mf * 16 + qd * 4;
          int nl = wn * 32 + nf * 16 + r;
#pragma unroll
          for (int e = 0; e < 4; e++) Ds[(ml + e) * 68 + nl] = acc[mf][nf][e];
        }
      __syncthreads();
      const int row = tid >> 2, p = tid & 3;
      const float bb = bias[m0 + row];
      u16 hs[16];
#pragma unroll
      for (int jj = 0; jj < 16; jj++)
        hs[jj] = bf_rne(Ds[row * 68 + p * 16 + jj] + bb);
      size_t da = ((size_t)bhI * KCz + row) * Tz + t0 + p * 16;
      *(uint4*)&pvh[da] = *(uint4*)&hs[0];
      *(uint4*)&pvh[da + 8] = *(uint4*)&hs[8];
    }
  } else {
#pragma unroll
    for (int mf = 0; mf < 2; mf++)
#pragma unroll
      for (int nf = 0; nf < 2; nf++) {
        int ml = wm * 32 + mf * 16 + qd * 4;
        int nl = wn * 32 + nf * 16 + r;
#pragma unroll
        for (int e = 0; e < 4; e++) Ds[(ml + e) * 68 + nl] = acc[mf][nf][e];
      }
    __syncthreads();
    const int row = tid >> 2, p = tid & 3;
    size_t oa = ((size_t)b * Cz + (m0 - m_base) + row) * Tz + t0 + p * 16;
#pragma unroll
    for (int jj = 0; jj < 4; jj++)
      *(float4*)&outp[oa + jj * 4] = *(float4*)&Ds[row * 68 + p * 16 + jj * 4];
  }
}

// qkv wrapper: (256,3) -> VGPR<=170, 3 blocks/CU, 768-block grid co-resident.
__global__ __launch_bounds__(256, 3) void qkv_gemm(
    const u16* __restrict__ Ah, const u16* __restrict__ Bh,
    const u16* __restrict__ Bl, const float* __restrict__ bias,
    u16* __restrict__ pqh, u16* __restrict__ pql, u16* __restrict__ pkh,
    u16* __restrict__ pvh, int M, int Kc) {
  __shared__ __align__(16) char smraw[17408];
  gemm_body<0>(Ah, Bh, Bl, bias, nullptr, nullptr, pqh, pql, pkh, pvh,
               nullptr, nullptr, nullptr, nullptr, nullptr, nullptr, nullptr,
               nullptr, M, Kc, 0, smraw);
}

// wo wrapper: unconstrained (register-heavy fused-combine epilogue).
__global__ __launch_bounds__(256) void wo_gemm(
    const u16* __restrict__ Ah, const u16* __restrict__ Bh,
    const u16* __restrict__ Bl, const float* __restrict__ bias,
    float* __restrict__ out, float* __restrict__ out2,
    const float* __restrict__ Ox0, const float* __restrict__ Ox1,
    const float* __restrict__ Ox2, const float* __restrict__ Ox3,
    const float* __restrict__ sl0, const float* __restrict__ sl1,
    const float* __restrict__ sl2, const float* __restrict__ sl3, int M,
    int Kc, int m_base) {
  __shared__ __align__(16) char smraw[17408];
  gemm_body<3>(Ah, Bh, Bl, bias, out, out2, nullptr, nullptr, nullptr,
               nullptr, Ox0, Ox1, Ox2, Ox3, sl0, sl1, sl2, sl3, M, Kc, m_base,
               smraw);
}

// ---------------------------------------------------------------------------
// Conv (K=3) as 2-pass MFMA GEMM, 64m x 128t tile, 4 waves = 4 t-strips.
// Tap-shared B staging (130 rows once per 32-k chunk); reg-prefetch.
// Halo rows (prow 0 / 1025) zero-predicated in staging.
// EPI 1: conv1: +bias, relu, mask, pack hi/lo rows+1. grid (8, M/64, B).
// EPI 3: conv2: K-split x4 -> fp32 partials o0..o3. grid (8, 4*4, B).
// ---------------------------------------------------------------------------
template <int EPI>
__global__ __launch_bounds__(256, 2) void conv_mfma(
    const u16* __restrict__ Ah, const u16* __restrict__ Bh,
    const u16* __restrict__ Bl, const float* __restrict__ bias,
    const float* __restrict__ mask, u16* __restrict__ ph,
    u16* __restrict__ pl, float* __restrict__ o0, float* __restrict__ o1,
    float* __restrict__ o2, float* __restrict__ o3, int M, int Kc) {
  __shared__ __align__(16) char smraw[36480];
  u16* Ash = (u16*)smraw;        // [3][64][40]
  u16* Bsh = Ash + 3 * 64 * 40;  // [132][40] (130 rows used)
  u16* Bsl = Bsh + 132 * 40;
  const int tid = threadIdx.x;
  const int lane = tid & 63, wn = tid >> 6;  // 4 waves: t-strip wn*32
  const int r = lane & 15, qd = lane >> 4;
  const int t0 = blockIdx.x * 128;
  const int b = blockIdx.z;

  int m0, kc0, kcN;
  float* outp = nullptr;
  if constexpr (EPI == 3) {
    int mt = blockIdx.y >> 2, sp = blockIdx.y & 3;
    m0 = mt * 64;
    kc0 = sp * (Kc / 4);
    kcN = Kc / 4;
    outp = sp == 0 ? o0 : (sp == 1 ? o1 : (sp == 2 ? o2 : o3));
  } else {
    m0 = blockIdx.y * 64;
    kc0 = 0;
    kcN = Kc;
  }

  const int srow = tid >> 2, sseg = (tid & 3) * 8;  // rows 0..63
  const bool btail = tid < 8;                       // B rows 128..129
  const int brow2 = 128 + (tid >> 2);
  const bool h0 = (t0 + srow == 0);
  const bool hT = btail && (t0 + brow2 == PROWS - 1);
  const uint4 z4 = {0u, 0u, 0u, 0u};

  f4v acc[4][2];
#pragma unroll
  for (int i = 0; i < 4; i++)
#pragma unroll
    for (int j = 0; j < 2; j++) acc[i][j] = (f4v)(0.f);

  const size_t abase = (size_t)(m0 + srow) * Kc + kc0 + sseg;
  const size_t bbase = ((size_t)b * PROWS + t0 + srow) * Kc + kc0 + sseg;
  const size_t bbase64 = bbase + (size_t)64 * Kc;
  const size_t bbaseT = ((size_t)b * PROWS + t0 + brow2) * Kc + kc0 + sseg;

  uint4 ar[3], bh0, bh1, bl0, bl1, bht, blt;
  auto LOADR = [&](int kc) {
#pragma unroll
    for (int tp = 0; tp < 3; tp++)
      ar[tp] = *(const uint4*)&Ah[(size_t)tp * M * Kc + abase + kc];
    bh0 = *(const uint4*)&Bh[bbase + kc];
    bl0 = *(const uint4*)&Bl[bbase + kc];
    if (h0) {
      bh0 = z4;
      bl0 = z4;
    }
    bh1 = *(const uint4*)&Bh[bbase64 + kc];
    bl1 = *(const uint4*)&Bl[bbase64 + kc];
    if (btail) {
      bht = *(const uint4*)&Bh[bbaseT + kc];
      blt = *(const uint4*)&Bl[bbaseT + kc];
      if (hT) {
        bht = z4;
        blt = z4;
      }
    }
  };

  LOADR(0);
  for (int kc = 0; kc < kcN; kc += 32) {
#pragma unroll
    for (int tp = 0; tp < 3; tp++)
      *(uint4*)&Ash[(tp * 64 + srow) * 40 + sseg] = ar[tp];
    *(uint4*)&Bsh[srow * 40 + sseg] = bh0;
    *(uint4*)&Bsh[(srow + 64) * 40 + sseg] = bh1;
    *(uint4*)&Bsl[srow * 40 + sseg] = bl0;
    *(uint4*)&Bsl[(srow + 64) * 40 + sseg] = bl1;
    if (btail) {
      *(uint4*)&Bsh[brow2 * 40 + sseg] = bht;
      *(uint4*)&Bsl[brow2 * 40 + sseg] = blt;
    }
    __syncthreads();
    if (kc + 32 < kcN) LOADR(kc + 32);  // prefetch next chunk
#pragma unroll
    for (int tap = 0; tap < 3; tap++) {
      bf8v ah[4], bh2[2], bl2[2];
#pragma unroll
      for (int mf = 0; mf < 4; mf++)
        ah[mf] = *(bf8v*)&Ash[(tap * 64 + mf * 16 + r) * 40 + qd * 8];
#pragma unroll
      for (int nf = 0; nf < 2; nf++) {
        int br = (wn * 32 + nf * 16 + r + tap) * 40 + qd * 8;
        bh2[nf] = *(bf8v*)&Bsh[br];
        bl2[nf] = *(bf8v*)&Bsl[br];
      }
#pragma unroll
      for (int mf = 0; mf < 4; mf++)
#pragma unroll
        for (int nf = 0; nf < 2; nf++) {
          acc[mf][nf] = MFMA(ah[mf], bh2[nf], acc[mf][nf]);
          acc[mf][nf] = MFMA(ah[mf], bl2[nf], acc[mf][nf]);
        }
    }
    __syncthreads();
  }

  // acc[mf][nf][e]: m = mf*16 + qd*4 + e, t = wn*32 + nf*16 + r
  if constexpr (EPI == 1) {
    float* Ds = (float*)smraw;  // [t 128][m 68]
#pragma unroll
    for (int mf = 0; mf < 4; mf++)
#pragma unroll
      for (int nf = 0; nf < 2; nf++) {
        int tl = wn * 32 + nf * 16 + r;
        int ml = mf * 16 + qd * 4;
        *(f4v*)&Ds[tl * 68 + ml] = acc[mf][nf];
      }
    __syncthreads();
    const int row = tid >> 1, half = (tid & 1) * 32;
    const int t = t0 + row;
    const float mv = mask[(size_t)b * Tz + t];
    u16 hs[32], ls[32];
#pragma unroll
    for (int j = 0; j < 32; j += 4) {
      float4 dv = *(float4*)&Ds[row * 68 + half + j];
      float4 bb = *(const float4*)&bias[m0 + half + j];
      float vv[4] = {dv.x + bb.x, dv.y + bb.y, dv.z + bb.z, dv.w + bb.w};
#pragma unroll
      for (int e = 0; e < 4; e++) {
        float v = fmaxf(vv[e], 0.f) * mv;
        bf_split(v, hs[j + e], ls[j + e]);
      }
    }
    size_t da = ((size_t)b * PROWS + t + 1) * M + m0 + half;
#pragma unroll
    for (int j = 0; j < 32; j += 8) {
      *(uint4*)&ph[da + j] = *(uint4*)&hs[j];
      *(uint4*)&pl[da + j] = *(uint4*)&ls[j];
    }
  } else {
    float* Ds = (float*)smraw;  // [m 64][t 132]
#pragma unroll
    for (int mf = 0; mf < 4; mf++)
#pragma unroll
      for (int nf = 0; nf < 2; nf++) {
        int ml = mf * 16 + qd * 4;
        int nl = wn * 32 + nf * 16 + r;
#pragma unroll
        for (int e = 0; e < 4; e++) Ds[(ml + e) * 132 + nl] = acc[mf][nf][e];
      }
    __syncthreads();
    const int row = tid >> 2, seg = (tid & 3) * 32;
    size_t oa = ((size_t)b * Cz + m0 + row) * Tz + t0 + seg;
#pragma unroll
    for (int j = 0; j < 8; j++)
      *(float4*)&outp[oa + j * 4] = *(float4*)&Ds[row * 132 + seg + j * 4];
  }
}

// ---------------------------------------------------------------------------
// Barrier-free MFMA flash attention, fixed-max softmax, 32 q-rows/wave,
// j-split x4. Q hi/lo; K,V,er single bf16: S 2-pass, PV 1-pass.
// grid 1024 = 16 bh x 4 splits x 16 i-blocks(64); 128 thr (2 waves).
// ---------------------------------------------------------------------------
__global__ __launch_bounds__(128, 2) void attn_mfma(
    const u16* __restrict__ Qh_, const u16* __restrict__ Ql_,
    const u16* __restrict__ Kh_, const u16* __restrict__ Vh_,
    const float* __restrict__ mask, const u16* __restrict__ erkH,
    const u16* __restrict__ ervH, float* __restrict__ O0,
    float* __restrict__ O1, float* __restrict__ O2, float* __restrict__ O3,
    float* __restrict__ lp0, float* __restrict__ lp1,
    float* __restrict__ lp2, float* __restrict__ lp3) {
  __shared__ __align__(16) char smraw[2][14336];
  const int tid = threadIdx.x;
  const int lane = tid & 63, wid = tid >> 6;
  const int r = lane & 15, qd = lane >> 4;
  const int idx = blockIdx.x;
  const int bh = idx & 15;
  const int split = (idx >> 4) & 3;
  const int i0w = (idx >> 6) * 64 + wid * 32;
  const int b = bh >> 2, h = bh & 3;
  const float* mb = mask + (size_t)b * Tz;
  const size_t qkbase = (size_t)bh * Tz * KCz;
  const size_t vbase = (size_t)bh * KCz * Tz;
  float* Op = split == 0 ? O0 : (split == 1 ? O1 : (split == 2 ? O2 : O3));
  float* lp = split == 0 ? lp0 : (split == 1 ? lp1 : (split == 2 ? lp2 : lp3));
  const int j0beg = split * 256;

  float* rqs = (float*)(smraw[wid]);      // [32][22]
  float* bands = rqs + 704;               // [32][22]
  u16* Pp = (u16*)(smraw[wid] + 5632);    // [32][72]; reused as Os f32

  bf8v qh[2][2], ql[2][2];
#pragma unroll
  for (int rs = 0; rs < 2; rs++) {
    const size_t qrow = qkbase + (size_t)(i0w + rs * 16 + r) * KCz;
#pragma unroll
    for (int ks = 0; ks < 2; ks++) {
      qh[rs][ks] = *(const bf8v*)&Qh_[qrow + ks * 32 + qd * 8];
      ql[rs][ks] = *(const bf8v*)&Ql_[qrow + ks * 32 + qd * 8];
    }
  }
  for (int t = lane; t < 704; t += 64) bands[t] = -1e30f;

#pragma unroll
  for (int rs = 0; rs < 2; rs++) {
    f4v rc[2] = {(f4v)(0.f), (f4v)(0.f)};
#pragma unroll
    for (int nf = 0; nf < 2; nf++)
#pragma unroll
      for (int ks = 0; ks < 2; ks++) {
        bf8v eh = *(const bf8v*)&erkH[(16 * nf + r) * 64 + ks * 32 + qd * 8];
        rc[nf] = MFMA(qh[rs][ks], eh, rc[nf]);
        rc[nf] = MFMA(ql[rs][ks], eh, rc[nf]);
      }
#pragma unroll
    for (int nf = 0; nf < 2; nf++) {
      int rr = 16 * nf + r;
      if (rr < NR) {
#pragma unroll
        for (int e = 0; e < 4; e++)
          rqs[(rs * 16 + 4 * qd + e) * 22 + rr] = rc[nf][e];
      }
    }
  }

  float qm[2][4];
#pragma unroll
  for (int rs = 0; rs < 2; rs++)
#pragma unroll
    for (int e = 0; e < 4; e++) qm[rs][e] = mb[i0w + rs * 16 + 4 * qd + e];

  float lacc[2][4] = {};
  f4v oacc[2][4];
#pragma unroll
  for (int rs = 0; rs < 2; rs++)
#pragma unroll
    for (int nf = 0; nf < 4; nf++) oacc[rs][nf] = (f4v)(0.f);

#pragma unroll 2
  for (int jt = 0; jt < 4; jt++) {
    const int j0 = j0beg + jt * 64;
    bf8v kh[4][2], vh[4][2];
#pragma unroll
    for (int nf = 0; nf < 4; nf++) {
      const size_t kr = qkbase + (size_t)(j0 + 16 * nf + r) * KCz;
      const size_t vr = vbase + (size_t)(16 * nf + r) * Tz + j0;
#pragma unroll
      for (int ks = 0; ks < 2; ks++) {
        kh[nf][ks] = *(const bf8v*)&Kh_[kr + ks * 32 + qd * 8];
        vh[nf][ks] = *(const bf8v*)&Vh_[vr + ks * 32 + qd * 8];
      }
    }
    float km4[4];
#pragma unroll
    for (int nf = 0; nf < 4; nf++) km4[nf] = mb[j0 + 16 * nf + r];

#pragma unroll
    for (int rs = 0; rs < 2; rs++) {
      f4v sa[4];
#pragma unroll
      for (int nf = 0; nf < 4; nf++) sa[nf] = (f4v)(0.f);
#pragma unroll
      for (int nf = 0; nf < 4; nf++)
#pragma unroll
        for (int ks = 0; ks < 2; ks++) {
          sa[nf] = MFMA(qh[rs][ks], kh[nf][ks], sa[nf]);
          sa[nf] = MFMA(ql[rs][ks], kh[nf][ks], sa[nf]);
        }
      const int ibase = i0w + rs * 16;
      const bool diag = (j0 + 63 >= ibase - Wz) && (j0 <= ibase + 15 + Wz);
#pragma unroll
      for (int nf = 0; nf < 4; nf++)
#pragma unroll
        for (int e = 0; e < 4; e++) {
          const int iloc = rs * 16 + 4 * qd + e;
          float s = sa[nf][e];
          if (diag) {
            int dl = (j0 + 16 * nf + r) - (i0w + iloc);
            bool inb = (unsigned)(dl + Wz) <= 2u * Wz;
            if (inb) s += rqs[iloc * 22 + dl + Wz];
            if (qm[rs][e] * km4[nf] == 0.f) s = -1e4f;
            if (inb) bands[iloc * 22 + dl + Wz] = s;
          } else {
            if (qm[rs][e] * km4[nf] == 0.f) s = -1e4f;
          }
          float p = __expf(s - MFIX);
          lacc[rs][e] += p;
          Pp[iloc * 72 + 16 * nf + r] = bf_rne(p);
        }
    }
#pragma unroll
    for (int rs = 0; rs < 2; rs++)
#pragma unroll
      for (int ks = 0; ks < 2; ks++) {
        bf8v Ph = *(bf8v*)&Pp[(rs * 16 + r) * 72 + ks * 32 + qd * 8];
#pragma unroll
        for (int nf = 0; nf < 4; nf++)
          oacc[rs][nf] = MFMA(Ph, vh[nf][ks], oacc[rs][nf]);
      }
  }

  for (int t = lane; t < 32 * 32; t += 64) {
    int i = t >> 5, rr = t & 31;
    float p = (rr < NR) ? __expf(bands[i * 22 + rr] - MFIX) : 0.f;
    Pp[i * 72 + rr] = bf_rne(p);
  }
#pragma unroll
  for (int rs = 0; rs < 2; rs++) {
    bf8v Ph = *(bf8v*)&Pp[(rs * 16 + r) * 72 + qd * 8];
#pragma unroll
    for (int nf = 0; nf < 4; nf++) {
      bf8v eh = *(const bf8v*)&ervH[(16 * nf + r) * 32 + qd * 8];
      oacc[rs][nf] = MFMA(Ph, eh, oacc[rs][nf]);
    }
  }

#pragma unroll
  for (int off = 1; off < 16; off <<= 1)
#pragma unroll
    for (int rs = 0; rs < 2; rs++)
#pragma unroll
      for (int e = 0; e < 4; e++)
        lacc[rs][e] += __shfl_xor(lacc[rs][e], off, 16);
  if (r == 0) {
#pragma unroll
    for (int rs = 0; rs < 2; rs++)
#pragma unroll
      for (int e = 0; e < 4; e++)
        lp[(size_t)bh * Tz + i0w + rs * 16 + 4 * qd + e] = lacc[rs][e];
  }

  float* Os = (float*)Pp;  // [32][68]
#pragma unroll
  for (int rs = 0; rs < 2; rs++)
#pragma unroll
    for (int nf = 0; nf < 4; nf++)
#pragma unroll
      for (int e = 0; e < 4; e++)
        Os[(rs * 16 + 4 * qd + e) * 68 + 16 * nf + r] = oacc[rs][nf][e];
#pragma unroll
  for (int rs = 0; rs < 2; rs++) {
    const float* src = &Os[(rs * 16 + r) * 68 + qd * 16];
    size_t oa = ((size_t)bh * Tz + i0w + rs * 16 + r) * KCz + qd * 16;
#pragma unroll
    for (int jj = 0; jj < 4; jj++)
      *(float4*)&Op[oa + jj * 4] = *(const float4*)&src[jj * 4];
  }
}

// ---------------------------------------------------------------------------
// Fused residual + channel LayerNorm + transpose-pack.
// 8 t-cols/block, grid (128, B) = 512 blocks (2/CU); wave-0 shfl reduce.
// VAR 1 (NP partials, mask): x = LN(x + (sum(parts) + cbias)*mask)  [conv2]
// VAR 2 (NP partials, no mask): x = LN(x + sum(parts) + cbias)      [wo]
// ---------------------------------------------------------------------------
template <int VAR, int NP>
__global__ __launch_bounds__(256) void fused_ln(
    float* __restrict__ x, const float* __restrict__ y,
    const float* __restrict__ p1, const float* __restrict__ p2,
    const float* __restrict__ p3, const float* __restrict__ cbias,
    const float* __restrict__ g, const float* __restrict__ bb,
    const float* __restrict__ mask, u16* __restrict__ dhi,
    u16* __restrict__ dlo) {
  __shared__ float L[256 * 9];
  __shared__ float red[32][8], red2[32][8];
  __shared__ float ms[8], rs[8];
  const int tid = threadIdx.x;
  const int t0 = blockIdx.x * 8, b = blockIdx.y;
  const int tl = tid & 7, grp = tid >> 3;  // 32 c-groups of 8 t-cols
  const size_t bx = (size_t)b * Cz * TS + PADF + t0 + tl;
  const size_t by = (size_t)b * Cz * Tz + t0 + tl;
  const float mv = mask[(size_t)b * Tz + t0 + tl];
  float s = 0.f, sq = 0.f;
#pragma unroll
  for (int i = 0; i < 8; i++) {
    int c = grp + i * 32;
    float add = y[by + (size_t)c * Tz] + p1[by + (size_t)c * Tz] + cbias[c];
    if constexpr (NP == 4)
      add += p2[by + (size_t)c * Tz] + p3[by + (size_t)c * Tz];
    if constexpr (VAR == 1) add *= mv;
    float v = x[bx + (size_t)c * TS] + add;
    L[c * 9 + tl] = v;
    s += v;
    sq += v * v;
  }
  red[grp][tl] = s;
  red2[grp][tl] = sq;
  __syncthreads();
  if (tid < 64) {
    const int j = tid >> 3, tt = tid & 7;
    float su = red[j][tt] + red[j + 8][tt] + red[j + 16][tt] + red[j + 24][tt];
    float sqq =
        red2[j][tt] + red2[j + 8][tt] + red2[j + 16][tt] + red2[j + 24][tt];
    su += __shfl_xor(su, 8);
    su += __shfl_xor(su, 16);
    su += __shfl_xor(su, 32);
    sqq += __shfl_xor(sqq, 8);
    sqq += __shfl_xor(sqq, 16);
    sqq += __shfl_xor(sqq, 32);
    if (j == 0) {
      float m = su * (1.f / Cz);
      ms[tt] = m;
      rs[tt] = rsqrtf(sqq * (1.f / Cz) - m * m + 1e-5f);
    }
  }
  __syncthreads();
  const float m = ms[tl], r = rs[tl];
#pragma unroll
  for (int i = 0; i < 8; i++) {
    int c = grp + i * 32;
    float v = (L[c * 9 + tl] - m) * r * g[c] + bb[c];
    x[bx + (size_t)c * TS] = v;
    L[c * 9 + tl] = v * mv;
  }
  __syncthreads();
  const int tt = tid & 7, p = tid >> 3;  // 32 segs of 8 channels
  u16 hs[8], ls[8];
#pragma unroll
  for (int j = 0; j < 8; j++)
    bf_split(L[(p * 8 + j) * 9 + tt], hs[j], ls[j]);
  size_t da = ((size_t)b * PROWS + t0 + tt + 1) * Cz + p * 8;
  *(uint4*)&dhi[da] = *(uint4*)&hs[0];
  *(uint4*)&dlo[da] = *(uint4*)&ls[0];
}

// ---------------------------------------------------------------------------
extern "C" void kernel_launch(void* const* d_in, const int* in_sizes, int n_in,
                              void* d_out, int out_size, void* d_ws,
                              size_t ws_size, hipStream_t stream) {
  const float* x = (const float*)d_in[0];
  const float* xm = (const float*)d_in[1];
  const float* wq = (const float*)d_in[2];
  const float* bq = (const float*)d_in[3];
  const float* wk = (const float*)d_in[4];
  const float* bk = (const float*)d_in[5];
  const float* wv = (const float*)d_in[6];
  const float* bv = (const float*)d_in[7];
  const float* wo = (const float*)d_in[8];
  const float* bo = (const float*)d_in[9];
  const float* erk = (const float*)d_in[10];
  const float* erv = (const float*)d_in[11];
  const float* g1 = (const float*)d_in[12];
  const float* b1 = (const float*)d_in[13];
  const float* fw1 = (const float*)d_in[14];
  const float* fb1 = (const float*)d_in[15];
  const float* fw2 = (const float*)d_in[16];
  const float* fb2 = (const float*)d_in[17];
  const float* g2 = (const float*)d_in[18];
  const float* b2 = (const float*)d_in[19];

  const size_t NBC = (size_t)Bz * Cz * Tz;       // 1,048,576
  const size_t XBN = (size_t)Bz * Cz * TS;       // 1,056,768
  const size_t HP = (size_t)Bz * PROWS * FCz;    // 4,202,496 u16/array
  const size_t XP = (size_t)Bz * PROWS * Cz;     // 1,050,624 u16/array
  const size_t QS = (size_t)Bz * Hz * Tz * KCz;  // 1,048,576 u16/array

  float* ws = (float*)d_ws;
  float* xb = ws;
  float* yb = xb + XBN;   // attn partial O0
  float* p1 = yb + NBC;   // O1
  float* p2 = p1 + NBC;   // O2
  float* p3 = p2 + NBC;   // O3
  float* unf = p3 + NBC;  // union: Q/K/V packed OR wo outputs OR FFN hidden
  u16* hpH = (u16*)unf;
  u16* hpL = hpH + HP;
  u16* Qh = (u16*)unf;
  u16* Ql = Qh + QS;
  u16* Kh = Ql + QS;
  u16* Vh = Kh + QS;
  float* wo0 = unf;        // wo k-half 0 output (over dead Q/Ql, 4 MB)
  float* wo1 = unf + NBC;  // wo k-half 1 output (over dead Kh/Vh, 4 MB)
  float* xpf = unf + HP;
  u16* xpH = (u16*)xpf;
  u16* xpL = xpH + XP;
  float* qwf = xpf + XP;
  u16* qwAll = (u16*)qwf;  // 6 x 262144 u16
  float* w1f = qwf + 786432;
  u16* w1All = (u16*)w1f;  // 6 x 786432 u16
  float* w2f = w1f + 2359296;
  u16* w2All = (u16*)w2f;  // 6 x 786432 u16
  float* erf = w2f + 2359296;
  u16* ekAll = (u16*)erf;      // 6 x 2048 u16
  u16* evAll = ekAll + 12288;  // 6 x 2048 u16
  float* pbAll = erf + 12288;  // 6 x 1024 f32
  float* lb0 = pbAll + 6144;
  float* lb1 = lb0 + 16384;
  float* lb2 = lb1 + 16384;
  float* lb3 = lb2 + 16384;

  const int ntot = (int)NBC;
  pack_all<<<dim3(6 * 7184), 256, 0, stream>>>(
      wq, wk, wv, wo, bq, bk, bv, bo, erk, erv, fw1, fw2, qwAll, pbAll, ekAll,
      evAll, w1All, w2All);
  tpack<<<dim3(16, 4, 4), 256, 0, stream>>>(x, xm, xb, xpH, xpL, Cz);

  for (int l = 0; l < Lz; l++) {
    qkv_gemm<<<dim3(16, 12, 4), 256, 0, stream>>>(
        qwAll + (size_t)l * 262144, xpH, xpL, pbAll + l * 1024, Qh, Ql, Kh,
        Vh, 1024, Cz);
    attn_mfma<<<dim3(1024), 128, 0, stream>>>(
        Qh, Ql, Kh, Vh, xm, ekAll + l * 2048, evAll + l * 2048, yb, p1, p2,
        p3, lb0, lb1, lb2, lb3);
    // wo GEMM with fused combine: B staged from O0..3 + l0..3 (Q/K/V dead).
    wo_gemm<<<dim3(16, 8, 4), 256, 0, stream>>>(
        qwAll + (size_t)l * 262144, xpH, xpL, pbAll + l * 1024, wo0, wo1, yb,
        p1, p2, p3, lb0, lb1, lb2, lb3, 1024, Cz, 768);
    fused_ln<2, 2><<<dim3(128, 4), 256, 0, stream>>>(
        xb, wo0, wo1, nullptr, nullptr, bo + l * Cz, g1 + l * Cz, b1 + l * Cz,
        xm, xpH, xpL);
    conv_mfma<1><<<dim3(8, 16, 4), 256, 0, stream>>>(
        w1All + (size_t)l * 786432, xpH, xpL, fb1 + l * FCz, xm, hpH, hpL,
        nullptr, nullptr, nullptr, nullptr, FCz, Cz);
    conv_mfma<3><<<dim3(8, 16, 4), 256, 0, stream>>>(
        w2All + (size_t)l * 786432, hpH, hpL, nullptr, xm, nullptr, nullptr,
        yb, p1, p2, p3, Cz, FCz);
    fused_ln<1, 4><<<dim3(128, 4), 256, 0, stream>>>(
        xb, yb, p1, p2, p3, fb2 + l * Cz, g2 + l * Cz, b2 + l * Cz, xm, xpH,
        xpL);
  }
  mask_out<<<dim3((ntot + 255) / 256), 256, 0, stream>>>(xb, xm,
                                                         (float*)d_out);
}

// Round 11
// 934.906 us; speedup vs baseline: 1.0584x; 1.0367x over previous
//
#include <hip/hip_runtime.h>

// Encoder: L=6 layers of (rel-pos attention + channel-LN + K=3 conv FFN + LN)
// B=4, C=256, T=1024, H=4, KC=64, FC=1024, W=10, fp32 I/O.
// ROUND 11: spend absmax headroom (0.031 vs 0.084 threshold) -- FFN hidden
// goes SINGLE bf16: conv1 writes rne(v) only (no lo pass/stores), conv2
// stages Bsh only and runs 1 MFMA per fragment (conv2 matrix work halved,
// LDS traffic -45%). conv1's own B input (post-LN x) stays hi/lo.
// Base = R10 (969us): qkv launch_bounds(256,3); wo unconstrained with fused
// attn-combine B-staging; tpack fused mask_in; halo-predicated convs.

#define Lz 6
#define Cz 256
#define FCz 1024
#define Hz 4
#define Wz 10
#define Bz 4
#define Tz 1024
#define KCz 64
#define NR 21
#define TS 1032
#define PADF 4
#define PROWS 1026
#define MFIX 8.0f

typedef unsigned short u16;
typedef unsigned int u32;
typedef __attribute__((ext_vector_type(8))) short bf8v;
typedef __attribute__((ext_vector_type(4))) float f4v;

#define MFMA(a, b, c) __builtin_amdgcn_mfma_f32_16x16x32_bf16(a, b, c, 0, 0, 0)

__device__ inline void bf_split(float v, u16& hi, u16& lo) {
  unsigned u = __float_as_uint(v);
  unsigned hr = (u + 0x7FFFu + ((u >> 16) & 1u)) >> 16;
  float rem = v - __uint_as_float(hr << 16);
  unsigned u2 = __float_as_uint(rem);
  unsigned lr = (u2 + 0x7FFFu + ((u2 >> 16) & 1u)) >> 16;
  hi = (u16)hr;
  lo = (u16)lr;
}

__device__ inline u16 bf_rne(float v) {
  u32 u = __float_as_uint(v);
  return (u16)((u + 0x7FFFu + ((u >> 16) & 1u)) >> 16);
}

// ---------------------------------------------------------------------------
__global__ __launch_bounds__(256) void mask_out(const float* __restrict__ xp,
                                                const float* __restrict__ m,
                                                float* __restrict__ out) {
  int id = blockIdx.x * 256 + threadIdx.x;
  if (id < Bz * Cz * Tz) {
    int t = id & (Tz - 1), row = id >> 10, b = id >> 18;
    out[id] = xp[(size_t)row * TS + PADF + t] * m[b * Tz + t];
  }
}

// ---------------------------------------------------------------------------
// Fused mask_in + transpose-pack: reads x [b][c][Tz] + mask, writes
// xb = x*m (TS-padded layout) AND packed hi/lo [b][1026][Cd] of (x*m)*m.
// ---------------------------------------------------------------------------
__global__ __launch_bounds__(256) void tpack(const float* __restrict__ xsrc,
                                             const float* __restrict__ mask,
                                             float* __restrict__ xb,
                                             u16* __restrict__ dhi,
                                             u16* __restrict__ dlo, int Cd) {
  __shared__ float L[64 * 68];
  const int tid = threadIdx.x;
  const int t0 = blockIdx.x * 64, c0 = blockIdx.y * 64, b = blockIdx.z;
#pragma unroll
  for (int i = 0; i < 16; i++) {
    int id = tid + 256 * i;
    int cc = id >> 6, tt = id & 63;
    float mv = mask[(size_t)b * Tz + t0 + tt];
    float v = xsrc[((size_t)(b * Cz + c0 + cc)) * Tz + t0 + tt] * mv;
    xb[((size_t)(b * Cz + c0 + cc)) * TS + PADF + t0 + tt] = v;
    L[cc * 68 + tt] = v;
  }
  __syncthreads();
  const int tt = tid >> 2, p = tid & 3;
  float mv = mask[(size_t)b * Tz + t0 + tt];
  u16 hs[16], ls[16];
#pragma unroll
  for (int j = 0; j < 16; j++) {
    float v = L[(p * 16 + j) * 68 + tt] * mv;
    bf_split(v, hs[j], ls[j]);
  }
  size_t da = ((size_t)b * PROWS + t0 + tt + 1) * Cd + c0 + p * 16;
  *(uint4*)&dhi[da] = *(uint4*)&hs[0];
  *(uint4*)&dhi[da + 8] = *(uint4*)&hs[8];
  *(uint4*)&dlo[da] = *(uint4*)&ls[0];
  *(uint4*)&dlo[da + 8] = *(uint4*)&ls[8];
}

// ---------------------------------------------------------------------------
// Pack ALL layers' weights in one launch. grid = 6 * 7184 blocks.
// ---------------------------------------------------------------------------
__global__ __launch_bounds__(256) void pack_all(
    const float* __restrict__ wq, const float* __restrict__ wk,
    const float* __restrict__ wv, const float* __restrict__ wo_,
    const float* __restrict__ bq, const float* __restrict__ bk,
    const float* __restrict__ bv, const float* __restrict__ bo,
    const float* __restrict__ erk, const float* __restrict__ erv,
    const float* __restrict__ fw1, const float* __restrict__ fw2,
    u16* __restrict__ qwAll, float* __restrict__ pbAll,
    u16* __restrict__ ekAll, u16* __restrict__ evAll,
    u16* __restrict__ w1All, u16* __restrict__ w2All) {
  const int blk = blockIdx.x, tid = threadIdx.x;
  const int layer = blk / 7184;
  const int bl = blk % 7184;
  if (bl < 1024) {
    int id = bl * 256 + tid;
    int o = id >> 8, c = id & 255;
    int sel = o >> 8;
    const size_t wof = (size_t)layer * Cz * Cz;
    const float* w = sel == 0 ? wq + wof
                              : (sel == 1 ? wk + wof
                                          : (sel == 2 ? wv + wof : wo_ + wof));
    qwAll[(size_t)layer * 262144 + id] = bf_rne(w[((o & 255) << 8) + c]);
    if (id < 1024) {
      int s2 = id >> 8;
      const float* bs = s2 == 0 ? bq : (s2 == 1 ? bk : (s2 == 2 ? bv : bo));
      pbAll[layer * 1024 + id] = bs[layer * Cz + (id & 255)];
    }
  } else if (bl < 1040) {
    int id = (bl - 1024) * 256 + tid;
    if (id < 2048) {
      int rr = id >> 6, d = id & 63;
      ekAll[layer * 2048 + id] =
          bf_rne((rr < NR) ? erk[(size_t)layer * NR * KCz + rr * KCz + d]
                           : 0.f);
    } else {
      int id2 = id - 2048;
      int d = id2 >> 5, rr = id2 & 31;
      evAll[layer * 2048 + id2] =
          bf_rne((rr < NR) ? erv[(size_t)layer * NR * KCz + rr * KCz + d]
                           : 0.f);
    }
  } else if (bl < 4112) {
    int id = (bl - 1040) * 256 + tid;
    int c = id % Cz;
    int rest = id / Cz;
    int o = rest % FCz, tap = rest / FCz;
    w1All[(size_t)layer * 786432 + id] =
        bf_rne(fw1[(size_t)layer * FCz * Cz * 3 + ((size_t)o * Cz + c) * 3 +
                   tap]);
  } else {
    int id = (bl - 4112) * 256 + tid;
    int c = id % FCz;
    int rest = id / FCz;
    int o = rest % Cz, tap = rest / Cz;
    w2All[(size_t)layer * 786432 + id] =
        bf_rne(fw2[(size_t)layer * Cz * FCz * 3 + ((size_t)o * FCz + c) * 3 +
                   tap]);
  }
}

// ---------------------------------------------------------------------------
// 2-pass MFMA GEMM body (A = single bf16 weights). Tile 64x64.
// EPI 0: B = hi/lo packed acts; qkv -> Q hi/lo (x0.125), K hi, V hi.
// EPI 3: wo, K-split-2; B staged from attn partials O0..O3 (fused combine).
// ---------------------------------------------------------------------------
template <int EPI>
static __device__ __forceinline__ void gemm_body(
    const u16* __restrict__ Ah, const u16* __restrict__ Bh,
    const u16* __restrict__ Bl, const float* __restrict__ bias,
    float* __restrict__ out, float* __restrict__ out2,
    u16* __restrict__ pqh, u16* __restrict__ pql, u16* __restrict__ pkh,
    u16* __restrict__ pvh, const float* __restrict__ Ox0,
    const float* __restrict__ Ox1, const float* __restrict__ Ox2,
    const float* __restrict__ Ox3, const float* __restrict__ sl0,
    const float* __restrict__ sl1, const float* __restrict__ sl2,
    const float* __restrict__ sl3, int M, int Kc, int m_base, char* smraw) {
  u16* Ash = (u16*)smraw;
  u16* Bsh = Ash + 2560;
  u16* Bsl = Bsh + 2560;
  const int tid = threadIdx.x;
  const int lane = tid & 63, wid = tid >> 6;
  const int wm = wid & 1, wn = wid >> 1;
  const int r = lane & 15, qd = lane >> 4;
  const int t0 = blockIdx.x * 64;
  const int b = blockIdx.z;
  const int srow = tid >> 2, sseg = (tid & 3) * 8;

  int m0, kc0, kcN;
  float* outp = out;
  if constexpr (EPI == 3) {
    m0 = m_base + (blockIdx.y >> 1) * 64;
    kc0 = (blockIdx.y & 1) * (Kc / 2);
    kcN = Kc / 2;
    outp = (blockIdx.y & 1) ? out2 : out;
  } else {
    m0 = blockIdx.y * 64 + m_base;
    kc0 = 0;
    kcN = Kc;
  }

  f4v acc[2][2];
#pragma unroll
  for (int i = 0; i < 2; i++)
#pragma unroll
    for (int j = 0; j < 2; j++) acc[i][j] = (f4v)(0.f);

  const size_t arow = (size_t)(m0 + srow) * Kc + kc0;
  const size_t brow = ((size_t)b * PROWS + t0 + 1 + srow) * Kc + kc0;
  for (int kc = 0; kc < kcN; kc += 32) {
    *(uint4*)&Ash[srow * 40 + sseg] = *(const uint4*)&Ah[arow + kc + sseg];
    if constexpr (EPI == 3) {
      // fused attn_combine: B row t = t0+srow, cols cc..cc+7 (one head blk)
      const int cc = kc0 + kc + sseg;
      const int hh = cc >> 6, dd = cc & 63;
      const size_t lbi = (size_t)(b * Hz + hh) * Tz + t0 + srow;
      const size_t ob = lbi * KCz + dd;
      float4 qa = *(const float4*)&Ox0[ob];
      float4 qb = *(const float4*)&Ox0[ob + 4];
      float4 ra = *(const float4*)&Ox1[ob];
      float4 rb = *(const float4*)&Ox1[ob + 4];
      float4 sa = *(const float4*)&Ox2[ob];
      float4 sb = *(const float4*)&Ox2[ob + 4];
      float4 ta = *(const float4*)&Ox3[ob];
      float4 tb = *(const float4*)&Ox3[ob + 4];
      const float li = 1.f / (sl0[lbi] + sl1[lbi] + sl2[lbi] + sl3[lbi]);
      float v[8] = {(qa.x + ra.x + sa.x + ta.x) * li,
                    (qa.y + ra.y + sa.y + ta.y) * li,
                    (qa.z + ra.z + sa.z + ta.z) * li,
                    (qa.w + ra.w + sa.w + ta.w) * li,
                    (qb.x + rb.x + sb.x + tb.x) * li,
                    (qb.y + rb.y + sb.y + tb.y) * li,
                    (qb.z + rb.z + sb.z + tb.z) * li,
                    (qb.w + rb.w + sb.w + tb.w) * li};
      u16 hhs[8], lls[8];
#pragma unroll
      for (int e = 0; e < 8; e++) bf_split(v[e], hhs[e], lls[e]);
      *(uint4*)&Bsh[srow * 40 + sseg] = *(uint4*)&hhs[0];
      *(uint4*)&Bsl[srow * 40 + sseg] = *(uint4*)&lls[0];
    } else {
      *(uint4*)&Bsh[srow * 40 + sseg] = *(const uint4*)&Bh[brow + kc + sseg];
      *(uint4*)&Bsl[srow * 40 + sseg] = *(const uint4*)&Bl[brow + kc + sseg];
    }
    __syncthreads();
    bf8v ah[2], bh2[2], bl2[2];
#pragma unroll
    for (int f = 0; f < 2; f++) {
      int ar = (wm * 32 + f * 16 + r) * 40 + qd * 8;
      int br = (wn * 32 + f * 16 + r) * 40 + qd * 8;
      ah[f] = *(bf8v*)&Ash[ar];
      bh2[f] = *(bf8v*)&Bsh[br];
      bl2[f] = *(bf8v*)&Bsl[br];
    }
#pragma unroll
    for (int mf = 0; mf < 2; mf++)
#pragma unroll
      for (int nf = 0; nf < 2; nf++) {
        acc[mf][nf] = MFMA(ah[mf], bh2[nf], acc[mf][nf]);
        acc[mf][nf] = MFMA(ah[mf], bl2[nf], acc[mf][nf]);
      }
    __syncthreads();
  }

  float* Ds = (float*)smraw;
  if constexpr (EPI == 0) {
    const int sel = m0 >> 8;
    const int h = (m0 >> 6) & 3;
    const int bhI = b * Hz + h;
    if (sel < 2) {
#pragma unroll
      for (int mf = 0; mf < 2; mf++)
#pragma unroll
        for (int nf = 0; nf < 2; nf++) {
          int nl = wn * 32 + nf * 16 + r;
          int ml = wm * 32 + mf * 16 + qd * 4;
          *(f4v*)&Ds[nl * 68 + ml] = acc[mf][nf];
        }
      __syncthreads();
      const int row = tid >> 2, p = tid & 3;
      size_t da = ((size_t)bhI * Tz + t0 + row) * KCz + p * 16;
      if (sel == 0) {
        u16 hs[16], ls[16];
#pragma unroll
        for (int jj = 0; jj < 4; jj++) {
          float4 dv = *(float4*)&Ds[row * 68 + p * 16 + jj * 4];
          float4 bb = *(const float4*)&bias[m0 + p * 16 + jj * 4];
          float vv[4] = {(dv.x + bb.x) * 0.125f, (dv.y + bb.y) * 0.125f,
                         (dv.z + bb.z) * 0.125f, (dv.w + bb.w) * 0.125f};
#pragma unroll
          for (int e = 0; e < 4; e++)
            bf_split(vv[e], hs[jj * 4 + e], ls[jj * 4 + e]);
        }
        *(uint4*)&pqh[da] = *(uint4*)&hs[0];
        *(uint4*)&pqh[da + 8] = *(uint4*)&hs[8];
        *(uint4*)&pql[da] = *(uint4*)&ls[0];
        *(uint4*)&pql[da + 8] = *(uint4*)&ls[8];
      } else {
        u16 hs[16];
#pragma unroll
        for (int jj = 0; jj < 4; jj++) {
          float4 dv = *(float4*)&Ds[row * 68 + p * 16 + jj * 4];
          float4 bb = *(const float4*)&bias[m0 + p * 16 + jj * 4];
          hs[jj * 4 + 0] = bf_rne(dv.x + bb.x);
          hs[jj * 4 + 1] = bf_rne(dv.y + bb.y);
          hs[jj * 4 + 2] = bf_rne(dv.z + bb.z);
          hs[jj * 4 + 3] = bf_rne(dv.w + bb.w);
        }
        *(uint4*)&pkh[da] = *(uint4*)&hs[0];
        *(uint4*)&pkh[da + 8] = *(uint4*)&hs[8];
      }
    } else {
#pragma unroll
      for (int mf = 0; mf < 2; mf++)
#pragma unroll
        for (int nf = 0; nf < 2; nf++) {
          int ml = wm * 32 + mf * 16 + qd * 4;
          int nl = wn * 32 + nf * 16 + r;
#pragma unroll
          for (int e = 0; e < 4; e++) Ds[(ml + e) * 68 + nl] = acc[mf][nf][e];
        }
      __syncthreads();
      const int row = tid >> 2, p = tid & 3;
      const float bb = bias[m0 + row];
      u16 hs[16];
#pragma unroll
      for (int jj = 0; jj < 16; jj++)
        hs[jj] = bf_rne(Ds[row * 68 + p * 16 + jj] + bb);
      size_t da = ((size_t)bhI * KCz + row) * Tz + t0 + p * 16;
      *(uint4*)&pvh[da] = *(uint4*)&hs[0];
      *(uint4*)&pvh[da + 8] = *(uint4*)&hs[8];
    }
  } else {
#pragma unroll
    for (int mf = 0; mf < 2; mf++)
#pragma unroll
      for (int nf = 0; nf < 2; nf++) {
        int ml = wm * 32 + mf * 16 + qd * 4;
        int nl = wn * 32 + nf * 16 + r;
#pragma unroll
        for (int e = 0; e < 4; e++) Ds[(ml + e) * 68 + nl] = acc[mf][nf][e];
      }
    __syncthreads();
    const int row = tid >> 2, p = tid & 3;
    size_t oa = ((size_t)b * Cz + (m0 - m_base) + row) * Tz + t0 + p * 16;
#pragma unroll
    for (int jj = 0; jj < 4; jj++)
      *(float4*)&outp[oa + jj * 4] = *(float4*)&Ds[row * 68 + p * 16 + jj * 4];
  }
}

// qkv wrapper: (256,3) -> VGPR<=170, 3 blocks/CU, 768-block grid co-resident.
__global__ __launch_bounds__(256, 3) void qkv_gemm(
    const u16* __restrict__ Ah, const u16* __restrict__ Bh,
    const u16* __restrict__ Bl, const float* __restrict__ bias,
    u16* __restrict__ pqh, u16* __restrict__ pql, u16* __restrict__ pkh,
    u16* __restrict__ pvh, int M, int Kc) {
  __shared__ __align__(16) char smraw[17408];
  gemm_body<0>(Ah, Bh, Bl, bias, nullptr, nullptr, pqh, pql, pkh, pvh,
               nullptr, nullptr, nullptr, nullptr, nullptr, nullptr, nullptr,
               nullptr, M, Kc, 0, smraw);
}

// wo wrapper: unconstrained (register-heavy fused-combine epilogue).
__global__ __launch_bounds__(256) void wo_gemm(
    const u16* __restrict__ Ah, const u16* __restrict__ Bh,
    const u16* __restrict__ Bl, const float* __restrict__ bias,
    float* __restrict__ out, float* __restrict__ out2,
    const float* __restrict__ Ox0, const float* __restrict__ Ox1,
    const float* __restrict__ Ox2, const float* __restrict__ Ox3,
    const float* __restrict__ sl0, const float* __restrict__ sl1,
    const float* __restrict__ sl2, const float* __restrict__ sl3, int M,
    int Kc, int m_base) {
  __shared__ __align__(16) char smraw[17408];
  gemm_body<3>(Ah, Bh, Bl, bias, out, out2, nullptr, nullptr, nullptr,
               nullptr, Ox0, Ox1, Ox2, Ox3, sl0, sl1, sl2, sl3, M, Kc, m_base,
               smraw);
}

// ---------------------------------------------------------------------------
// Conv (K=3) as MFMA GEMM, 64m x 128t tile, 4 waves = 4 t-strips.
// Tap-shared B staging (130 rows once per 32-k chunk); reg-prefetch.
// Halo rows (prow 0 / 1025) zero-predicated in staging.
// EPI 1: conv1: B = xp hi/lo (2-pass); out +bias,relu,mask -> SINGLE bf16
//        hidden (rne), ph only. grid (8, M/64, B).
// EPI 3: conv2: B = hp SINGLE bf16 (1-pass, half the MFMAs); K-split x4
//        -> fp32 partials o0..o3. grid (8, 4*4, B).
// ---------------------------------------------------------------------------
template <int EPI>
__global__ __launch_bounds__(256, 2) void conv_mfma(
    const u16* __restrict__ Ah, const u16* __restrict__ Bh,
    const u16* __restrict__ Bl, const float* __restrict__ bias,
    const float* __restrict__ mask, u16* __restrict__ ph,
    float* __restrict__ o0, float* __restrict__ o1, float* __restrict__ o2,
    float* __restrict__ o3, int M, int Kc) {
  __shared__ __align__(16) char smraw[36480];
  u16* Ash = (u16*)smraw;        // [3][64][40]
  u16* Bsh = Ash + 3 * 64 * 40;  // [132][40] (130 rows used)
  u16* Bsl = Bsh + 132 * 40;     // only used when EPI==1
  const int tid = threadIdx.x;
  const int lane = tid & 63, wn = tid >> 6;  // 4 waves: t-strip wn*32
  const int r = lane & 15, qd = lane >> 4;
  const int t0 = blockIdx.x * 128;
  const int b = blockIdx.z;

  int m0, kc0, kcN;
  float* outp = nullptr;
  if constexpr (EPI == 3) {
    int mt = blockIdx.y >> 2, sp = blockIdx.y & 3;
    m0 = mt * 64;
    kc0 = sp * (Kc / 4);
    kcN = Kc / 4;
    outp = sp == 0 ? o0 : (sp == 1 ? o1 : (sp == 2 ? o2 : o3));
  } else {
    m0 = blockIdx.y * 64;
    kc0 = 0;
    kcN = Kc;
  }

  const int srow = tid >> 2, sseg = (tid & 3) * 8;  // rows 0..63
  const bool btail = tid < 8;                       // B rows 128..129
  const int brow2 = 128 + (tid >> 2);
  const bool h0 = (t0 + srow == 0);
  const bool hT = btail && (t0 + brow2 == PROWS - 1);
  const uint4 z4 = {0u, 0u, 0u, 0u};

  f4v acc[4][2];
#pragma unroll
  for (int i = 0; i < 4; i++)
#pragma unroll
    for (int j = 0; j < 2; j++) acc[i][j] = (f4v)(0.f);

  const size_t abase = (size_t)(m0 + srow) * Kc + kc0 + sseg;
  const size_t bbase = ((size_t)b * PROWS + t0 + srow) * Kc + kc0 + sseg;
  const size_t bbase64 = bbase + (size_t)64 * Kc;
  const size_t bbaseT = ((size_t)b * PROWS + t0 + brow2) * Kc + kc0 + sseg;

  uint4 ar[3], bh0, bh1, bl0, bl1, bht, blt;
  auto LOADR = [&](int kc) {
#pragma unroll
    for (int tp = 0; tp < 3; tp++)
      ar[tp] = *(const uint4*)&Ah[(size_t)tp * M * Kc + abase + kc];
    bh0 = *(const uint4*)&Bh[bbase + kc];
    bh1 = *(const uint4*)&Bh[bbase64 + kc];
    if constexpr (EPI == 1) {
      bl0 = *(const uint4*)&Bl[bbase + kc];
      bl1 = *(const uint4*)&Bl[bbase64 + kc];
    }
    if (h0) {
      bh0 = z4;
      bl0 = z4;
    }
    if (btail) {
      bht = *(const uint4*)&Bh[bbaseT + kc];
      if constexpr (EPI == 1) blt = *(const uint4*)&Bl[bbaseT + kc];
      if (hT) {
        bht = z4;
        blt = z4;
      }
    }
  };

  LOADR(0);
  for (int kc = 0; kc < kcN; kc += 32) {
#pragma unroll
    for (int tp = 0; tp < 3; tp++)
      *(uint4*)&Ash[(tp * 64 + srow) * 40 + sseg] = ar[tp];
    *(uint4*)&Bsh[srow * 40 + sseg] = bh0;
    *(uint4*)&Bsh[(srow + 64) * 40 + sseg] = bh1;
    if constexpr (EPI == 1) {
      *(uint4*)&Bsl[srow * 40 + sseg] = bl0;
      *(uint4*)&Bsl[(srow + 64) * 40 + sseg] = bl1;
    }
    if (btail) {
      *(uint4*)&Bsh[brow2 * 40 + sseg] = bht;
      if constexpr (EPI == 1) *(uint4*)&Bsl[brow2 * 40 + sseg] = blt;
    }
    __syncthreads();
    if (kc + 32 < kcN) LOADR(kc + 32);  // prefetch next chunk
#pragma unroll
    for (int tap = 0; tap < 3; tap++) {
      bf8v ah[4], bh2[2], bl2[2];
#pragma unroll
      for (int mf = 0; mf < 4; mf++)
        ah[mf] = *(bf8v*)&Ash[(tap * 64 + mf * 16 + r) * 40 + qd * 8];
#pragma unroll
      for (int nf = 0; nf < 2; nf++) {
        int br = (wn * 32 + nf * 16 + r + tap) * 40 + qd * 8;
        bh2[nf] = *(bf8v*)&Bsh[br];
        if constexpr (EPI == 1) bl2[nf] = *(bf8v*)&Bsl[br];
      }
#pragma unroll
      for (int mf = 0; mf < 4; mf++)
#pragma unroll
        for (int nf = 0; nf < 2; nf++) {
          acc[mf][nf] = MFMA(ah[mf], bh2[nf], acc[mf][nf]);
          if constexpr (EPI == 1)
            acc[mf][nf] = MFMA(ah[mf], bl2[nf], acc[mf][nf]);
        }
    }
    __syncthreads();
  }

  // acc[mf][nf][e]: m = mf*16 + qd*4 + e, t = wn*32 + nf*16 + r
  if constexpr (EPI == 1) {
    float* Ds = (float*)smraw;  // [t 128][m 68]
#pragma unroll
    for (int mf = 0; mf < 4; mf++)
#pragma unroll
      for (int nf = 0; nf < 2; nf++) {
        int tl = wn * 32 + nf * 16 + r;
        int ml = mf * 16 + qd * 4;
        *(f4v*)&Ds[tl * 68 + ml] = acc[mf][nf];
      }
    __syncthreads();
    const int row = tid >> 1, half = (tid & 1) * 32;
    const int t = t0 + row;
    const float mv = mask[(size_t)b * Tz + t];
    u16 hs[32];
#pragma unroll
    for (int j = 0; j < 32; j += 4) {
      float4 dv = *(float4*)&Ds[row * 68 + half + j];
      float4 bb = *(const float4*)&bias[m0 + half + j];
      hs[j + 0] = bf_rne(fmaxf(dv.x + bb.x, 0.f) * mv);
      hs[j + 1] = bf_rne(fmaxf(dv.y + bb.y, 0.f) * mv);
      hs[j + 2] = bf_rne(fmaxf(dv.z + bb.z, 0.f) * mv);
      hs[j + 3] = bf_rne(fmaxf(dv.w + bb.w, 0.f) * mv);
    }
    size_t da = ((size_t)b * PROWS + t + 1) * M + m0 + half;
#pragma unroll
    for (int j = 0; j < 32; j += 8) *(uint4*)&ph[da + j] = *(uint4*)&hs[j];
  } else {
    float* Ds = (float*)smraw;  // [m 64][t 132]
#pragma unroll
    for (int mf = 0; mf < 4; mf++)
#pragma unroll
      for (int nf = 0; nf < 2; nf++) {
        int ml = mf * 16 + qd * 4;
        int nl = wn * 32 + nf * 16 + r;
#pragma unroll
        for (int e = 0; e < 4; e++) Ds[(ml + e) * 132 + nl] = acc[mf][nf][e];
      }
    __syncthreads();
    const int row = tid >> 2, seg = (tid & 3) * 32;
    size_t oa = ((size_t)b * Cz + m0 + row) * Tz + t0 + seg;
#pragma unroll
    for (int j = 0; j < 8; j++)
      *(float4*)&outp[oa + j * 4] = *(float4*)&Ds[row * 132 + seg + j * 4];
  }
}

// ---------------------------------------------------------------------------
// Barrier-free MFMA flash attention, fixed-max softmax, 32 q-rows/wave,
// j-split x4. Q hi/lo; K,V,er single bf16: S 2-pass, PV 1-pass.
// grid 1024 = 16 bh x 4 splits x 16 i-blocks(64); 128 thr (2 waves).
// ---------------------------------------------------------------------------
__global__ __launch_bounds__(128, 2) void attn_mfma(
    const u16* __restrict__ Qh_, const u16* __restrict__ Ql_,
    const u16* __restrict__ Kh_, const u16* __restrict__ Vh_,
    const float* __restrict__ mask, const u16* __restrict__ erkH,
    const u16* __restrict__ ervH, float* __restrict__ O0,
    float* __restrict__ O1, float* __restrict__ O2, float* __restrict__ O3,
    float* __restrict__ lp0, float* __restrict__ lp1,
    float* __restrict__ lp2, float* __restrict__ lp3) {
  __shared__ __align__(16) char smraw[2][14336];
  const int tid = threadIdx.x;
  const int lane = tid & 63, wid = tid >> 6;
  const int r = lane & 15, qd = lane >> 4;
  const int idx = blockIdx.x;
  const int bh = idx & 15;
  const int split = (idx >> 4) & 3;
  const int i0w = (idx >> 6) * 64 + wid * 32;
  const int b = bh >> 2, h = bh & 3;
  const float* mb = mask + (size_t)b * Tz;
  const size_t qkbase = (size_t)bh * Tz * KCz;
  const size_t vbase = (size_t)bh * KCz * Tz;
  float* Op = split == 0 ? O0 : (split == 1 ? O1 : (split == 2 ? O2 : O3));
  float* lp = split == 0 ? lp0 : (split == 1 ? lp1 : (split == 2 ? lp2 : lp3));
  const int j0beg = split * 256;

  float* rqs = (float*)(smraw[wid]);      // [32][22]
  float* bands = rqs + 704;               // [32][22]
  u16* Pp = (u16*)(smraw[wid] + 5632);    // [32][72]; reused as Os f32

  bf8v qh[2][2], ql[2][2];
#pragma unroll
  for (int rs = 0; rs < 2; rs++) {
    const size_t qrow = qkbase + (size_t)(i0w + rs * 16 + r) * KCz;
#pragma unroll
    for (int ks = 0; ks < 2; ks++) {
      qh[rs][ks] = *(const bf8v*)&Qh_[qrow + ks * 32 + qd * 8];
      ql[rs][ks] = *(const bf8v*)&Ql_[qrow + ks * 32 + qd * 8];
    }
  }
  for (int t = lane; t < 704; t += 64) bands[t] = -1e30f;

#pragma unroll
  for (int rs = 0; rs < 2; rs++) {
    f4v rc[2] = {(f4v)(0.f), (f4v)(0.f)};
#pragma unroll
    for (int nf = 0; nf < 2; nf++)
#pragma unroll
      for (int ks = 0; ks < 2; ks++) {
        bf8v eh = *(const bf8v*)&erkH[(16 * nf + r) * 64 + ks * 32 + qd * 8];
        rc[nf] = MFMA(qh[rs][ks], eh, rc[nf]);
        rc[nf] = MFMA(ql[rs][ks], eh, rc[nf]);
      }
#pragma unroll
    for (int nf = 0; nf < 2; nf++) {
      int rr = 16 * nf + r;
      if (rr < NR) {
#pragma unroll
        for (int e = 0; e < 4; e++)
          rqs[(rs * 16 + 4 * qd + e) * 22 + rr] = rc[nf][e];
      }
    }
  }

  float qm[2][4];
#pragma unroll
  for (int rs = 0; rs < 2; rs++)
#pragma unroll
    for (int e = 0; e < 4; e++) qm[rs][e] = mb[i0w + rs * 16 + 4 * qd + e];

  float lacc[2][4] = {};
  f4v oacc[2][4];
#pragma unroll
  for (int rs = 0; rs < 2; rs++)
#pragma unroll
    for (int nf = 0; nf < 4; nf++) oacc[rs][nf] = (f4v)(0.f);

#pragma unroll 2
  for (int jt = 0; jt < 4; jt++) {
    const int j0 = j0beg + jt * 64;
    bf8v kh[4][2], vh[4][2];
#pragma unroll
    for (int nf = 0; nf < 4; nf++) {
      const size_t kr = qkbase + (size_t)(j0 + 16 * nf + r) * KCz;
      const size_t vr = vbase + (size_t)(16 * nf + r) * Tz + j0;
#pragma unroll
      for (int ks = 0; ks < 2; ks++) {
        kh[nf][ks] = *(const bf8v*)&Kh_[kr + ks * 32 + qd * 8];
        vh[nf][ks] = *(const bf8v*)&Vh_[vr + ks * 32 + qd * 8];
      }
    }
    float km4[4];
#pragma unroll
    for (int nf = 0; nf < 4; nf++) km4[nf] = mb[j0 + 16 * nf + r];

#pragma unroll
    for (int rs = 0; rs < 2; rs++) {
      f4v sa[4];
#pragma unroll
      for (int nf = 0; nf < 4; nf++) sa[nf] = (f4v)(0.f);
#pragma unroll
      for (int nf = 0; nf < 4; nf++)
#pragma unroll
        for (int ks = 0; ks < 2; ks++) {
          sa[nf] = MFMA(qh[rs][ks], kh[nf][ks], sa[nf]);
          sa[nf] = MFMA(ql[rs][ks], kh[nf][ks], sa[nf]);
        }
      const int ibase = i0w + rs * 16;
      const bool diag = (j0 + 63 >= ibase - Wz) && (j0 <= ibase + 15 + Wz);
#pragma unroll
      for (int nf = 0; nf < 4; nf++)
#pragma unroll
        for (int e = 0; e < 4; e++) {
          const int iloc = rs * 16 + 4 * qd + e;
          float s = sa[nf][e];
          if (diag) {
            int dl = (j0 + 16 * nf + r) - (i0w + iloc);
            bool inb = (unsigned)(dl + Wz) <= 2u * Wz;
            if (inb) s += rqs[iloc * 22 + dl + Wz];
            if (qm[rs][e] * km4[nf] == 0.f) s = -1e4f;
            if (inb) bands[iloc * 22 + dl + Wz] = s;
          } else {
            if (qm[rs][e] * km4[nf] == 0.f) s = -1e4f;
          }
          float p = __expf(s - MFIX);
          lacc[rs][e] += p;
          Pp[iloc * 72 + 16 * nf + r] = bf_rne(p);
        }
    }
#pragma unroll
    for (int rs = 0; rs < 2; rs++)
#pragma unroll
      for (int ks = 0; ks < 2; ks++) {
        bf8v Ph = *(bf8v*)&Pp[(rs * 16 + r) * 72 + ks * 32 + qd * 8];
#pragma unroll
        for (int nf = 0; nf < 4; nf++)
          oacc[rs][nf] = MFMA(Ph, vh[nf][ks], oacc[rs][nf]);
      }
  }

  for (int t = lane; t < 32 * 32; t += 64) {
    int i = t >> 5, rr = t & 31;
    float p = (rr < NR) ? __expf(bands[i * 22 + rr] - MFIX) : 0.f;
    Pp[i * 72 + rr] = bf_rne(p);
  }
#pragma unroll
  for (int rs = 0; rs < 2; rs++) {
    bf8v Ph = *(bf8v*)&Pp[(rs * 16 + r) * 72 + qd * 8];
#pragma unroll
    for (int nf = 0; nf < 4; nf++) {
      bf8v eh = *(const bf8v*)&ervH[(16 * nf + r) * 32 + qd * 8];
      oacc[rs][nf] = MFMA(Ph, eh, oacc[rs][nf]);
    }
  }

#pragma unroll
  for (int off = 1; off < 16; off <<= 1)
#pragma unroll
    for (int rs = 0; rs < 2; rs++)
#pragma unroll
      for (int e = 0; e < 4; e++)
        lacc[rs][e] += __shfl_xor(lacc[rs][e], off, 16);
  if (r == 0) {
#pragma unroll
    for (int rs = 0; rs < 2; rs++)
#pragma unroll
      for (int e = 0; e < 4; e++)
        lp[(size_t)bh * Tz + i0w + rs * 16 + 4 * qd + e] = lacc[rs][e];
  }

  float* Os = (float*)Pp;  // [32][68]
#pragma unroll
  for (int rs = 0; rs < 2; rs++)
#pragma unroll
    for (int nf = 0; nf < 4; nf++)
#pragma unroll
      for (int e = 0; e < 4; e++)
        Os[(rs * 16 + 4 * qd + e) * 68 + 16 * nf + r] = oacc[rs][nf][e];
#pragma unroll
  for (int rs = 0; rs < 2; rs++) {
    const float* src = &Os[(rs * 16 + r) * 68 + qd * 16];
    size_t oa = ((size_t)bh * Tz + i0w + rs * 16 + r) * KCz + qd * 16;
#pragma unroll
    for (int jj = 0; jj < 4; jj++)
      *(float4*)&Op[oa + jj * 4] = *(const float4*)&src[jj * 4];
  }
}

// ---------------------------------------------------------------------------
// Fused residual + channel LayerNorm + transpose-pack.
// 8 t-cols/block, grid (128, B) = 512 blocks (2/CU); wave-0 shfl reduce.
// VAR 1 (NP partials, mask): x = LN(x + (sum(parts) + cbias)*mask)  [conv2]
// VAR 2 (NP partials, no mask): x = LN(x + sum(parts) + cbias)      [wo]
// ---------------------------------------------------------------------------
template <int VAR, int NP>
__global__ __launch_bounds__(256) void fused_ln(
    float* __restrict__ x, const float* __restrict__ y,
    const float* __restrict__ p1, const float* __restrict__ p2,
    const float* __restrict__ p3, const float* __restrict__ cbias,
    const float* __restrict__ g, const float* __restrict__ bb,
    const float* __restrict__ mask, u16* __restrict__ dhi,
    u16* __restrict__ dlo) {
  __shared__ float L[256 * 9];
  __shared__ float red[32][8], red2[32][8];
  __shared__ float ms[8], rs[8];
  const int tid = threadIdx.x;
  const int t0 = blockIdx.x * 8, b = blockIdx.y;
  const int tl = tid & 7, grp = tid >> 3;  // 32 c-groups of 8 t-cols
  const size_t bx = (size_t)b * Cz * TS + PADF + t0 + tl;
  const size_t by = (size_t)b * Cz * Tz + t0 + tl;
  const float mv = mask[(size_t)b * Tz + t0 + tl];
  float s = 0.f, sq = 0.f;
#pragma unroll
  for (int i = 0; i < 8; i++) {
    int c = grp + i * 32;
    float add = y[by + (size_t)c * Tz] + p1[by + (size_t)c * Tz] + cbias[c];
    if constexpr (NP == 4)
      add += p2[by + (size_t)c * Tz] + p3[by + (size_t)c * Tz];
    if constexpr (VAR == 1) add *= mv;
    float v = x[bx + (size_t)c * TS] + add;
    L[c * 9 + tl] = v;
    s += v;
    sq += v * v;
  }
  red[grp][tl] = s;
  red2[grp][tl] = sq;
  __syncthreads();
  if (tid < 64) {
    const int j = tid >> 3, tt = tid & 7;
    float su = red[j][tt] + red[j + 8][tt] + red[j + 16][tt] + red[j + 24][tt];
    float sqq =
        red2[j][tt] + red2[j + 8][tt] + red2[j + 16][tt] + red2[j + 24][tt];
    su += __shfl_xor(su, 8);
    su += __shfl_xor(su, 16);
    su += __shfl_xor(su, 32);
    sqq += __shfl_xor(sqq, 8);
    sqq += __shfl_xor(sqq, 16);
    sqq += __shfl_xor(sqq, 32);
    if (j == 0) {
      float m = su * (1.f / Cz);
      ms[tt] = m;
      rs[tt] = rsqrtf(sqq * (1.f / Cz) - m * m + 1e-5f);
    }
  }
  __syncthreads();
  const float m = ms[tl], r = rs[tl];
#pragma unroll
  for (int i = 0; i < 8; i++) {
    int c = grp + i * 32;
    float v = (L[c * 9 + tl] - m) * r * g[c] + bb[c];
    x[bx + (size_t)c * TS] = v;
    L[c * 9 + tl] = v * mv;
  }
  __syncthreads();
  const int tt = tid & 7, p = tid >> 3;  // 32 segs of 8 channels
  u16 hs[8], ls[8];
#pragma unroll
  for (int j = 0; j < 8; j++)
    bf_split(L[(p * 8 + j) * 9 + tt], hs[j], ls[j]);
  size_t da = ((size_t)b * PROWS + t0 + tt + 1) * Cz + p * 8;
  *(uint4*)&dhi[da] = *(uint4*)&hs[0];
  *(uint4*)&dlo[da] = *(uint4*)&ls[0];
}

// ---------------------------------------------------------------------------
extern "C" void kernel_launch(void* const* d_in, const int* in_sizes, int n_in,
                              void* d_out, int out_size, void* d_ws,
                              size_t ws_size, hipStream_t stream) {
  const float* x = (const float*)d_in[0];
  const float* xm = (const float*)d_in[1];
  const float* wq = (const float*)d_in[2];
  const float* bq = (const float*)d_in[3];
  const float* wk = (const float*)d_in[4];
  const float* bk = (const float*)d_in[5];
  const float* wv = (const float*)d_in[6];
  const float* bv = (const float*)d_in[7];
  const float* wo = (const float*)d_in[8];
  const float* bo = (const float*)d_in[9];
  const float* erk = (const float*)d_in[10];
  const float* erv = (const float*)d_in[11];
  const float* g1 = (const float*)d_in[12];
  const float* b1 = (const float*)d_in[13];
  const float* fw1 = (const float*)d_in[14];
  const float* fb1 = (const float*)d_in[15];
  const float* fw2 = (const float*)d_in[16];
  const float* fb2 = (const float*)d_in[17];
  const float* g2 = (const float*)d_in[18];
  const float* b2 = (const float*)d_in[19];

  const size_t NBC = (size_t)Bz * Cz * Tz;       // 1,048,576
  const size_t XBN = (size_t)Bz * Cz * TS;       // 1,056,768
  const size_t HP = (size_t)Bz * PROWS * FCz;    // 4,202,496 u16/array
  const size_t XP = (size_t)Bz * PROWS * Cz;     // 1,050,624 u16/array
  const size_t QS = (size_t)Bz * Hz * Tz * KCz;  // 1,048,576 u16/array

  float* ws = (float*)d_ws;
  float* xb = ws;
  float* yb = xb + XBN;   // attn partial O0
  float* p1 = yb + NBC;   // O1
  float* p2 = p1 + NBC;   // O2
  float* p3 = p2 + NBC;   // O3
  float* unf = p3 + NBC;  // union: Q/K/V packed OR wo outputs OR FFN hidden
  u16* hpH = (u16*)unf;   // single-bf16 hidden (hpL slot unused now)
  u16* Qh = (u16*)unf;
  u16* Ql = Qh + QS;
  u16* Kh = Ql + QS;
  u16* Vh = Kh + QS;
  float* wo0 = unf;        // wo k-half 0 output (over dead Q/Ql, 4 MB)
  float* wo1 = unf + NBC;  // wo k-half 1 output (over dead Kh/Vh, 4 MB)
  float* xpf = unf + HP;
  u16* xpH = (u16*)xpf;
  u16* xpL = xpH + XP;
  float* qwf = xpf + XP;
  u16* qwAll = (u16*)qwf;  // 6 x 262144 u16
  float* w1f = qwf + 786432;
  u16* w1All = (u16*)w1f;  // 6 x 786432 u16
  float* w2f = w1f + 2359296;
  u16* w2All = (u16*)w2f;  // 6 x 786432 u16
  float* erf = w2f + 2359296;
  u16* ekAll = (u16*)erf;      // 6 x 2048 u16
  u16* evAll = ekAll + 12288;  // 6 x 2048 u16
  float* pbAll = erf + 12288;  // 6 x 1024 f32
  float* lb0 = pbAll + 6144;
  float* lb1 = lb0 + 16384;
  float* lb2 = lb1 + 16384;
  float* lb3 = lb2 + 16384;

  const int ntot = (int)NBC;
  pack_all<<<dim3(6 * 7184), 256, 0, stream>>>(
      wq, wk, wv, wo, bq, bk, bv, bo, erk, erv, fw1, fw2, qwAll, pbAll, ekAll,
      evAll, w1All, w2All);
  tpack<<<dim3(16, 4, 4), 256, 0, stream>>>(x, xm, xb, xpH, xpL, Cz);

  for (int l = 0; l < Lz; l++) {
    qkv_gemm<<<dim3(16, 12, 4), 256, 0, stream>>>(
        qwAll + (size_t)l * 262144, xpH, xpL, pbAll + l * 1024, Qh, Ql, Kh,
        Vh, 1024, Cz);
    attn_mfma<<<dim3(1024), 128, 0, stream>>>(
        Qh, Ql, Kh, Vh, xm, ekAll + l * 2048, evAll + l * 2048, yb, p1, p2,
        p3, lb0, lb1, lb2, lb3);
    // wo GEMM with fused combine: B staged from O0..3 + l0..3 (Q/K/V dead).
    wo_gemm<<<dim3(16, 8, 4), 256, 0, stream>>>(
        qwAll + (size_t)l * 262144, xpH, xpL, pbAll + l * 1024, wo0, wo1, yb,
        p1, p2, p3, lb0, lb1, lb2, lb3, 1024, Cz, 768);
    fused_ln<2, 2><<<dim3(128, 4), 256, 0, stream>>>(
        xb, wo0, wo1, nullptr, nullptr, bo + l * Cz, g1 + l * Cz, b1 + l * Cz,
        xm, xpH, xpL);
    conv_mfma<1><<<dim3(8, 16, 4), 256, 0, stream>>>(
        w1All + (size_t)l * 786432, xpH, xpL, fb1 + l * FCz, xm, hpH,
        nullptr, nullptr, nullptr, nullptr, FCz, Cz);
    conv_mfma<3><<<dim3(8, 16, 4), 256, 0, stream>>>(
        w2All + (size_t)l * 786432, hpH, hpH, nullptr, xm, nullptr, yb, p1,
        p2, p3, Cz, FCz);
    fused_ln<1, 4><<<dim3(128, 4), 256, 0, stream>>>(
        xb, yb, p1, p2, p3, fb2 + l * Cz, g2 + l * Cz, b2 + l * Cz, xm, xpH,
        xpL);
  }
  mask_out<<<dim3((ntot + 255) / 256), 256, 0, stream>>>(xb, xm,
                                                         (float*)d_out);
}

// Round 12
// 912.627 us; speedup vs baseline: 1.0843x; 1.0244x over previous
//
#include <hip/hip_runtime.h>

// Encoder: L=6 layers of (rel-pos attention + channel-LN + K=3 conv FFN + LN)
// B=4, C=256, T=1024, H=4, KC=64, FC=1024, W=10, fp32 I/O.
// ROUND 12: spend more absmax headroom (0.031 unchanged after R11; thr 0.084)
// -- conv1's B (post-LN x) and wo's B (combined attn out) go SINGLE bf16
// 1-pass (halves conv1 MFMA -- the largest consumer -- and wo MFMA).
// qkv keeps hi/lo B (score path precision). FFN hidden single (R11).
// Base: qkv launch_bounds(256,3); wo fused attn-combine B-staging; tpack
// fused mask_in; halo-predicated convs; tap-shared conv B staging.

#define Lz 6
#define Cz 256
#define FCz 1024
#define Hz 4
#define Wz 10
#define Bz 4
#define Tz 1024
#define KCz 64
#define NR 21
#define TS 1032
#define PADF 4
#define PROWS 1026
#define MFIX 8.0f

typedef unsigned short u16;
typedef unsigned int u32;
typedef __attribute__((ext_vector_type(8))) short bf8v;
typedef __attribute__((ext_vector_type(4))) float f4v;

#define MFMA(a, b, c) __builtin_amdgcn_mfma_f32_16x16x32_bf16(a, b, c, 0, 0, 0)

__device__ inline void bf_split(float v, u16& hi, u16& lo) {
  unsigned u = __float_as_uint(v);
  unsigned hr = (u + 0x7FFFu + ((u >> 16) & 1u)) >> 16;
  float rem = v - __uint_as_float(hr << 16);
  unsigned u2 = __float_as_uint(rem);
  unsigned lr = (u2 + 0x7FFFu + ((u2 >> 16) & 1u)) >> 16;
  hi = (u16)hr;
  lo = (u16)lr;
}

__device__ inline u16 bf_rne(float v) {
  u32 u = __float_as_uint(v);
  return (u16)((u + 0x7FFFu + ((u >> 16) & 1u)) >> 16);
}

// ---------------------------------------------------------------------------
__global__ __launch_bounds__(256) void mask_out(const float* __restrict__ xp,
                                                const float* __restrict__ m,
                                                float* __restrict__ out) {
  int id = blockIdx.x * 256 + threadIdx.x;
  if (id < Bz * Cz * Tz) {
    int t = id & (Tz - 1), row = id >> 10, b = id >> 18;
    out[id] = xp[(size_t)row * TS + PADF + t] * m[b * Tz + t];
  }
}

// ---------------------------------------------------------------------------
// Fused mask_in + transpose-pack: reads x [b][c][Tz] + mask, writes
// xb = x*m (TS-padded layout) AND packed hi/lo [b][1026][Cd] of (x*m)*m.
// ---------------------------------------------------------------------------
__global__ __launch_bounds__(256) void tpack(const float* __restrict__ xsrc,
                                             const float* __restrict__ mask,
                                             float* __restrict__ xb,
                                             u16* __restrict__ dhi,
                                             u16* __restrict__ dlo, int Cd) {
  __shared__ float L[64 * 68];
  const int tid = threadIdx.x;
  const int t0 = blockIdx.x * 64, c0 = blockIdx.y * 64, b = blockIdx.z;
#pragma unroll
  for (int i = 0; i < 16; i++) {
    int id = tid + 256 * i;
    int cc = id >> 6, tt = id & 63;
    float mv = mask[(size_t)b * Tz + t0 + tt];
    float v = xsrc[((size_t)(b * Cz + c0 + cc)) * Tz + t0 + tt] * mv;
    xb[((size_t)(b * Cz + c0 + cc)) * TS + PADF + t0 + tt] = v;
    L[cc * 68 + tt] = v;
  }
  __syncthreads();
  const int tt = tid >> 2, p = tid & 3;
  float mv = mask[(size_t)b * Tz + t0 + tt];
  u16 hs[16], ls[16];
#pragma unroll
  for (int j = 0; j < 16; j++) {
    float v = L[(p * 16 + j) * 68 + tt] * mv;
    bf_split(v, hs[j], ls[j]);
  }
  size_t da = ((size_t)b * PROWS + t0 + tt + 1) * Cd + c0 + p * 16;
  *(uint4*)&dhi[da] = *(uint4*)&hs[0];
  *(uint4*)&dhi[da + 8] = *(uint4*)&hs[8];
  *(uint4*)&dlo[da] = *(uint4*)&ls[0];
  *(uint4*)&dlo[da + 8] = *(uint4*)&ls[8];
}

// ---------------------------------------------------------------------------
// Pack ALL layers' weights in one launch. grid = 6 * 7184 blocks.
// ---------------------------------------------------------------------------
__global__ __launch_bounds__(256) void pack_all(
    const float* __restrict__ wq, const float* __restrict__ wk,
    const float* __restrict__ wv, const float* __restrict__ wo_,
    const float* __restrict__ bq, const float* __restrict__ bk,
    const float* __restrict__ bv, const float* __restrict__ bo,
    const float* __restrict__ erk, const float* __restrict__ erv,
    const float* __restrict__ fw1, const float* __restrict__ fw2,
    u16* __restrict__ qwAll, float* __restrict__ pbAll,
    u16* __restrict__ ekAll, u16* __restrict__ evAll,
    u16* __restrict__ w1All, u16* __restrict__ w2All) {
  const int blk = blockIdx.x, tid = threadIdx.x;
  const int layer = blk / 7184;
  const int bl = blk % 7184;
  if (bl < 1024) {
    int id = bl * 256 + tid;
    int o = id >> 8, c = id & 255;
    int sel = o >> 8;
    const size_t wof = (size_t)layer * Cz * Cz;
    const float* w = sel == 0 ? wq + wof
                              : (sel == 1 ? wk + wof
                                          : (sel == 2 ? wv + wof : wo_ + wof));
    qwAll[(size_t)layer * 262144 + id] = bf_rne(w[((o & 255) << 8) + c]);
    if (id < 1024) {
      int s2 = id >> 8;
      const float* bs = s2 == 0 ? bq : (s2 == 1 ? bk : (s2 == 2 ? bv : bo));
      pbAll[layer * 1024 + id] = bs[layer * Cz + (id & 255)];
    }
  } else if (bl < 1040) {
    int id = (bl - 1024) * 256 + tid;
    if (id < 2048) {
      int rr = id >> 6, d = id & 63;
      ekAll[layer * 2048 + id] =
          bf_rne((rr < NR) ? erk[(size_t)layer * NR * KCz + rr * KCz + d]
                           : 0.f);
    } else {
      int id2 = id - 2048;
      int d = id2 >> 5, rr = id2 & 31;
      evAll[layer * 2048 + id2] =
          bf_rne((rr < NR) ? erv[(size_t)layer * NR * KCz + rr * KCz + d]
                           : 0.f);
    }
  } else if (bl < 4112) {
    int id = (bl - 1040) * 256 + tid;
    int c = id % Cz;
    int rest = id / Cz;
    int o = rest % FCz, tap = rest / FCz;
    w1All[(size_t)layer * 786432 + id] =
        bf_rne(fw1[(size_t)layer * FCz * Cz * 3 + ((size_t)o * Cz + c) * 3 +
                   tap]);
  } else {
    int id = (bl - 4112) * 256 + tid;
    int c = id % FCz;
    int rest = id / FCz;
    int o = rest % Cz, tap = rest / Cz;
    w2All[(size_t)layer * 786432 + id] =
        bf_rne(fw2[(size_t)layer * Cz * FCz * 3 + ((size_t)o * FCz + c) * 3 +
                   tap]);
  }
}

// ---------------------------------------------------------------------------
// MFMA GEMM body (A = single bf16 weights). Tile 64x64.
// EPI 0: B = hi/lo packed acts (2-pass); qkv -> Q hi/lo (x0.125), K, V.
// EPI 3: wo, K-split-2; B staged SINGLE bf16 from attn partials (fused
//        combine, 1-pass -- spend absmax headroom).
// ---------------------------------------------------------------------------
template <int EPI>
static __device__ __forceinline__ void gemm_body(
    const u16* __restrict__ Ah, const u16* __restrict__ Bh,
    const u16* __restrict__ Bl, const float* __restrict__ bias,
    float* __restrict__ out, float* __restrict__ out2,
    u16* __restrict__ pqh, u16* __restrict__ pql, u16* __restrict__ pkh,
    u16* __restrict__ pvh, const float* __restrict__ Ox0,
    const float* __restrict__ Ox1, const float* __restrict__ Ox2,
    const float* __restrict__ Ox3, const float* __restrict__ sl0,
    const float* __restrict__ sl1, const float* __restrict__ sl2,
    const float* __restrict__ sl3, int M, int Kc, int m_base, char* smraw) {
  u16* Ash = (u16*)smraw;
  u16* Bsh = Ash + 2560;
  u16* Bsl = Bsh + 2560;  // unused when EPI==3
  const int tid = threadIdx.x;
  const int lane = tid & 63, wid = tid >> 6;
  const int wm = wid & 1, wn = wid >> 1;
  const int r = lane & 15, qd = lane >> 4;
  const int t0 = blockIdx.x * 64;
  const int b = blockIdx.z;
  const int srow = tid >> 2, sseg = (tid & 3) * 8;

  int m0, kc0, kcN;
  float* outp = out;
  if constexpr (EPI == 3) {
    m0 = m_base + (blockIdx.y >> 1) * 64;
    kc0 = (blockIdx.y & 1) * (Kc / 2);
    kcN = Kc / 2;
    outp = (blockIdx.y & 1) ? out2 : out;
  } else {
    m0 = blockIdx.y * 64 + m_base;
    kc0 = 0;
    kcN = Kc;
  }

  f4v acc[2][2];
#pragma unroll
  for (int i = 0; i < 2; i++)
#pragma unroll
    for (int j = 0; j < 2; j++) acc[i][j] = (f4v)(0.f);

  const size_t arow = (size_t)(m0 + srow) * Kc + kc0;
  const size_t brow = ((size_t)b * PROWS + t0 + 1 + srow) * Kc + kc0;
  for (int kc = 0; kc < kcN; kc += 32) {
    *(uint4*)&Ash[srow * 40 + sseg] = *(const uint4*)&Ah[arow + kc + sseg];
    if constexpr (EPI == 3) {
      // fused attn_combine (single bf16): row t = t0+srow, cols cc..cc+7
      const int cc = kc0 + kc + sseg;
      const int hh = cc >> 6, dd = cc & 63;
      const size_t lbi = (size_t)(b * Hz + hh) * Tz + t0 + srow;
      const size_t ob = lbi * KCz + dd;
      float4 qa = *(const float4*)&Ox0[ob];
      float4 qb = *(const float4*)&Ox0[ob + 4];
      float4 ra = *(const float4*)&Ox1[ob];
      float4 rb = *(const float4*)&Ox1[ob + 4];
      float4 sa = *(const float4*)&Ox2[ob];
      float4 sb = *(const float4*)&Ox2[ob + 4];
      float4 ta = *(const float4*)&Ox3[ob];
      float4 tb = *(const float4*)&Ox3[ob + 4];
      const float li = 1.f / (sl0[lbi] + sl1[lbi] + sl2[lbi] + sl3[lbi]);
      u16 hhs[8];
      hhs[0] = bf_rne((qa.x + ra.x + sa.x + ta.x) * li);
      hhs[1] = bf_rne((qa.y + ra.y + sa.y + ta.y) * li);
      hhs[2] = bf_rne((qa.z + ra.z + sa.z + ta.z) * li);
      hhs[3] = bf_rne((qa.w + ra.w + sa.w + ta.w) * li);
      hhs[4] = bf_rne((qb.x + rb.x + sb.x + tb.x) * li);
      hhs[5] = bf_rne((qb.y + rb.y + sb.y + tb.y) * li);
      hhs[6] = bf_rne((qb.z + rb.z + sb.z + tb.z) * li);
      hhs[7] = bf_rne((qb.w + rb.w + sb.w + tb.w) * li);
      *(uint4*)&Bsh[srow * 40 + sseg] = *(uint4*)&hhs[0];
    } else {
      *(uint4*)&Bsh[srow * 40 + sseg] = *(const uint4*)&Bh[brow + kc + sseg];
      *(uint4*)&Bsl[srow * 40 + sseg] = *(const uint4*)&Bl[brow + kc + sseg];
    }
    __syncthreads();
    bf8v ah[2], bh2[2], bl2[2];
#pragma unroll
    for (int f = 0; f < 2; f++) {
      int ar = (wm * 32 + f * 16 + r) * 40 + qd * 8;
      int br = (wn * 32 + f * 16 + r) * 40 + qd * 8;
      ah[f] = *(bf8v*)&Ash[ar];
      bh2[f] = *(bf8v*)&Bsh[br];
      if constexpr (EPI == 0) bl2[f] = *(bf8v*)&Bsl[br];
    }
#pragma unroll
    for (int mf = 0; mf < 2; mf++)
#pragma unroll
      for (int nf = 0; nf < 2; nf++) {
        acc[mf][nf] = MFMA(ah[mf], bh2[nf], acc[mf][nf]);
        if constexpr (EPI == 0)
          acc[mf][nf] = MFMA(ah[mf], bl2[nf], acc[mf][nf]);
      }
    __syncthreads();
  }

  float* Ds = (float*)smraw;
  if constexpr (EPI == 0) {
    const int sel = m0 >> 8;
    const int h = (m0 >> 6) & 3;
    const int bhI = b * Hz + h;
    if (sel < 2) {
#pragma unroll
      for (int mf = 0; mf < 2; mf++)
#pragma unroll
        for (int nf = 0; nf < 2; nf++) {
          int nl = wn * 32 + nf * 16 + r;
          int ml = wm * 32 + mf * 16 + qd * 4;
          *(f4v*)&Ds[nl * 68 + ml] = acc[mf][nf];
        }
      __syncthreads();
      const int row = tid >> 2, p = tid & 3;
      size_t da = ((size_t)bhI * Tz + t0 + row) * KCz + p * 16;
      if (sel == 0) {
        u16 hs[16], ls[16];
#pragma unroll
        for (int jj = 0; jj < 4; jj++) {
          float4 dv = *(float4*)&Ds[row * 68 + p * 16 + jj * 4];
          float4 bb = *(const float4*)&bias[m0 + p * 16 + jj * 4];
          float vv[4] = {(dv.x + bb.x) * 0.125f, (dv.y + bb.y) * 0.125f,
                         (dv.z + bb.z) * 0.125f, (dv.w + bb.w) * 0.125f};
#pragma unroll
          for (int e = 0; e < 4; e++)
            bf_split(vv[e], hs[jj * 4 + e], ls[jj * 4 + e]);
        }
        *(uint4*)&pqh[da] = *(uint4*)&hs[0];
        *(uint4*)&pqh[da + 8] = *(uint4*)&hs[8];
        *(uint4*)&pql[da] = *(uint4*)&ls[0];
        *(uint4*)&pql[da + 8] = *(uint4*)&ls[8];
      } else {
        u16 hs[16];
#pragma unroll
        for (int jj = 0; jj < 4; jj++) {
          float4 dv = *(float4*)&Ds[row * 68 + p * 16 + jj * 4];
          float4 bb = *(const float4*)&bias[m0 + p * 16 + jj * 4];
          hs[jj * 4 + 0] = bf_rne(dv.x + bb.x);
          hs[jj * 4 + 1] = bf_rne(dv.y + bb.y);
          hs[jj * 4 + 2] = bf_rne(dv.z + bb.z);
          hs[jj * 4 + 3] = bf_rne(dv.w + bb.w);
        }
        *(uint4*)&pkh[da] = *(uint4*)&hs[0];
        *(uint4*)&pkh[da + 8] = *(uint4*)&hs[8];
      }
    } else {
#pragma unroll
      for (int mf = 0; mf < 2; mf++)
#pragma unroll
        for (int nf = 0; nf < 2; nf++) {
          int ml = wm * 32 + mf * 16 + qd * 4;
          int nl = wn * 32 + nf * 16 + r;
#pragma unroll
          for (int e = 0; e < 4; e++) Ds[(ml + e) * 68 + nl] = acc[mf][nf][e];
        }
      __syncthreads();
      const int row = tid >> 2, p = tid & 3;
      const float bb = bias[m0 + row];
      u16 hs[16];
#pragma unroll
      for (int jj = 0; jj < 16; jj++)
        hs[jj] = bf_rne(Ds[row * 68 + p * 16 + jj] + bb);
      size_t da = ((size_t)bhI * KCz + row) * Tz + t0 + p * 16;
      *(uint4*)&pvh[da] = *(uint4*)&hs[0];
      *(uint4*)&pvh[da + 8] = *(uint4*)&hs[8];
    }
  } else {
#pragma unroll
    for (int mf = 0; mf < 2; mf++)
#pragma unroll
      for (int nf = 0; nf < 2; nf++) {
        int ml = wm * 32 + mf * 16 + qd * 4;
        int nl = wn * 32 + nf * 16 + r;
#pragma unroll
        for (int e = 0; e < 4; e++) Ds[(ml + e) * 68 + nl] = acc[mf][nf][e];
      }
    __syncthreads();
    const int row = tid >> 2, p = tid & 3;
    size_t oa = ((size_t)b * Cz + (m0 - m_base) + row) * Tz + t0 + p * 16;
#pragma unroll
    for (int jj = 0; jj < 4; jj++)
      *(float4*)&outp[oa + jj * 4] = *(float4*)&Ds[row * 68 + p * 16 + jj * 4];
  }
}

// qkv wrapper: (256,3) -> VGPR<=170, 3 blocks/CU, 768-block grid co-resident.
__global__ __launch_bounds__(256, 3) void qkv_gemm(
    const u16* __restrict__ Ah, const u16* __restrict__ Bh,
    const u16* __restrict__ Bl, const float* __restrict__ bias,
    u16* __restrict__ pqh, u16* __restrict__ pql, u16* __restrict__ pkh,
    u16* __restrict__ pvh, int M, int Kc) {
  __shared__ __align__(16) char smraw[17408];
  gemm_body<0>(Ah, Bh, Bl, bias, nullptr, nullptr, pqh, pql, pkh, pvh,
               nullptr, nullptr, nullptr, nullptr, nullptr, nullptr, nullptr,
               nullptr, M, Kc, 0, smraw);
}

// wo wrapper: unconstrained (fused-combine epilogue).
__global__ __launch_bounds__(256) void wo_gemm(
    const u16* __restrict__ Ah, const u16* __restrict__ Bh,
    const u16* __restrict__ Bl, const float* __restrict__ bias,
    float* __restrict__ out, float* __restrict__ out2,
    const float* __restrict__ Ox0, const float* __restrict__ Ox1,
    const float* __restrict__ Ox2, const float* __restrict__ Ox3,
    const float* __restrict__ sl0, const float* __restrict__ sl1,
    const float* __restrict__ sl2, const float* __restrict__ sl3, int M,
    int Kc, int m_base) {
  __shared__ __align__(16) char smraw[17408];
  gemm_body<3>(Ah, Bh, Bl, bias, out, out2, nullptr, nullptr, nullptr,
               nullptr, Ox0, Ox1, Ox2, Ox3, sl0, sl1, sl2, sl3, M, Kc, m_base,
               smraw);
}

// ---------------------------------------------------------------------------
// Conv (K=3) as MFMA GEMM, 64m x 128t tile, 4 waves = 4 t-strips.
// SINGLE-bf16 B both convs now (spend absmax headroom): 1-pass MFMA.
// Tap-shared B staging (130 rows once per 32-k chunk); reg-prefetch.
// Halo rows (prow 0 / 1025) zero-predicated in staging.
// EPI 1: conv1: B = xp single; out +bias,relu,mask -> single bf16 hidden.
// EPI 3: conv2: B = hp single; K-split x4 -> fp32 partials o0..o3.
// ---------------------------------------------------------------------------
template <int EPI>
__global__ __launch_bounds__(256, 2) void conv_mfma(
    const u16* __restrict__ Ah, const u16* __restrict__ Bh,
    const float* __restrict__ bias, const float* __restrict__ mask,
    u16* __restrict__ ph, float* __restrict__ o0, float* __restrict__ o1,
    float* __restrict__ o2, float* __restrict__ o3, int M, int Kc) {
  __shared__ __align__(16) char smraw[36480];
  u16* Ash = (u16*)smraw;        // [3][64][40]
  u16* Bsh = Ash + 3 * 64 * 40;  // [132][40] (130 rows used)
  const int tid = threadIdx.x;
  const int lane = tid & 63, wn = tid >> 6;  // 4 waves: t-strip wn*32
  const int r = lane & 15, qd = lane >> 4;
  const int t0 = blockIdx.x * 128;
  const int b = blockIdx.z;

  int m0, kc0, kcN;
  float* outp = nullptr;
  if constexpr (EPI == 3) {
    int mt = blockIdx.y >> 2, sp = blockIdx.y & 3;
    m0 = mt * 64;
    kc0 = sp * (Kc / 4);
    kcN = Kc / 4;
    outp = sp == 0 ? o0 : (sp == 1 ? o1 : (sp == 2 ? o2 : o3));
  } else {
    m0 = blockIdx.y * 64;
    kc0 = 0;
    kcN = Kc;
  }

  const int srow = tid >> 2, sseg = (tid & 3) * 8;  // rows 0..63
  const bool btail = tid < 8;                       // B rows 128..129
  const int brow2 = 128 + (tid >> 2);
  const bool h0 = (t0 + srow == 0);
  const bool hT = btail && (t0 + brow2 == PROWS - 1);
  const uint4 z4 = {0u, 0u, 0u, 0u};

  f4v acc[4][2];
#pragma unroll
  for (int i = 0; i < 4; i++)
#pragma unroll
    for (int j = 0; j < 2; j++) acc[i][j] = (f4v)(0.f);

  const size_t abase = (size_t)(m0 + srow) * Kc + kc0 + sseg;
  const size_t bbase = ((size_t)b * PROWS + t0 + srow) * Kc + kc0 + sseg;
  const size_t bbase64 = bbase + (size_t)64 * Kc;
  const size_t bbaseT = ((size_t)b * PROWS + t0 + brow2) * Kc + kc0 + sseg;

  uint4 ar[3], bh0, bh1, bht;
  auto LOADR = [&](int kc) {
#pragma unroll
    for (int tp = 0; tp < 3; tp++)
      ar[tp] = *(const uint4*)&Ah[(size_t)tp * M * Kc + abase + kc];
    bh0 = *(const uint4*)&Bh[bbase + kc];
    bh1 = *(const uint4*)&Bh[bbase64 + kc];
    if (h0) bh0 = z4;
    if (btail) {
      bht = *(const uint4*)&Bh[bbaseT + kc];
      if (hT) bht = z4;
    }
  };

  LOADR(0);
  for (int kc = 0; kc < kcN; kc += 32) {
#pragma unroll
    for (int tp = 0; tp < 3; tp++)
      *(uint4*)&Ash[(tp * 64 + srow) * 40 + sseg] = ar[tp];
    *(uint4*)&Bsh[srow * 40 + sseg] = bh0;
    *(uint4*)&Bsh[(srow + 64) * 40 + sseg] = bh1;
    if (btail) *(uint4*)&Bsh[brow2 * 40 + sseg] = bht;
    __syncthreads();
    if (kc + 32 < kcN) LOADR(kc + 32);  // prefetch next chunk
#pragma unroll
    for (int tap = 0; tap < 3; tap++) {
      bf8v ah[4], bh2[2];
#pragma unroll
      for (int mf = 0; mf < 4; mf++)
        ah[mf] = *(bf8v*)&Ash[(tap * 64 + mf * 16 + r) * 40 + qd * 8];
#pragma unroll
      for (int nf = 0; nf < 2; nf++)
        bh2[nf] = *(bf8v*)&Bsh[(wn * 32 + nf * 16 + r + tap) * 40 + qd * 8];
#pragma unroll
      for (int mf = 0; mf < 4; mf++)
#pragma unroll
        for (int nf = 0; nf < 2; nf++)
          acc[mf][nf] = MFMA(ah[mf], bh2[nf], acc[mf][nf]);
    }
    __syncthreads();
  }

  // acc[mf][nf][e]: m = mf*16 + qd*4 + e, t = wn*32 + nf*16 + r
  if constexpr (EPI == 1) {
    float* Ds = (float*)smraw;  // [t 128][m 68]
#pragma unroll
    for (int mf = 0; mf < 4; mf++)
#pragma unroll
      for (int nf = 0; nf < 2; nf++) {
        int tl = wn * 32 + nf * 16 + r;
        int ml = mf * 16 + qd * 4;
        *(f4v*)&Ds[tl * 68 + ml] = acc[mf][nf];
      }
    __syncthreads();
    const int row = tid >> 1, half = (tid & 1) * 32;
    const int t = t0 + row;
    const float mv = mask[(size_t)b * Tz + t];
    u16 hs[32];
#pragma unroll
    for (int j = 0; j < 32; j += 4) {
      float4 dv = *(float4*)&Ds[row * 68 + half + j];
      float4 bb = *(const float4*)&bias[m0 + half + j];
      hs[j + 0] = bf_rne(fmaxf(dv.x + bb.x, 0.f) * mv);
      hs[j + 1] = bf_rne(fmaxf(dv.y + bb.y, 0.f) * mv);
      hs[j + 2] = bf_rne(fmaxf(dv.z + bb.z, 0.f) * mv);
      hs[j + 3] = bf_rne(fmaxf(dv.w + bb.w, 0.f) * mv);
    }
    size_t da = ((size_t)b * PROWS + t + 1) * M + m0 + half;
#pragma unroll
    for (int j = 0; j < 32; j += 8) *(uint4*)&ph[da + j] = *(uint4*)&hs[j];
  } else {
    float* Ds = (float*)smraw;  // [m 64][t 132]
#pragma unroll
    for (int mf = 0; mf < 4; mf++)
#pragma unroll
      for (int nf = 0; nf < 2; nf++) {
        int ml = mf * 16 + qd * 4;
        int nl = wn * 32 + nf * 16 + r;
#pragma unroll
        for (int e = 0; e < 4; e++) Ds[(ml + e) * 132 + nl] = acc[mf][nf][e];
      }
    __syncthreads();
    const int row = tid >> 2, seg = (tid & 3) * 32;
    size_t oa = ((size_t)b * Cz + m0 + row) * Tz + t0 + seg;
#pragma unroll
    for (int j = 0; j < 8; j++)
      *(float4*)&outp[oa + j * 4] = *(float4*)&Ds[row * 132 + seg + j * 4];
  }
}

// ---------------------------------------------------------------------------
// Barrier-free MFMA flash attention, fixed-max softmax, 32 q-rows/wave,
// j-split x4. Q hi/lo; K,V,er single bf16: S 2-pass, PV 1-pass.
// grid 1024 = 16 bh x 4 splits x 16 i-blocks(64); 128 thr (2 waves).
// ---------------------------------------------------------------------------
__global__ __launch_bounds__(128, 2) void attn_mfma(
    const u16* __restrict__ Qh_, const u16* __restrict__ Ql_,
    const u16* __restrict__ Kh_, const u16* __restrict__ Vh_,
    const float* __restrict__ mask, const u16* __restrict__ erkH,
    const u16* __restrict__ ervH, float* __restrict__ O0,
    float* __restrict__ O1, float* __restrict__ O2, float* __restrict__ O3,
    float* __restrict__ lp0, float* __restrict__ lp1,
    float* __restrict__ lp2, float* __restrict__ lp3) {
  __shared__ __align__(16) char smraw[2][14336];
  const int tid = threadIdx.x;
  const int lane = tid & 63, wid = tid >> 6;
  const int r = lane & 15, qd = lane >> 4;
  const int idx = blockIdx.x;
  const int bh = idx & 15;
  const int split = (idx >> 4) & 3;
  const int i0w = (idx >> 6) * 64 + wid * 32;
  const int b = bh >> 2, h = bh & 3;
  const float* mb = mask + (size_t)b * Tz;
  const size_t qkbase = (size_t)bh * Tz * KCz;
  const size_t vbase = (size_t)bh * KCz * Tz;
  float* Op = split == 0 ? O0 : (split == 1 ? O1 : (split == 2 ? O2 : O3));
  float* lp = split == 0 ? lp0 : (split == 1 ? lp1 : (split == 2 ? lp2 : lp3));
  const int j0beg = split * 256;

  float* rqs = (float*)(smraw[wid]);      // [32][22]
  float* bands = rqs + 704;               // [32][22]
  u16* Pp = (u16*)(smraw[wid] + 5632);    // [32][72]; reused as Os f32

  bf8v qh[2][2], ql[2][2];
#pragma unroll
  for (int rs = 0; rs < 2; rs++) {
    const size_t qrow = qkbase + (size_t)(i0w + rs * 16 + r) * KCz;
#pragma unroll
    for (int ks = 0; ks < 2; ks++) {
      qh[rs][ks] = *(const bf8v*)&Qh_[qrow + ks * 32 + qd * 8];
      ql[rs][ks] = *(const bf8v*)&Ql_[qrow + ks * 32 + qd * 8];
    }
  }
  for (int t = lane; t < 704; t += 64) bands[t] = -1e30f;

#pragma unroll
  for (int rs = 0; rs < 2; rs++) {
    f4v rc[2] = {(f4v)(0.f), (f4v)(0.f)};
#pragma unroll
    for (int nf = 0; nf < 2; nf++)
#pragma unroll
      for (int ks = 0; ks < 2; ks++) {
        bf8v eh = *(const bf8v*)&erkH[(16 * nf + r) * 64 + ks * 32 + qd * 8];
        rc[nf] = MFMA(qh[rs][ks], eh, rc[nf]);
        rc[nf] = MFMA(ql[rs][ks], eh, rc[nf]);
      }
#pragma unroll
    for (int nf = 0; nf < 2; nf++) {
      int rr = 16 * nf + r;
      if (rr < NR) {
#pragma unroll
        for (int e = 0; e < 4; e++)
          rqs[(rs * 16 + 4 * qd + e) * 22 + rr] = rc[nf][e];
      }
    }
  }

  float qm[2][4];
#pragma unroll
  for (int rs = 0; rs < 2; rs++)
#pragma unroll
    for (int e = 0; e < 4; e++) qm[rs][e] = mb[i0w + rs * 16 + 4 * qd + e];

  float lacc[2][4] = {};
  f4v oacc[2][4];
#pragma unroll
  for (int rs = 0; rs < 2; rs++)
#pragma unroll
    for (int nf = 0; nf < 4; nf++) oacc[rs][nf] = (f4v)(0.f);

#pragma unroll 2
  for (int jt = 0; jt < 4; jt++) {
    const int j0 = j0beg + jt * 64;
    bf8v kh[4][2], vh[4][2];
#pragma unroll
    for (int nf = 0; nf < 4; nf++) {
      const size_t kr = qkbase + (size_t)(j0 + 16 * nf + r) * KCz;
      const size_t vr = vbase + (size_t)(16 * nf + r) * Tz + j0;
#pragma unroll
      for (int ks = 0; ks < 2; ks++) {
        kh[nf][ks] = *(const bf8v*)&Kh_[kr + ks * 32 + qd * 8];
        vh[nf][ks] = *(const bf8v*)&Vh_[vr + ks * 32 + qd * 8];
      }
    }
    float km4[4];
#pragma unroll
    for (int nf = 0; nf < 4; nf++) km4[nf] = mb[j0 + 16 * nf + r];

#pragma unroll
    for (int rs = 0; rs < 2; rs++) {
      f4v sa[4];
#pragma unroll
      for (int nf = 0; nf < 4; nf++) sa[nf] = (f4v)(0.f);
#pragma unroll
      for (int nf = 0; nf < 4; nf++)
#pragma unroll
        for (int ks = 0; ks < 2; ks++) {
          sa[nf] = MFMA(qh[rs][ks], kh[nf][ks], sa[nf]);
          sa[nf] = MFMA(ql[rs][ks], kh[nf][ks], sa[nf]);
        }
      const int ibase = i0w + rs * 16;
      const bool diag = (j0 + 63 >= ibase - Wz) && (j0 <= ibase + 15 + Wz);
#pragma unroll
      for (int nf = 0; nf < 4; nf++)
#pragma unroll
        for (int e = 0; e < 4; e++) {
          const int iloc = rs * 16 + 4 * qd + e;
          float s = sa[nf][e];
          if (diag) {
            int dl = (j0 + 16 * nf + r) - (i0w + iloc);
            bool inb = (unsigned)(dl + Wz) <= 2u * Wz;
            if (inb) s += rqs[iloc * 22 + dl + Wz];
            if (qm[rs][e] * km4[nf] == 0.f) s = -1e4f;
            if (inb) bands[iloc * 22 + dl + Wz] = s;
          } else {
            if (qm[rs][e] * km4[nf] == 0.f) s = -1e4f;
          }
          float p = __expf(s - MFIX);
          lacc[rs][e] += p;
          Pp[iloc * 72 + 16 * nf + r] = bf_rne(p);
        }
    }
#pragma unroll
    for (int rs = 0; rs < 2; rs++)
#pragma unroll
      for (int ks = 0; ks < 2; ks++) {
        bf8v Ph = *(bf8v*)&Pp[(rs * 16 + r) * 72 + ks * 32 + qd * 8];
#pragma unroll
        for (int nf = 0; nf < 4; nf++)
          oacc[rs][nf] = MFMA(Ph, vh[nf][ks], oacc[rs][nf]);
      }
  }

  for (int t = lane; t < 32 * 32; t += 64) {
    int i = t >> 5, rr = t & 31;
    float p = (rr < NR) ? __expf(bands[i * 22 + rr] - MFIX) : 0.f;
    Pp[i * 72 + rr] = bf_rne(p);
  }
#pragma unroll
  for (int rs = 0; rs < 2; rs++) {
    bf8v Ph = *(bf8v*)&Pp[(rs * 16 + r) * 72 + qd * 8];
#pragma unroll
    for (int nf = 0; nf < 4; nf++) {
      bf8v eh = *(const bf8v*)&ervH[(16 * nf + r) * 32 + qd * 8];
      oacc[rs][nf] = MFMA(Ph, eh, oacc[rs][nf]);
    }
  }

#pragma unroll
  for (int off = 1; off < 16; off <<= 1)
#pragma unroll
    for (int rs = 0; rs < 2; rs++)
#pragma unroll
      for (int e = 0; e < 4; e++)
        lacc[rs][e] += __shfl_xor(lacc[rs][e], off, 16);
  if (r == 0) {
#pragma unroll
    for (int rs = 0; rs < 2; rs++)
#pragma unroll
      for (int e = 0; e < 4; e++)
        lp[(size_t)bh * Tz + i0w + rs * 16 + 4 * qd + e] = lacc[rs][e];
  }

  float* Os = (float*)Pp;  // [32][68]
#pragma unroll
  for (int rs = 0; rs < 2; rs++)
#pragma unroll
    for (int nf = 0; nf < 4; nf++)
#pragma unroll
      for (int e = 0; e < 4; e++)
        Os[(rs * 16 + 4 * qd + e) * 68 + 16 * nf + r] = oacc[rs][nf][e];
#pragma unroll
  for (int rs = 0; rs < 2; rs++) {
    const float* src = &Os[(rs * 16 + r) * 68 + qd * 16];
    size_t oa = ((size_t)bh * Tz + i0w + rs * 16 + r) * KCz + qd * 16;
#pragma unroll
    for (int jj = 0; jj < 4; jj++)
      *(float4*)&Op[oa + jj * 4] = *(const float4*)&src[jj * 4];
  }
}

// ---------------------------------------------------------------------------
// Fused residual + channel LayerNorm + transpose-pack.
// 8 t-cols/block, grid (128, B) = 512 blocks (2/CU); wave-0 shfl reduce.
// VAR 1 (NP partials, mask): x = LN(x + (sum(parts) + cbias)*mask)  [conv2]
// VAR 2 (NP partials, no mask): x = LN(x + sum(parts) + cbias)      [wo]
// ---------------------------------------------------------------------------
template <int VAR, int NP>
__global__ __launch_bounds__(256) void fused_ln(
    float* __restrict__ x, const float* __restrict__ y,
    const float* __restrict__ p1, const float* __restrict__ p2,
    const float* __restrict__ p3, const float* __restrict__ cbias,
    const float* __restrict__ g, const float* __restrict__ bb,
    const float* __restrict__ mask, u16* __restrict__ dhi,
    u16* __restrict__ dlo) {
  __shared__ float L[256 * 9];
  __shared__ float red[32][8], red2[32][8];
  __shared__ float ms[8], rs[8];
  const int tid = threadIdx.x;
  const int t0 = blockIdx.x * 8, b = blockIdx.y;
  const int tl = tid & 7, grp = tid >> 3;  // 32 c-groups of 8 t-cols
  const size_t bx = (size_t)b * Cz * TS + PADF + t0 + tl;
  const size_t by = (size_t)b * Cz * Tz + t0 + tl;
  const float mv = mask[(size_t)b * Tz + t0 + tl];
  float s = 0.f, sq = 0.f;
#pragma unroll
  for (int i = 0; i < 8; i++) {
    int c = grp + i * 32;
    float add = y[by + (size_t)c * Tz] + p1[by + (size_t)c * Tz] + cbias[c];
    if constexpr (NP == 4)
      add += p2[by + (size_t)c * Tz] + p3[by + (size_t)c * Tz];
    if constexpr (VAR == 1) add *= mv;
    float v = x[bx + (size_t)c * TS] + add;
    L[c * 9 + tl] = v;
    s += v;
    sq += v * v;
  }
  red[grp][tl] = s;
  red2[grp][tl] = sq;
  __syncthreads();
  if (tid < 64) {
    const int j = tid >> 3, tt = tid & 7;
    float su = red[j][tt] + red[j + 8][tt] + red[j + 16][tt] + red[j + 24][tt];
    float sqq =
        red2[j][tt] + red2[j + 8][tt] + red2[j + 16][tt] + red2[j + 24][tt];
    su += __shfl_xor(su, 8);
    su += __shfl_xor(su, 16);
    su += __shfl_xor(su, 32);
    sqq += __shfl_xor(sqq, 8);
    sqq += __shfl_xor(sqq, 16);
    sqq += __shfl_xor(sqq, 32);
    if (j == 0) {
      float m = su * (1.f / Cz);
      ms[tt] = m;
      rs[tt] = rsqrtf(sqq * (1.f / Cz) - m * m + 1e-5f);
    }
  }
  __syncthreads();
  const float m = ms[tl], r = rs[tl];
#pragma unroll
  for (int i = 0; i < 8; i++) {
    int c = grp + i * 32;
    float v = (L[c * 9 + tl] - m) * r * g[c] + bb[c];
    x[bx + (size_t)c * TS] = v;
    L[c * 9 + tl] = v * mv;
  }
  __syncthreads();
  const int tt = tid & 7, p = tid >> 3;  // 32 segs of 8 channels
  u16 hs[8], ls[8];
#pragma unroll
  for (int j = 0; j < 8; j++)
    bf_split(L[(p * 8 + j) * 9 + tt], hs[j], ls[j]);
  size_t da = ((size_t)b * PROWS + t0 + tt + 1) * Cz + p * 8;
  *(uint4*)&dhi[da] = *(uint4*)&hs[0];
  *(uint4*)&dlo[da] = *(uint4*)&ls[0];
}

// ---------------------------------------------------------------------------
extern "C" void kernel_launch(void* const* d_in, const int* in_sizes, int n_in,
                              void* d_out, int out_size, void* d_ws,
                              size_t ws_size, hipStream_t stream) {
  const float* x = (const float*)d_in[0];
  const float* xm = (const float*)d_in[1];
  const float* wq = (const float*)d_in[2];
  const float* bq = (const float*)d_in[3];
  const float* wk = (const float*)d_in[4];
  const float* bk = (const float*)d_in[5];
  const float* wv = (const float*)d_in[6];
  const float* bv = (const float*)d_in[7];
  const float* wo = (const float*)d_in[8];
  const float* bo = (const float*)d_in[9];
  const float* erk = (const float*)d_in[10];
  const float* erv = (const float*)d_in[11];
  const float* g1 = (const float*)d_in[12];
  const float* b1 = (const float*)d_in[13];
  const float* fw1 = (const float*)d_in[14];
  const float* fb1 = (const float*)d_in[15];
  const float* fw2 = (const float*)d_in[16];
  const float* fb2 = (const float*)d_in[17];
  const float* g2 = (const float*)d_in[18];
  const float* b2 = (const float*)d_in[19];

  const size_t NBC = (size_t)Bz * Cz * Tz;       // 1,048,576
  const size_t XBN = (size_t)Bz * Cz * TS;       // 1,056,768
  const size_t HP = (size_t)Bz * PROWS * FCz;    // 4,202,496 u16/array
  const size_t XP = (size_t)Bz * PROWS * Cz;     // 1,050,624 u16/array
  const size_t QS = (size_t)Bz * Hz * Tz * KCz;  // 1,048,576 u16/array

  float* ws = (float*)d_ws;
  float* xb = ws;
  float* yb = xb + XBN;   // attn partial O0
  float* p1 = yb + NBC;   // O1
  float* p2 = p1 + NBC;   // O2
  float* p3 = p2 + NBC;   // O3
  float* unf = p3 + NBC;  // union: Q/K/V packed OR wo outputs OR FFN hidden
  u16* hpH = (u16*)unf;   // single-bf16 hidden
  u16* Qh = (u16*)unf;
  u16* Ql = Qh + QS;
  u16* Kh = Ql + QS;
  u16* Vh = Kh + QS;
  float* wo0 = unf;        // wo k-half 0 output (over dead Q/Ql, 4 MB)
  float* wo1 = unf + NBC;  // wo k-half 1 output (over dead Kh/Vh, 4 MB)
  float* xpf = unf + HP;
  u16* xpH = (u16*)xpf;
  u16* xpL = xpH + XP;
  float* qwf = xpf + XP;
  u16* qwAll = (u16*)qwf;  // 6 x 262144 u16
  float* w1f = qwf + 786432;
  u16* w1All = (u16*)w1f;  // 6 x 786432 u16
  float* w2f = w1f + 2359296;
  u16* w2All = (u16*)w2f;  // 6 x 786432 u16
  float* erf = w2f + 2359296;
  u16* ekAll = (u16*)erf;      // 6 x 2048 u16
  u16* evAll = ekAll + 12288;  // 6 x 2048 u16
  float* pbAll = erf + 12288;  // 6 x 1024 f32
  float* lb0 = pbAll + 6144;
  float* lb1 = lb0 + 16384;
  float* lb2 = lb1 + 16384;
  float* lb3 = lb2 + 16384;

  const int ntot = (int)NBC;
  pack_all<<<dim3(6 * 7184), 256, 0, stream>>>(
      wq, wk, wv, wo, bq, bk, bv, bo, erk, erv, fw1, fw2, qwAll, pbAll, ekAll,
      evAll, w1All, w2All);
  tpack<<<dim3(16, 4, 4), 256, 0, stream>>>(x, xm, xb, xpH, xpL, Cz);

  for (int l = 0; l < Lz; l++) {
    qkv_gemm<<<dim3(16, 12, 4), 256, 0, stream>>>(
        qwAll + (size_t)l * 262144, xpH, xpL, pbAll + l * 1024, Qh, Ql, Kh,
        Vh, 1024, Cz);
    attn_mfma<<<dim3(1024), 128, 0, stream>>>(
        Qh, Ql, Kh, Vh, xm, ekAll + l * 2048, evAll + l * 2048, yb, p1, p2,
        p3, lb0, lb1, lb2, lb3);
    // wo GEMM with fused combine (single-bf16 B): Q/K/V dead after attn.
    wo_gemm<<<dim3(16, 8, 4), 256, 0, stream>>>(
        qwAll + (size_t)l * 262144, xpH, xpL, pbAll + l * 1024, wo0, wo1, yb,
        p1, p2, p3, lb0, lb1, lb2, lb3, 1024, Cz, 768);
    fused_ln<2, 2><<<dim3(128, 4), 256, 0, stream>>>(
        xb, wo0, wo1, nullptr, nullptr, bo + l * Cz, g1 + l * Cz, b1 + l * Cz,
        xm, xpH, xpL);
    conv_mfma<1><<<dim3(8, 16, 4), 256, 0, stream>>>(
        w1All + (size_t)l * 786432, xpH, fb1 + l * FCz, xm, hpH, nullptr,
        nullptr, nullptr, nullptr, FCz, Cz);
    conv_mfma<3><<<dim3(8, 16, 4), 256, 0, stream>>>(
        w2All + (size_t)l * 786432, hpH, nullptr, xm, nullptr, yb, p1, p2,
        p3, Cz, FCz);
    fused_ln<1, 4><<<dim3(128, 4), 256, 0, stream>>>(
        xb, yb, p1, p2, p3, fb2 + l * Cz, g2 + l * Cz, b2 + l * Cz, xm, xpH,
        xpL);
  }
  mask_out<<<dim3((ntot + 255) / 256), 256, 0, stream>>>(xb, xm,
                                                         (float*)d_out);
}

// Round 13
// 899.081 us; speedup vs baseline: 1.1006x; 1.0151x over previous
//
#include <hip/hip_runtime.h>

// Encoder: L=6 layers of (rel-pos attention + channel-LN + K=3 conv FFN + LN)
// B=4, C=256, T=1024, H=4, KC=64, FC=1024, W=10, fp32 I/O.
// ROUND 13: spend remaining absmax headroom (0.039 vs 0.084) on the last
// 2-pass structures: (a) attention S-phase drops Q-lo (1-pass mfma(qh,kh);
// rel-pos too) -- S err ~1e-3 on ~0.6-scale scores; (b) qkv B single-pass.
// Cascade: xpL fully dead -> fused_ln/tpack drop bf_split+lo stores; Q packs
// single bf16 (no Ql). Base R12 (913us): single-B convs+wo, fused combines,
// qkv launch_bounds(256,3), halo-predicated convs, tap-shared staging.

#define Lz 6
#define Cz 256
#define FCz 1024
#define Hz 4
#define Wz 10
#define Bz 4
#define Tz 1024
#define KCz 64
#define NR 21
#define TS 1032
#define PADF 4
#define PROWS 1026
#define MFIX 8.0f

typedef unsigned short u16;
typedef unsigned int u32;
typedef __attribute__((ext_vector_type(8))) short bf8v;
typedef __attribute__((ext_vector_type(4))) float f4v;

#define MFMA(a, b, c) __builtin_amdgcn_mfma_f32_16x16x32_bf16(a, b, c, 0, 0, 0)

__device__ inline u16 bf_rne(float v) {
  u32 u = __float_as_uint(v);
  return (u16)((u + 0x7FFFu + ((u >> 16) & 1u)) >> 16);
}

// ---------------------------------------------------------------------------
__global__ __launch_bounds__(256) void mask_out(const float* __restrict__ xp,
                                                const float* __restrict__ m,
                                                float* __restrict__ out) {
  int id = blockIdx.x * 256 + threadIdx.x;
  if (id < Bz * Cz * Tz) {
    int t = id & (Tz - 1), row = id >> 10, b = id >> 18;
    out[id] = xp[(size_t)row * TS + PADF + t] * m[b * Tz + t];
  }
}

// ---------------------------------------------------------------------------
// Fused mask_in + transpose-pack: reads x [b][c][Tz] + mask, writes
// xb = x*m (TS-padded layout) AND packed single-bf16 [b][1026][Cd] of (x*m)*m.
// ---------------------------------------------------------------------------
__global__ __launch_bounds__(256) void tpack(const float* __restrict__ xsrc,
                                             const float* __restrict__ mask,
                                             float* __restrict__ xb,
                                             u16* __restrict__ dhi, int Cd) {
  __shared__ float L[64 * 68];
  const int tid = threadIdx.x;
  const int t0 = blockIdx.x * 64, c0 = blockIdx.y * 64, b = blockIdx.z;
#pragma unroll
  for (int i = 0; i < 16; i++) {
    int id = tid + 256 * i;
    int cc = id >> 6, tt = id & 63;
    float mv = mask[(size_t)b * Tz + t0 + tt];
    float v = xsrc[((size_t)(b * Cz + c0 + cc)) * Tz + t0 + tt] * mv;
    xb[((size_t)(b * Cz + c0 + cc)) * TS + PADF + t0 + tt] = v;
    L[cc * 68 + tt] = v;
  }
  __syncthreads();
  const int tt = tid >> 2, p = tid & 3;
  float mv = mask[(size_t)b * Tz + t0 + tt];
  u16 hs[16];
#pragma unroll
  for (int j = 0; j < 16; j++)
    hs[j] = bf_rne(L[(p * 16 + j) * 68 + tt] * mv);
  size_t da = ((size_t)b * PROWS + t0 + tt + 1) * Cd + c0 + p * 16;
  *(uint4*)&dhi[da] = *(uint4*)&hs[0];
  *(uint4*)&dhi[da + 8] = *(uint4*)&hs[8];
}

// ---------------------------------------------------------------------------
// Pack ALL layers' weights in one launch. grid = 6 * 7184 blocks.
// ---------------------------------------------------------------------------
__global__ __launch_bounds__(256) void pack_all(
    const float* __restrict__ wq, const float* __restrict__ wk,
    const float* __restrict__ wv, const float* __restrict__ wo_,
    const float* __restrict__ bq, const float* __restrict__ bk,
    const float* __restrict__ bv, const float* __restrict__ bo,
    const float* __restrict__ erk, const float* __restrict__ erv,
    const float* __restrict__ fw1, const float* __restrict__ fw2,
    u16* __restrict__ qwAll, float* __restrict__ pbAll,
    u16* __restrict__ ekAll, u16* __restrict__ evAll,
    u16* __restrict__ w1All, u16* __restrict__ w2All) {
  const int blk = blockIdx.x, tid = threadIdx.x;
  const int layer = blk / 7184;
  const int bl = blk % 7184;
  if (bl < 1024) {
    int id = bl * 256 + tid;
    int o = id >> 8, c = id & 255;
    int sel = o >> 8;
    const size_t wof = (size_t)layer * Cz * Cz;
    const float* w = sel == 0 ? wq + wof
                              : (sel == 1 ? wk + wof
                                          : (sel == 2 ? wv + wof : wo_ + wof));
    qwAll[(size_t)layer * 262144 + id] = bf_rne(w[((o & 255) << 8) + c]);
    if (id < 1024) {
      int s2 = id >> 8;
      const float* bs = s2 == 0 ? bq : (s2 == 1 ? bk : (s2 == 2 ? bv : bo));
      pbAll[layer * 1024 + id] = bs[layer * Cz + (id & 255)];
    }
  } else if (bl < 1040) {
    int id = (bl - 1024) * 256 + tid;
    if (id < 2048) {
      int rr = id >> 6, d = id & 63;
      ekAll[layer * 2048 + id] =
          bf_rne((rr < NR) ? erk[(size_t)layer * NR * KCz + rr * KCz + d]
                           : 0.f);
    } else {
      int id2 = id - 2048;
      int d = id2 >> 5, rr = id2 & 31;
      evAll[layer * 2048 + id2] =
          bf_rne((rr < NR) ? erv[(size_t)layer * NR * KCz + rr * KCz + d]
                           : 0.f);
    }
  } else if (bl < 4112) {
    int id = (bl - 1040) * 256 + tid;
    int c = id % Cz;
    int rest = id / Cz;
    int o = rest % FCz, tap = rest / FCz;
    w1All[(size_t)layer * 786432 + id] =
        bf_rne(fw1[(size_t)layer * FCz * Cz * 3 + ((size_t)o * Cz + c) * 3 +
                   tap]);
  } else {
    int id = (bl - 4112) * 256 + tid;
    int c = id % FCz;
    int rest = id / FCz;
    int o = rest % Cz, tap = rest / Cz;
    w2All[(size_t)layer * 786432 + id] =
        bf_rne(fw2[(size_t)layer * Cz * FCz * 3 + ((size_t)o * FCz + c) * 3 +
                   tap]);
  }
}

// ---------------------------------------------------------------------------
// MFMA GEMM body (A = single bf16 weights; B single bf16). Tile 64x64.
// EPI 0: B = packed acts; qkv -> Q (x0.125), K (t-major), V (kc-major).
// EPI 3: wo, K-split-2; B staged single bf16 from attn partials (fused
//        combine).
// ---------------------------------------------------------------------------
template <int EPI>
static __device__ __forceinline__ void gemm_body(
    const u16* __restrict__ Ah, const u16* __restrict__ Bh,
    const float* __restrict__ bias, float* __restrict__ out,
    float* __restrict__ out2, u16* __restrict__ pqh, u16* __restrict__ pkh,
    u16* __restrict__ pvh, const float* __restrict__ Ox0,
    const float* __restrict__ Ox1, const float* __restrict__ Ox2,
    const float* __restrict__ Ox3, const float* __restrict__ sl0,
    const float* __restrict__ sl1, const float* __restrict__ sl2,
    const float* __restrict__ sl3, int M, int Kc, int m_base, char* smraw) {
  u16* Ash = (u16*)smraw;
  u16* Bsh = Ash + 2560;
  const int tid = threadIdx.x;
  const int lane = tid & 63, wid = tid >> 6;
  const int wm = wid & 1, wn = wid >> 1;
  const int r = lane & 15, qd = lane >> 4;
  const int t0 = blockIdx.x * 64;
  const int b = blockIdx.z;
  const int srow = tid >> 2, sseg = (tid & 3) * 8;

  int m0, kc0, kcN;
  float* outp = out;
  if constexpr (EPI == 3) {
    m0 = m_base + (blockIdx.y >> 1) * 64;
    kc0 = (blockIdx.y & 1) * (Kc / 2);
    kcN = Kc / 2;
    outp = (blockIdx.y & 1) ? out2 : out;
  } else {
    m0 = blockIdx.y * 64 + m_base;
    kc0 = 0;
    kcN = Kc;
  }

  f4v acc[2][2];
#pragma unroll
  for (int i = 0; i < 2; i++)
#pragma unroll
    for (int j = 0; j < 2; j++) acc[i][j] = (f4v)(0.f);

  const size_t arow = (size_t)(m0 + srow) * Kc + kc0;
  const size_t brow = ((size_t)b * PROWS + t0 + 1 + srow) * Kc + kc0;
  for (int kc = 0; kc < kcN; kc += 32) {
    *(uint4*)&Ash[srow * 40 + sseg] = *(const uint4*)&Ah[arow + kc + sseg];
    if constexpr (EPI == 3) {
      // fused attn_combine (single bf16): row t = t0+srow, cols cc..cc+7
      const int cc = kc0 + kc + sseg;
      const int hh = cc >> 6, dd = cc & 63;
      const size_t lbi = (size_t)(b * Hz + hh) * Tz + t0 + srow;
      const size_t ob = lbi * KCz + dd;
      float4 qa = *(const float4*)&Ox0[ob];
      float4 qb = *(const float4*)&Ox0[ob + 4];
      float4 ra = *(const float4*)&Ox1[ob];
      float4 rb = *(const float4*)&Ox1[ob + 4];
      float4 sa = *(const float4*)&Ox2[ob];
      float4 sb = *(const float4*)&Ox2[ob + 4];
      float4 ta = *(const float4*)&Ox3[ob];
      float4 tb = *(const float4*)&Ox3[ob + 4];
      const float li = 1.f / (sl0[lbi] + sl1[lbi] + sl2[lbi] + sl3[lbi]);
      u16 hhs[8];
      hhs[0] = bf_rne((qa.x + ra.x + sa.x + ta.x) * li);
      hhs[1] = bf_rne((qa.y + ra.y + sa.y + ta.y) * li);
      hhs[2] = bf_rne((qa.z + ra.z + sa.z + ta.z) * li);
      hhs[3] = bf_rne((qa.w + ra.w + sa.w + ta.w) * li);
      hhs[4] = bf_rne((qb.x + rb.x + sb.x + tb.x) * li);
      hhs[5] = bf_rne((qb.y + rb.y + sb.y + tb.y) * li);
      hhs[6] = bf_rne((qb.z + rb.z + sb.z + tb.z) * li);
      hhs[7] = bf_rne((qb.w + rb.w + sb.w + tb.w) * li);
      *(uint4*)&Bsh[srow * 40 + sseg] = *(uint4*)&hhs[0];
    } else {
      *(uint4*)&Bsh[srow * 40 + sseg] = *(const uint4*)&Bh[brow + kc + sseg];
    }
    __syncthreads();
    bf8v ah[2], bh2[2];
#pragma unroll
    for (int f = 0; f < 2; f++) {
      int ar = (wm * 32 + f * 16 + r) * 40 + qd * 8;
      int br = (wn * 32 + f * 16 + r) * 40 + qd * 8;
      ah[f] = *(bf8v*)&Ash[ar];
      bh2[f] = *(bf8v*)&Bsh[br];
    }
#pragma unroll
    for (int mf = 0; mf < 2; mf++)
#pragma unroll
      for (int nf = 0; nf < 2; nf++)
        acc[mf][nf] = MFMA(ah[mf], bh2[nf], acc[mf][nf]);
    __syncthreads();
  }

  float* Ds = (float*)smraw;
  if constexpr (EPI == 0) {
    const int sel = m0 >> 8;
    const int h = (m0 >> 6) & 3;
    const int bhI = b * Hz + h;
    if (sel < 2) {
#pragma unroll
      for (int mf = 0; mf < 2; mf++)
#pragma unroll
        for (int nf = 0; nf < 2; nf++) {
          int nl = wn * 32 + nf * 16 + r;
          int ml = wm * 32 + mf * 16 + qd * 4;
          *(f4v*)&Ds[nl * 68 + ml] = acc[mf][nf];
        }
      __syncthreads();
      const int row = tid >> 2, p = tid & 3;
      size_t da = ((size_t)bhI * Tz + t0 + row) * KCz + p * 16;
      const float sc = (sel == 0) ? 0.125f : 1.0f;
      u16* dst = (sel == 0) ? pqh : pkh;
      u16 hs[16];
#pragma unroll
      for (int jj = 0; jj < 4; jj++) {
        float4 dv = *(float4*)&Ds[row * 68 + p * 16 + jj * 4];
        float4 bb = *(const float4*)&bias[m0 + p * 16 + jj * 4];
        hs[jj * 4 + 0] = bf_rne((dv.x + bb.x) * sc);
        hs[jj * 4 + 1] = bf_rne((dv.y + bb.y) * sc);
        hs[jj * 4 + 2] = bf_rne((dv.z + bb.z) * sc);
        hs[jj * 4 + 3] = bf_rne((dv.w + bb.w) * sc);
      }
      *(uint4*)&dst[da] = *(uint4*)&hs[0];
      *(uint4*)&dst[da + 8] = *(uint4*)&hs[8];
    } else {
#pragma unroll
      for (int mf = 0; mf < 2; mf++)
#pragma unroll
        for (int nf = 0; nf < 2; nf++) {
          int ml = wm * 32 + mf * 16 + qd * 4;
          int nl = wn * 32 + nf * 16 + r;
#pragma unroll
          for (int e = 0; e < 4; e++) Ds[(ml + e) * 68 + nl] = acc[mf][nf][e];
        }
      __syncthreads();
      const int row = tid >> 2, p = tid & 3;
      const float bb = bias[m0 + row];
      u16 hs[16];
#pragma unroll
      for (int jj = 0; jj < 16; jj++)
        hs[jj] = bf_rne(Ds[row * 68 + p * 16 + jj] + bb);
      size_t da = ((size_t)bhI * KCz + row) * Tz + t0 + p * 16;
      *(uint4*)&pvh[da] = *(uint4*)&hs[0];
      *(uint4*)&pvh[da + 8] = *(uint4*)&hs[8];
    }
  } else {
#pragma unroll
    for (int mf = 0; mf < 2; mf++)
#pragma unroll
      for (int nf = 0; nf < 2; nf++) {
        int ml = wm * 32 + mf * 16 + qd * 4;
        int nl = wn * 32 + nf * 16 + r;
#pragma unroll
        for (int e = 0; e < 4; e++) Ds[(ml + e) * 68 + nl] = acc[mf][nf][e];
      }
    __syncthreads();
    const int row = tid >> 2, p = tid & 3;
    size_t oa = ((size_t)b * Cz + (m0 - m_base) + row) * Tz + t0 + p * 16;
#pragma unroll
    for (int jj = 0; jj < 4; jj++)
      *(float4*)&outp[oa + jj * 4] = *(float4*)&Ds[row * 68 + p * 16 + jj * 4];
  }
}

// qkv wrapper: (256,3) -> 3 blocks/CU, 768-block grid co-resident.
__global__ __launch_bounds__(256, 3) void qkv_gemm(
    const u16* __restrict__ Ah, const u16* __restrict__ Bh,
    const float* __restrict__ bias, u16* __restrict__ pqh,
    u16* __restrict__ pkh, u16* __restrict__ pvh, int M, int Kc) {
  __shared__ __align__(16) char smraw[17408];
  gemm_body<0>(Ah, Bh, bias, nullptr, nullptr, pqh, pkh, pvh, nullptr,
               nullptr, nullptr, nullptr, nullptr, nullptr, nullptr, nullptr,
               M, Kc, 0, smraw);
}

// wo wrapper: unconstrained (fused-combine epilogue).
__global__ __launch_bounds__(256) void wo_gemm(
    const u16* __restrict__ Ah, const float* __restrict__ bias,
    float* __restrict__ out, float* __restrict__ out2,
    const float* __restrict__ Ox0, const float* __restrict__ Ox1,
    const float* __restrict__ Ox2, const float* __restrict__ Ox3,
    const float* __restrict__ sl0, const float* __restrict__ sl1,
    const float* __restrict__ sl2, const float* __restrict__ sl3, int M,
    int Kc, int m_base) {
  __shared__ __align__(16) char smraw[17408];
  gemm_body<3>(Ah, nullptr, bias, out, out2, nullptr, nullptr, nullptr, Ox0,
               Ox1, Ox2, Ox3, sl0, sl1, sl2, sl3, M, Kc, m_base, smraw);
}

// ---------------------------------------------------------------------------
// Conv (K=3) as MFMA GEMM, 64m x 128t tile, 4 waves = 4 t-strips.
// SINGLE-bf16 B both convs (1-pass MFMA). Tap-shared B staging; reg-prefetch.
// Halo rows (prow 0 / 1025) zero-predicated in staging.
// EPI 1: conv1: B = xp single; out +bias,relu,mask -> single bf16 hidden.
// EPI 3: conv2: B = hp single; K-split x4 -> fp32 partials o0..o3.
// ---------------------------------------------------------------------------
template <int EPI>
__global__ __launch_bounds__(256, 2) void conv_mfma(
    const u16* __restrict__ Ah, const u16* __restrict__ Bh,
    const float* __restrict__ bias, const float* __restrict__ mask,
    u16* __restrict__ ph, float* __restrict__ o0, float* __restrict__ o1,
    float* __restrict__ o2, float* __restrict__ o3, int M, int Kc) {
  __shared__ __align__(16) char smraw[36480];
  u16* Ash = (u16*)smraw;        // [3][64][40]
  u16* Bsh = Ash + 3 * 64 * 40;  // [132][40] (130 rows used)
  const int tid = threadIdx.x;
  const int lane = tid & 63, wn = tid >> 6;  // 4 waves: t-strip wn*32
  const int r = lane & 15, qd = lane >> 4;
  const int t0 = blockIdx.x * 128;
  const int b = blockIdx.z;

  int m0, kc0, kcN;
  float* outp = nullptr;
  if constexpr (EPI == 3) {
    int mt = blockIdx.y >> 2, sp = blockIdx.y & 3;
    m0 = mt * 64;
    kc0 = sp * (Kc / 4);
    kcN = Kc / 4;
    outp = sp == 0 ? o0 : (sp == 1 ? o1 : (sp == 2 ? o2 : o3));
  } else {
    m0 = blockIdx.y * 64;
    kc0 = 0;
    kcN = Kc;
  }

  const int srow = tid >> 2, sseg = (tid & 3) * 8;  // rows 0..63
  const bool btail = tid < 8;                       // B rows 128..129
  const int brow2 = 128 + (tid >> 2);
  const bool h0 = (t0 + srow == 0);
  const bool hT = btail && (t0 + brow2 == PROWS - 1);
  const uint4 z4 = {0u, 0u, 0u, 0u};

  f4v acc[4][2];
#pragma unroll
  for (int i = 0; i < 4; i++)
#pragma unroll
    for (int j = 0; j < 2; j++) acc[i][j] = (f4v)(0.f);

  const size_t abase = (size_t)(m0 + srow) * Kc + kc0 + sseg;
  const size_t bbase = ((size_t)b * PROWS + t0 + srow) * Kc + kc0 + sseg;
  const size_t bbase64 = bbase + (size_t)64 * Kc;
  const size_t bbaseT = ((size_t)b * PROWS + t0 + brow2) * Kc + kc0 + sseg;

  uint4 ar[3], bh0, bh1, bht;
  auto LOADR = [&](int kc) {
#pragma unroll
    for (int tp = 0; tp < 3; tp++)
      ar[tp] = *(const uint4*)&Ah[(size_t)tp * M * Kc + abase + kc];
    bh0 = *(const uint4*)&Bh[bbase + kc];
    bh1 = *(const uint4*)&Bh[bbase64 + kc];
    if (h0) bh0 = z4;
    if (btail) {
      bht = *(const uint4*)&Bh[bbaseT + kc];
      if (hT) bht = z4;
    }
  };

  LOADR(0);
  for (int kc = 0; kc < kcN; kc += 32) {
#pragma unroll
    for (int tp = 0; tp < 3; tp++)
      *(uint4*)&Ash[(tp * 64 + srow) * 40 + sseg] = ar[tp];
    *(uint4*)&Bsh[srow * 40 + sseg] = bh0;
    *(uint4*)&Bsh[(srow + 64) * 40 + sseg] = bh1;
    if (btail) *(uint4*)&Bsh[brow2 * 40 + sseg] = bht;
    __syncthreads();
    if (kc + 32 < kcN) LOADR(kc + 32);  // prefetch next chunk
#pragma unroll
    for (int tap = 0; tap < 3; tap++) {
      bf8v ah[4], bh2[2];
#pragma unroll
      for (int mf = 0; mf < 4; mf++)
        ah[mf] = *(bf8v*)&Ash[(tap * 64 + mf * 16 + r) * 40 + qd * 8];
#pragma unroll
      for (int nf = 0; nf < 2; nf++)
        bh2[nf] = *(bf8v*)&Bsh[(wn * 32 + nf * 16 + r + tap) * 40 + qd * 8];
#pragma unroll
      for (int mf = 0; mf < 4; mf++)
#pragma unroll
        for (int nf = 0; nf < 2; nf++)
          acc[mf][nf] = MFMA(ah[mf], bh2[nf], acc[mf][nf]);
    }
    __syncthreads();
  }

  // acc[mf][nf][e]: m = mf*16 + qd*4 + e, t = wn*32 + nf*16 + r
  if constexpr (EPI == 1) {
    float* Ds = (float*)smraw;  // [t 128][m 68]
#pragma unroll
    for (int mf = 0; mf < 4; mf++)
#pragma unroll
      for (int nf = 0; nf < 2; nf++) {
        int tl = wn * 32 + nf * 16 + r;
        int ml = mf * 16 + qd * 4;
        *(f4v*)&Ds[tl * 68 + ml] = acc[mf][nf];
      }
    __syncthreads();
    const int row = tid >> 1, half = (tid & 1) * 32;
    const int t = t0 + row;
    const float mv = mask[(size_t)b * Tz + t];
    u16 hs[32];
#pragma unroll
    for (int j = 0; j < 32; j += 4) {
      float4 dv = *(float4*)&Ds[row * 68 + half + j];
      float4 bb = *(const float4*)&bias[m0 + half + j];
      hs[j + 0] = bf_rne(fmaxf(dv.x + bb.x, 0.f) * mv);
      hs[j + 1] = bf_rne(fmaxf(dv.y + bb.y, 0.f) * mv);
      hs[j + 2] = bf_rne(fmaxf(dv.z + bb.z, 0.f) * mv);
      hs[j + 3] = bf_rne(fmaxf(dv.w + bb.w, 0.f) * mv);
    }
    size_t da = ((size_t)b * PROWS + t + 1) * M + m0 + half;
#pragma unroll
    for (int j = 0; j < 32; j += 8) *(uint4*)&ph[da + j] = *(uint4*)&hs[j];
  } else {
    float* Ds = (float*)smraw;  // [m 64][t 132]
#pragma unroll
    for (int mf = 0; mf < 4; mf++)
#pragma unroll
      for (int nf = 0; nf < 2; nf++) {
        int ml = mf * 16 + qd * 4;
        int nl = wn * 32 + nf * 16 + r;
#pragma unroll
        for (int e = 0; e < 4; e++) Ds[(ml + e) * 132 + nl] = acc[mf][nf][e];
      }
    __syncthreads();
    const int row = tid >> 2, seg = (tid & 3) * 32;
    size_t oa = ((size_t)b * Cz + m0 + row) * Tz + t0 + seg;
#pragma unroll
    for (int j = 0; j < 8; j++)
      *(float4*)&outp[oa + j * 4] = *(float4*)&Ds[row * 132 + seg + j * 4];
  }
}

// ---------------------------------------------------------------------------
// Barrier-free MFMA flash attention, fixed-max softmax, 32 q-rows/wave,
// j-split x4. Q,K,V,er single bf16: S 1-pass, PV 1-pass.
// grid 1024 = 16 bh x 4 splits x 16 i-blocks(64); 128 thr (2 waves).
// ---------------------------------------------------------------------------
__global__ __launch_bounds__(128, 2) void attn_mfma(
    const u16* __restrict__ Qh_, const u16* __restrict__ Kh_,
    const u16* __restrict__ Vh_, const float* __restrict__ mask,
    const u16* __restrict__ erkH, const u16* __restrict__ ervH,
    float* __restrict__ O0, float* __restrict__ O1, float* __restrict__ O2,
    float* __restrict__ O3, float* __restrict__ lp0, float* __restrict__ lp1,
    float* __restrict__ lp2, float* __restrict__ lp3) {
  __shared__ __align__(16) char smraw[2][14336];
  const int tid = threadIdx.x;
  const int lane = tid & 63, wid = tid >> 6;
  const int r = lane & 15, qd = lane >> 4;
  const int idx = blockIdx.x;
  const int bh = idx & 15;
  const int split = (idx >> 4) & 3;
  const int i0w = (idx >> 6) * 64 + wid * 32;
  const int b = bh >> 2, h = bh & 3;
  const float* mb = mask + (size_t)b * Tz;
  const size_t qkbase = (size_t)bh * Tz * KCz;
  const size_t vbase = (size_t)bh * KCz * Tz;
  float* Op = split == 0 ? O0 : (split == 1 ? O1 : (split == 2 ? O2 : O3));
  float* lp = split == 0 ? lp0 : (split == 1 ? lp1 : (split == 2 ? lp2 : lp3));
  const int j0beg = split * 256;

  float* rqs = (float*)(smraw[wid]);      // [32][22]
  float* bands = rqs + 704;               // [32][22]
  u16* Pp = (u16*)(smraw[wid] + 5632);    // [32][72]; reused as Os f32

  bf8v qh[2][2];
#pragma unroll
  for (int rs = 0; rs < 2; rs++) {
    const size_t qrow = qkbase + (size_t)(i0w + rs * 16 + r) * KCz;
#pragma unroll
    for (int ks = 0; ks < 2; ks++)
      qh[rs][ks] = *(const bf8v*)&Qh_[qrow + ks * 32 + qd * 8];
  }
  for (int t = lane; t < 704; t += 64) bands[t] = -1e30f;

#pragma unroll
  for (int rs = 0; rs < 2; rs++) {
    f4v rc[2] = {(f4v)(0.f), (f4v)(0.f)};
#pragma unroll
    for (int nf = 0; nf < 2; nf++)
#pragma unroll
      for (int ks = 0; ks < 2; ks++) {
        bf8v eh = *(const bf8v*)&erkH[(16 * nf + r) * 64 + ks * 32 + qd * 8];
        rc[nf] = MFMA(qh[rs][ks], eh, rc[nf]);
      }
#pragma unroll
    for (int nf = 0; nf < 2; nf++) {
      int rr = 16 * nf + r;
      if (rr < NR) {
#pragma unroll
        for (int e = 0; e < 4; e++)
          rqs[(rs * 16 + 4 * qd + e) * 22 + rr] = rc[nf][e];
      }
    }
  }

  float qm[2][4];
#pragma unroll
  for (int rs = 0; rs < 2; rs++)
#pragma unroll
    for (int e = 0; e < 4; e++) qm[rs][e] = mb[i0w + rs * 16 + 4 * qd + e];

  float lacc[2][4] = {};
  f4v oacc[2][4];
#pragma unroll
  for (int rs = 0; rs < 2; rs++)
#pragma unroll
    for (int nf = 0; nf < 4; nf++) oacc[rs][nf] = (f4v)(0.f);

#pragma unroll 2
  for (int jt = 0; jt < 4; jt++) {
    const int j0 = j0beg + jt * 64;
    bf8v kh[4][2], vh[4][2];
#pragma unroll
    for (int nf = 0; nf < 4; nf++) {
      const size_t kr = qkbase + (size_t)(j0 + 16 * nf + r) * KCz;
      const size_t vr = vbase + (size_t)(16 * nf + r) * Tz + j0;
#pragma unroll
      for (int ks = 0; ks < 2; ks++) {
        kh[nf][ks] = *(const bf8v*)&Kh_[kr + ks * 32 + qd * 8];
        vh[nf][ks] = *(const bf8v*)&Vh_[vr + ks * 32 + qd * 8];
      }
    }
    float km4[4];
#pragma unroll
    for (int nf = 0; nf < 4; nf++) km4[nf] = mb[j0 + 16 * nf + r];

#pragma unroll
    for (int rs = 0; rs < 2; rs++) {
      f4v sa[4];
#pragma unroll
      for (int nf = 0; nf < 4; nf++) sa[nf] = (f4v)(0.f);
#pragma unroll
      for (int nf = 0; nf < 4; nf++)
#pragma unroll
        for (int ks = 0; ks < 2; ks++)
          sa[nf] = MFMA(qh[rs][ks], kh[nf][ks], sa[nf]);
      const int ibase = i0w + rs * 16;
      const bool diag = (j0 + 63 >= ibase - Wz) && (j0 <= ibase + 15 + Wz);
#pragma unroll
      for (int nf = 0; nf < 4; nf++)
#pragma unroll
        for (int e = 0; e < 4; e++) {
          const int iloc = rs * 16 + 4 * qd + e;
          float s = sa[nf][e];
          if (diag) {
            int dl = (j0 + 16 * nf + r) - (i0w + iloc);
            bool inb = (unsigned)(dl + Wz) <= 2u * Wz;
            if (inb) s += rqs[iloc * 22 + dl + Wz];
            if (qm[rs][e] * km4[nf] == 0.f) s = -1e4f;
            if (inb) bands[iloc * 22 + dl + Wz] = s;
          } else {
            if (qm[rs][e] * km4[nf] == 0.f) s = -1e4f;
          }
          float p = __expf(s - MFIX);
          lacc[rs][e] += p;
          Pp[iloc * 72 + 16 * nf + r] = bf_rne(p);
        }
    }
#pragma unroll
    for (int rs = 0; rs < 2; rs++)
#pragma unroll
      for (int ks = 0; ks < 2; ks++) {
        bf8v Ph = *(bf8v*)&Pp[(rs * 16 + r) * 72 + ks * 32 + qd * 8];
#pragma unroll
        for (int nf = 0; nf < 4; nf++)
          oacc[rs][nf] = MFMA(Ph, vh[nf][ks], oacc[rs][nf]);
      }
  }

  for (int t = lane; t < 32 * 32; t += 64) {
    int i = t >> 5, rr = t & 31;
    float p = (rr < NR) ? __expf(bands[i * 22 + rr] - MFIX) : 0.f;
    Pp[i * 72 + rr] = bf_rne(p);
  }
#pragma unroll
  for (int rs = 0; rs < 2; rs++) {
    bf8v Ph = *(bf8v*)&Pp[(rs * 16 + r) * 72 + qd * 8];
#pragma unroll
    for (int nf = 0; nf < 4; nf++) {
      bf8v eh = *(const bf8v*)&ervH[(16 * nf + r) * 32 + qd * 8];
      oacc[rs][nf] = MFMA(Ph, eh, oacc[rs][nf]);
    }
  }

#pragma unroll
  for (int off = 1; off < 16; off <<= 1)
#pragma unroll
    for (int rs = 0; rs < 2; rs++)
#pragma unroll
      for (int e = 0; e < 4; e++)
        lacc[rs][e] += __shfl_xor(lacc[rs][e], off, 16);
  if (r == 0) {
#pragma unroll
    for (int rs = 0; rs < 2; rs++)
#pragma unroll
      for (int e = 0; e < 4; e++)
        lp[(size_t)bh * Tz + i0w + rs * 16 + 4 * qd + e] = lacc[rs][e];
  }

  float* Os = (float*)Pp;  // [32][68]
#pragma unroll
  for (int rs = 0; rs < 2; rs++)
#pragma unroll
    for (int nf = 0; nf < 4; nf++)
#pragma unroll
      for (int e = 0; e < 4; e++)
        Os[(rs * 16 + 4 * qd + e) * 68 + 16 * nf + r] = oacc[rs][nf][e];
#pragma unroll
  for (int rs = 0; rs < 2; rs++) {
    const float* src = &Os[(rs * 16 + r) * 68 + qd * 16];
    size_t oa = ((size_t)bh * Tz + i0w + rs * 16 + r) * KCz + qd * 16;
#pragma unroll
    for (int jj = 0; jj < 4; jj++)
      *(float4*)&Op[oa + jj * 4] = *(const float4*)&src[jj * 4];
  }
}

// ---------------------------------------------------------------------------
// Fused residual + channel LayerNorm + transpose-pack (single bf16 out).
// 8 t-cols/block, grid (128, B) = 512 blocks (2/CU); wave-0 shfl reduce.
// VAR 1 (NP partials, mask): x = LN(x + (sum(parts) + cbias)*mask)  [conv2]
// VAR 2 (NP partials, no mask): x = LN(x + sum(parts) + cbias)      [wo]
// ---------------------------------------------------------------------------
template <int VAR, int NP>
__global__ __launch_bounds__(256) void fused_ln(
    float* __restrict__ x, const float* __restrict__ y,
    const float* __restrict__ p1, const float* __restrict__ p2,
    const float* __restrict__ p3, const float* __restrict__ cbias,
    const float* __restrict__ g, const float* __restrict__ bb,
    const float* __restrict__ mask, u16* __restrict__ dhi) {
  __shared__ float L[256 * 9];
  __shared__ float red[32][8], red2[32][8];
  __shared__ float ms[8], rs[8];
  const int tid = threadIdx.x;
  const int t0 = blockIdx.x * 8, b = blockIdx.y;
  const int tl = tid & 7, grp = tid >> 3;  // 32 c-groups of 8 t-cols
  const size_t bx = (size_t)b * Cz * TS + PADF + t0 + tl;
  const size_t by = (size_t)b * Cz * Tz + t0 + tl;
  const float mv = mask[(size_t)b * Tz + t0 + tl];
  float s = 0.f, sq = 0.f;
#pragma unroll
  for (int i = 0; i < 8; i++) {
    int c = grp + i * 32;
    float add = y[by + (size_t)c * Tz] + p1[by + (size_t)c * Tz] + cbias[c];
    if constexpr (NP == 4)
      add += p2[by + (size_t)c * Tz] + p3[by + (size_t)c * Tz];
    if constexpr (VAR == 1) add *= mv;
    float v = x[bx + (size_t)c * TS] + add;
    L[c * 9 + tl] = v;
    s += v;
    sq += v * v;
  }
  red[grp][tl] = s;
  red2[grp][tl] = sq;
  __syncthreads();
  if (tid < 64) {
    const int j = tid >> 3, tt = tid & 7;
    float su = red[j][tt] + red[j + 8][tt] + red[j + 16][tt] + red[j + 24][tt];
    float sqq =
        red2[j][tt] + red2[j + 8][tt] + red2[j + 16][tt] + red2[j + 24][tt];
    su += __shfl_xor(su, 8);
    su += __shfl_xor(su, 16);
    su += __shfl_xor(su, 32);
    sqq += __shfl_xor(sqq, 8);
    sqq += __shfl_xor(sqq, 16);
    sqq += __shfl_xor(sqq, 32);
    if (j == 0) {
      float m = su * (1.f / Cz);
      ms[tt] = m;
      rs[tt] = rsqrtf(sqq * (1.f / Cz) - m * m + 1e-5f);
    }
  }
  __syncthreads();
  const float m = ms[tl], r = rs[tl];
#pragma unroll
  for (int i = 0; i < 8; i++) {
    int c = grp + i * 32;
    float v = (L[c * 9 + tl] - m) * r * g[c] + bb[c];
    x[bx + (size_t)c * TS] = v;
    L[c * 9 + tl] = v * mv;
  }
  __syncthreads();
  const int tt = tid & 7, p = tid >> 3;  // 32 segs of 8 channels
  u16 hs[8];
#pragma unroll
  for (int j = 0; j < 8; j++) hs[j] = bf_rne(L[(p * 8 + j) * 9 + tt]);
  size_t da = ((size_t)b * PROWS + t0 + tt + 1) * Cz + p * 8;
  *(uint4*)&dhi[da] = *(uint4*)&hs[0];
}

// ---------------------------------------------------------------------------
extern "C" void kernel_launch(void* const* d_in, const int* in_sizes, int n_in,
                              void* d_out, int out_size, void* d_ws,
                              size_t ws_size, hipStream_t stream) {
  const float* x = (const float*)d_in[0];
  const float* xm = (const float*)d_in[1];
  const float* wq = (const float*)d_in[2];
  const float* bq = (const float*)d_in[3];
  const float* wk = (const float*)d_in[4];
  const float* bk = (const float*)d_in[5];
  const float* wv = (const float*)d_in[6];
  const float* bv = (const float*)d_in[7];
  const float* wo = (const float*)d_in[8];
  const float* bo = (const float*)d_in[9];
  const float* erk = (const float*)d_in[10];
  const float* erv = (const float*)d_in[11];
  const float* g1 = (const float*)d_in[12];
  const float* b1 = (const float*)d_in[13];
  const float* fw1 = (const float*)d_in[14];
  const float* fb1 = (const float*)d_in[15];
  const float* fw2 = (const float*)d_in[16];
  const float* fb2 = (const float*)d_in[17];
  const float* g2 = (const float*)d_in[18];
  const float* b2 = (const float*)d_in[19];

  const size_t NBC = (size_t)Bz * Cz * Tz;       // 1,048,576
  const size_t XBN = (size_t)Bz * Cz * TS;       // 1,056,768
  const size_t HP = (size_t)Bz * PROWS * FCz;    // 4,202,496 u16/array
  const size_t XP = (size_t)Bz * PROWS * Cz;     // 1,050,624 u16/array
  const size_t QS = (size_t)Bz * Hz * Tz * KCz;  // 1,048,576 u16/array

  float* ws = (float*)d_ws;
  float* xb = ws;
  float* yb = xb + XBN;   // attn partial O0
  float* p1 = yb + NBC;   // O1
  float* p2 = p1 + NBC;   // O2
  float* p3 = p2 + NBC;   // O3
  float* unf = p3 + NBC;  // union: Q/K/V packed OR wo outputs OR FFN hidden
  u16* hpH = (u16*)unf;   // single-bf16 hidden
  u16* Qh = (u16*)unf;
  u16* Kh = Qh + QS;
  u16* Vh = Kh + QS;
  float* wo0 = unf;        // wo k-half 0 output (over dead Qh/Kh, 4 MB)
  float* wo1 = unf + NBC;  // wo k-half 1 output (over dead Vh + pad, 4 MB)
  float* xpf = unf + HP;
  u16* xpH = (u16*)xpf;    // single bf16 (lo slot dead)
  float* qwf = xpf + XP;
  u16* qwAll = (u16*)qwf;  // 6 x 262144 u16
  float* w1f = qwf + 786432;
  u16* w1All = (u16*)w1f;  // 6 x 786432 u16
  float* w2f = w1f + 2359296;
  u16* w2All = (u16*)w2f;  // 6 x 786432 u16
  float* erf = w2f + 2359296;
  u16* ekAll = (u16*)erf;      // 6 x 2048 u16
  u16* evAll = ekAll + 12288;  // 6 x 2048 u16
  float* pbAll = erf + 12288;  // 6 x 1024 f32
  float* lb0 = pbAll + 6144;
  float* lb1 = lb0 + 16384;
  float* lb2 = lb1 + 16384;
  float* lb3 = lb2 + 16384;

  const int ntot = (int)NBC;
  pack_all<<<dim3(6 * 7184), 256, 0, stream>>>(
      wq, wk, wv, wo, bq, bk, bv, bo, erk, erv, fw1, fw2, qwAll, pbAll, ekAll,
      evAll, w1All, w2All);
  tpack<<<dim3(16, 4, 4), 256, 0, stream>>>(x, xm, xb, xpH, Cz);

  for (int l = 0; l < Lz; l++) {
    qkv_gemm<<<dim3(16, 12, 4), 256, 0, stream>>>(
        qwAll + (size_t)l * 262144, xpH, pbAll + l * 1024, Qh, Kh, Vh, 1024,
        Cz);
    attn_mfma<<<dim3(1024), 128, 0, stream>>>(
        Qh, Kh, Vh, xm, ekAll + l * 2048, evAll + l * 2048, yb, p1, p2, p3,
        lb0, lb1, lb2, lb3);
    // wo GEMM with fused combine (single-bf16 B): Q/K/V dead after attn.
    wo_gemm<<<dim3(16, 8, 4), 256, 0, stream>>>(
        qwAll + (size_t)l * 262144, pbAll + l * 1024, wo0, wo1, yb, p1, p2,
        p3, lb0, lb1, lb2, lb3, 1024, Cz, 768);
    fused_ln<2, 2><<<dim3(128, 4), 256, 0, stream>>>(
        xb, wo0, wo1, nullptr, nullptr, bo + l * Cz, g1 + l * Cz, b1 + l * Cz,
        xm, xpH);
    conv_mfma<1><<<dim3(8, 16, 4), 256, 0, stream>>>(
        w1All + (size_t)l * 786432, xpH, fb1 + l * FCz, xm, hpH, nullptr,
        nullptr, nullptr, nullptr, FCz, Cz);
    conv_mfma<3><<<dim3(8, 16, 4), 256, 0, stream>>>(
        w2All + (size_t)l * 786432, hpH, nullptr, xm, nullptr, yb, p1, p2,
        p3, Cz, FCz);
    fused_ln<1, 4><<<dim3(128, 4), 256, 0, stream>>>(
        xb, yb, p1, p2, p3, fb2 + l * Cz, g2 + l * Cz, b2 + l * Cz, xm, xpH);
  }
  mask_out<<<dim3((ntot + 255) / 256), 256, 0, stream>>>(xb, xm,
                                                         (float*)d_out);
}

// Round 15
// 874.156 us; speedup vs baseline: 1.1320x; 1.0285x over previous
//
#include <hip/hip_runtime.h>

// Encoder: L=6 layers of (rel-pos attention + channel-LN + K=3 conv FFN + LN)
// B=4, C=256, T=1024, H=4, KC=64, FC=1024, W=10, fp32 I/O.
// ROUND 15 (= R14 resubmit after infra failure): ALL inter-kernel f32
// partials -> bf16 (attn O0..3, wo k-halves, conv2 k-split partials):
// saves ~40MB/layer HBM round-trip + halves the consumer staging loads.
// One extra 2^-9 rounding per site, LN renormalizes.
// Base R13 (899us): single-bf16 everything else, fused combines, qkv
// launch_bounds(256,3), halo-predicated convs, tap-shared staging.

#define Lz 6
#define Cz 256
#define FCz 1024
#define Hz 4
#define Wz 10
#define Bz 4
#define Tz 1024
#define KCz 64
#define NR 21
#define TS 1032
#define PADF 4
#define PROWS 1026
#define MFIX 8.0f

typedef unsigned short u16;
typedef unsigned int u32;
typedef __attribute__((ext_vector_type(8))) short bf8v;
typedef __attribute__((ext_vector_type(4))) float f4v;

#define MFMA(a, b, c) __builtin_amdgcn_mfma_f32_16x16x32_bf16(a, b, c, 0, 0, 0)

__device__ inline u16 bf_rne(float v) {
  u32 u = __float_as_uint(v);
  return (u16)((u + 0x7FFFu + ((u >> 16) & 1u)) >> 16);
}

__device__ inline float bf2f(u16 h) {
  return __uint_as_float((u32)h << 16);
}

// ---------------------------------------------------------------------------
__global__ __launch_bounds__(256) void mask_out(const float* __restrict__ xp,
                                                const float* __restrict__ m,
                                                float* __restrict__ out) {
  int id = blockIdx.x * 256 + threadIdx.x;
  if (id < Bz * Cz * Tz) {
    int t = id & (Tz - 1), row = id >> 10, b = id >> 18;
    out[id] = xp[(size_t)row * TS + PADF + t] * m[b * Tz + t];
  }
}

// ---------------------------------------------------------------------------
// Fused mask_in + transpose-pack: reads x [b][c][Tz] + mask, writes
// xb = x*m (TS-padded layout) AND packed single-bf16 [b][1026][Cd] of (x*m)*m.
// ---------------------------------------------------------------------------
__global__ __launch_bounds__(256) void tpack(const float* __restrict__ xsrc,
                                             const float* __restrict__ mask,
                                             float* __restrict__ xb,
                                             u16* __restrict__ dhi, int Cd) {
  __shared__ float L[64 * 68];
  const int tid = threadIdx.x;
  const int t0 = blockIdx.x * 64, c0 = blockIdx.y * 64, b = blockIdx.z;
#pragma unroll
  for (int i = 0; i < 16; i++) {
    int id = tid + 256 * i;
    int cc = id >> 6, tt = id & 63;
    float mv = mask[(size_t)b * Tz + t0 + tt];
    float v = xsrc[((size_t)(b * Cz + c0 + cc)) * Tz + t0 + tt] * mv;
    xb[((size_t)(b * Cz + c0 + cc)) * TS + PADF + t0 + tt] = v;
    L[cc * 68 + tt] = v;
  }
  __syncthreads();
  const int tt = tid >> 2, p = tid & 3;
  float mv = mask[(size_t)b * Tz + t0 + tt];
  u16 hs[16];
#pragma unroll
  for (int j = 0; j < 16; j++)
    hs[j] = bf_rne(L[(p * 16 + j) * 68 + tt] * mv);
  size_t da = ((size_t)b * PROWS + t0 + tt + 1) * Cd + c0 + p * 16;
  *(uint4*)&dhi[da] = *(uint4*)&hs[0];
  *(uint4*)&dhi[da + 8] = *(uint4*)&hs[8];
}

// ---------------------------------------------------------------------------
// Pack ALL layers' weights in one launch. grid = 6 * 7184 blocks.
// ---------------------------------------------------------------------------
__global__ __launch_bounds__(256) void pack_all(
    const float* __restrict__ wq, const float* __restrict__ wk,
    const float* __restrict__ wv, const float* __restrict__ wo_,
    const float* __restrict__ bq, const float* __restrict__ bk,
    const float* __restrict__ bv, const float* __restrict__ bo,
    const float* __restrict__ erk, const float* __restrict__ erv,
    const float* __restrict__ fw1, const float* __restrict__ fw2,
    u16* __restrict__ qwAll, float* __restrict__ pbAll,
    u16* __restrict__ ekAll, u16* __restrict__ evAll,
    u16* __restrict__ w1All, u16* __restrict__ w2All) {
  const int blk = blockIdx.x, tid = threadIdx.x;
  const int layer = blk / 7184;
  const int bl = blk % 7184;
  if (bl < 1024) {
    int id = bl * 256 + tid;
    int o = id >> 8, c = id & 255;
    int sel = o >> 8;
    const size_t wof = (size_t)layer * Cz * Cz;
    const float* w = sel == 0 ? wq + wof
                              : (sel == 1 ? wk + wof
                                          : (sel == 2 ? wv + wof : wo_ + wof));
    qwAll[(size_t)layer * 262144 + id] = bf_rne(w[((o & 255) << 8) + c]);
    if (id < 1024) {
      int s2 = id >> 8;
      const float* bs = s2 == 0 ? bq : (s2 == 1 ? bk : (s2 == 2 ? bv : bo));
      pbAll[layer * 1024 + id] = bs[layer * Cz + (id & 255)];
    }
  } else if (bl < 1040) {
    int id = (bl - 1024) * 256 + tid;
    if (id < 2048) {
      int rr = id >> 6, d = id & 63;
      ekAll[layer * 2048 + id] =
          bf_rne((rr < NR) ? erk[(size_t)layer * NR * KCz + rr * KCz + d]
                           : 0.f);
    } else {
      int id2 = id - 2048;
      int d = id2 >> 5, rr = id2 & 31;
      evAll[layer * 2048 + id2] =
          bf_rne((rr < NR) ? erv[(size_t)layer * NR * KCz + rr * KCz + d]
                           : 0.f);
    }
  } else if (bl < 4112) {
    int id = (bl - 1040) * 256 + tid;
    int c = id % Cz;
    int rest = id / Cz;
    int o = rest % FCz, tap = rest / FCz;
    w1All[(size_t)layer * 786432 + id] =
        bf_rne(fw1[(size_t)layer * FCz * Cz * 3 + ((size_t)o * Cz + c) * 3 +
                   tap]);
  } else {
    int id = (bl - 4112) * 256 + tid;
    int c = id % FCz;
    int rest = id / FCz;
    int o = rest % Cz, tap = rest / Cz;
    w2All[(size_t)layer * 786432 + id] =
        bf_rne(fw2[(size_t)layer * Cz * FCz * 3 + ((size_t)o * FCz + c) * 3 +
                   tap]);
  }
}

// ---------------------------------------------------------------------------
// MFMA GEMM body (A,B single bf16). Tile 64x64.
// EPI 0: B = packed acts; qkv -> Q (x0.125), K (t-major), V (kc-major).
// EPI 3: wo, K-split-2; B staged single bf16 from bf16 attn partials (fused
//        combine); outputs bf16 k-half partials.
// ---------------------------------------------------------------------------
template <int EPI>
static __device__ __forceinline__ void gemm_body(
    const u16* __restrict__ Ah, const u16* __restrict__ Bh,
    const float* __restrict__ bias, u16* __restrict__ out,
    u16* __restrict__ out2, u16* __restrict__ pqh, u16* __restrict__ pkh,
    u16* __restrict__ pvh, const u16* __restrict__ Ox0,
    const u16* __restrict__ Ox1, const u16* __restrict__ Ox2,
    const u16* __restrict__ Ox3, const float* __restrict__ sl0,
    const float* __restrict__ sl1, const float* __restrict__ sl2,
    const float* __restrict__ sl3, int M, int Kc, int m_base, char* smraw) {
  u16* Ash = (u16*)smraw;
  u16* Bsh = Ash + 2560;
  const int tid = threadIdx.x;
  const int lane = tid & 63, wid = tid >> 6;
  const int wm = wid & 1, wn = wid >> 1;
  const int r = lane & 15, qd = lane >> 4;
  const int t0 = blockIdx.x * 64;
  const int b = blockIdx.z;
  const int srow = tid >> 2, sseg = (tid & 3) * 8;

  int m0, kc0, kcN;
  u16* outp = out;
  if constexpr (EPI == 3) {
    m0 = m_base + (blockIdx.y >> 1) * 64;
    kc0 = (blockIdx.y & 1) * (Kc / 2);
    kcN = Kc / 2;
    outp = (blockIdx.y & 1) ? out2 : out;
  } else {
    m0 = blockIdx.y * 64 + m_base;
    kc0 = 0;
    kcN = Kc;
  }

  f4v acc[2][2];
#pragma unroll
  for (int i = 0; i < 2; i++)
#pragma unroll
    for (int j = 0; j < 2; j++) acc[i][j] = (f4v)(0.f);

  const size_t arow = (size_t)(m0 + srow) * Kc + kc0;
  const size_t brow = ((size_t)b * PROWS + t0 + 1 + srow) * Kc + kc0;
  for (int kc = 0; kc < kcN; kc += 32) {
    *(uint4*)&Ash[srow * 40 + sseg] = *(const uint4*)&Ah[arow + kc + sseg];
    if constexpr (EPI == 3) {
      // fused attn_combine (bf16 partials): row t = t0+srow, cols cc..cc+7
      const int cc = kc0 + kc + sseg;
      const int hh = cc >> 6, dd = cc & 63;
      const size_t lbi = (size_t)(b * Hz + hh) * Tz + t0 + srow;
      const size_t ob = lbi * KCz + dd;
      uint4 u0 = *(const uint4*)&Ox0[ob];
      uint4 u1 = *(const uint4*)&Ox1[ob];
      uint4 u2 = *(const uint4*)&Ox2[ob];
      uint4 u3 = *(const uint4*)&Ox3[ob];
      const u16* q0 = (const u16*)&u0;
      const u16* q1 = (const u16*)&u1;
      const u16* q2 = (const u16*)&u2;
      const u16* q3 = (const u16*)&u3;
      const float li = 1.f / (sl0[lbi] + sl1[lbi] + sl2[lbi] + sl3[lbi]);
      u16 hhs[8];
#pragma unroll
      for (int e = 0; e < 8; e++)
        hhs[e] = bf_rne(
            (bf2f(q0[e]) + bf2f(q1[e]) + bf2f(q2[e]) + bf2f(q3[e])) * li);
      *(uint4*)&Bsh[srow * 40 + sseg] = *(uint4*)&hhs[0];
    } else {
      *(uint4*)&Bsh[srow * 40 + sseg] = *(const uint4*)&Bh[brow + kc + sseg];
    }
    __syncthreads();
    bf8v ah[2], bh2[2];
#pragma unroll
    for (int f = 0; f < 2; f++) {
      int ar = (wm * 32 + f * 16 + r) * 40 + qd * 8;
      int br = (wn * 32 + f * 16 + r) * 40 + qd * 8;
      ah[f] = *(bf8v*)&Ash[ar];
      bh2[f] = *(bf8v*)&Bsh[br];
    }
#pragma unroll
    for (int mf = 0; mf < 2; mf++)
#pragma unroll
      for (int nf = 0; nf < 2; nf++)
        acc[mf][nf] = MFMA(ah[mf], bh2[nf], acc[mf][nf]);
    __syncthreads();
  }

  float* Ds = (float*)smraw;
  if constexpr (EPI == 0) {
    const int sel = m0 >> 8;
    const int h = (m0 >> 6) & 3;
    const int bhI = b * Hz + h;
    if (sel < 2) {
#pragma unroll
      for (int mf = 0; mf < 2; mf++)
#pragma unroll
        for (int nf = 0; nf < 2; nf++) {
          int nl = wn * 32 + nf * 16 + r;
          int ml = wm * 32 + mf * 16 + qd * 4;
          *(f4v*)&Ds[nl * 68 + ml] = acc[mf][nf];
        }
      __syncthreads();
      const int row = tid >> 2, p = tid & 3;
      size_t da = ((size_t)bhI * Tz + t0 + row) * KCz + p * 16;
      const float sc = (sel == 0) ? 0.125f : 1.0f;
      u16* dst = (sel == 0) ? pqh : pkh;
      u16 hs[16];
#pragma unroll
      for (int jj = 0; jj < 4; jj++) {
        float4 dv = *(float4*)&Ds[row * 68 + p * 16 + jj * 4];
        float4 bb = *(const float4*)&bias[m0 + p * 16 + jj * 4];
        hs[jj * 4 + 0] = bf_rne((dv.x + bb.x) * sc);
        hs[jj * 4 + 1] = bf_rne((dv.y + bb.y) * sc);
        hs[jj * 4 + 2] = bf_rne((dv.z + bb.z) * sc);
        hs[jj * 4 + 3] = bf_rne((dv.w + bb.w) * sc);
      }
      *(uint4*)&dst[da] = *(uint4*)&hs[0];
      *(uint4*)&dst[da + 8] = *(uint4*)&hs[8];
    } else {
#pragma unroll
      for (int mf = 0; mf < 2; mf++)
#pragma unroll
        for (int nf = 0; nf < 2; nf++) {
          int ml = wm * 32 + mf * 16 + qd * 4;
          int nl = wn * 32 + nf * 16 + r;
#pragma unroll
          for (int e = 0; e < 4; e++) Ds[(ml + e) * 68 + nl] = acc[mf][nf][e];
        }
      __syncthreads();
      const int row = tid >> 2, p = tid & 3;
      const float bb = bias[m0 + row];
      u16 hs[16];
#pragma unroll
      for (int jj = 0; jj < 16; jj++)
        hs[jj] = bf_rne(Ds[row * 68 + p * 16 + jj] + bb);
      size_t da = ((size_t)bhI * KCz + row) * Tz + t0 + p * 16;
      *(uint4*)&pvh[da] = *(uint4*)&hs[0];
      *(uint4*)&pvh[da + 8] = *(uint4*)&hs[8];
    }
  } else {
#pragma unroll
    for (int mf = 0; mf < 2; mf++)
#pragma unroll
      for (int nf = 0; nf < 2; nf++) {
        int ml = wm * 32 + mf * 16 + qd * 4;
        int nl = wn * 32 + nf * 16 + r;
#pragma unroll
        for (int e = 0; e < 4; e++) Ds[(ml + e) * 68 + nl] = acc[mf][nf][e];
      }
    __syncthreads();
    const int row = tid >> 2, p = tid & 3;
    size_t oa = ((size_t)b * Cz + (m0 - m_base) + row) * Tz + t0 + p * 16;
    u16 hs[16];
#pragma unroll
    for (int jj = 0; jj < 16; jj++)
      hs[jj] = bf_rne(Ds[row * 68 + p * 16 + jj]);
    *(uint4*)&outp[oa] = *(uint4*)&hs[0];
    *(uint4*)&outp[oa + 8] = *(uint4*)&hs[8];
  }
}

// qkv wrapper: (256,3) -> 3 blocks/CU, 768-block grid co-resident.
__global__ __launch_bounds__(256, 3) void qkv_gemm(
    const u16* __restrict__ Ah, const u16* __restrict__ Bh,
    const float* __restrict__ bias, u16* __restrict__ pqh,
    u16* __restrict__ pkh, u16* __restrict__ pvh, int M, int Kc) {
  __shared__ __align__(16) char smraw[17408];
  gemm_body<0>(Ah, Bh, bias, nullptr, nullptr, pqh, pkh, pvh, nullptr,
               nullptr, nullptr, nullptr, nullptr, nullptr, nullptr, nullptr,
               M, Kc, 0, smraw);
}

// wo wrapper: unconstrained (fused-combine epilogue).
__global__ __launch_bounds__(256) void wo_gemm(
    const u16* __restrict__ Ah, const float* __restrict__ bias,
    u16* __restrict__ out, u16* __restrict__ out2,
    const u16* __restrict__ Ox0, const u16* __restrict__ Ox1,
    const u16* __restrict__ Ox2, const u16* __restrict__ Ox3,
    const float* __restrict__ sl0, const float* __restrict__ sl1,
    const float* __restrict__ sl2, const float* __restrict__ sl3, int M,
    int Kc, int m_base) {
  __shared__ __align__(16) char smraw[17408];
  gemm_body<3>(Ah, nullptr, bias, out, out2, nullptr, nullptr, nullptr, Ox0,
               Ox1, Ox2, Ox3, sl0, sl1, sl2, sl3, M, Kc, m_base, smraw);
}

// ---------------------------------------------------------------------------
// Conv (K=3) as MFMA GEMM, 64m x 128t tile, 4 waves = 4 t-strips.
// SINGLE-bf16 B both convs (1-pass MFMA). Tap-shared B staging; reg-prefetch.
// Halo rows (prow 0 / 1025) zero-predicated in staging.
// EPI 1: conv1: B = xp single; out +bias,relu,mask -> single bf16 hidden.
// EPI 3: conv2: B = hp single; K-split x4 -> bf16 partials o0..o3.
// ---------------------------------------------------------------------------
template <int EPI>
__global__ __launch_bounds__(256, 2) void conv_mfma(
    const u16* __restrict__ Ah, const u16* __restrict__ Bh,
    const float* __restrict__ bias, const float* __restrict__ mask,
    u16* __restrict__ ph, u16* __restrict__ o0, u16* __restrict__ o1,
    u16* __restrict__ o2, u16* __restrict__ o3, int M, int Kc) {
  __shared__ __align__(16) char smraw[36480];
  u16* Ash = (u16*)smraw;        // [3][64][40]
  u16* Bsh = Ash + 3 * 64 * 40;  // [132][40] (130 rows used)
  const int tid = threadIdx.x;
  const int lane = tid & 63, wn = tid >> 6;  // 4 waves: t-strip wn*32
  const int r = lane & 15, qd = lane >> 4;
  const int t0 = blockIdx.x * 128;
  const int b = blockIdx.z;

  int m0, kc0, kcN;
  u16* outp = nullptr;
  if constexpr (EPI == 3) {
    int mt = blockIdx.y >> 2, sp = blockIdx.y & 3;
    m0 = mt * 64;
    kc0 = sp * (Kc / 4);
    kcN = Kc / 4;
    outp = sp == 0 ? o0 : (sp == 1 ? o1 : (sp == 2 ? o2 : o3));
  } else {
    m0 = blockIdx.y * 64;
    kc0 = 0;
    kcN = Kc;
  }

  const int srow = tid >> 2, sseg = (tid & 3) * 8;  // rows 0..63
  const bool btail = tid < 8;                       // B rows 128..129
  const int brow2 = 128 + (tid >> 2);
  const bool h0 = (t0 + srow == 0);
  const bool hT = btail && (t0 + brow2 == PROWS - 1);
  const uint4 z4 = {0u, 0u, 0u, 0u};

  f4v acc[4][2];
#pragma unroll
  for (int i = 0; i < 4; i++)
#pragma unroll
    for (int j = 0; j < 2; j++) acc[i][j] = (f4v)(0.f);

  const size_t abase = (size_t)(m0 + srow) * Kc + kc0 + sseg;
  const size_t bbase = ((size_t)b * PROWS + t0 + srow) * Kc + kc0 + sseg;
  const size_t bbase64 = bbase + (size_t)64 * Kc;
  const size_t bbaseT = ((size_t)b * PROWS + t0 + brow2) * Kc + kc0 + sseg;

  uint4 ar[3], bh0, bh1, bht;
  auto LOADR = [&](int kc) {
#pragma unroll
    for (int tp = 0; tp < 3; tp++)
      ar[tp] = *(const uint4*)&Ah[(size_t)tp * M * Kc + abase + kc];
    bh0 = *(const uint4*)&Bh[bbase + kc];
    bh1 = *(const uint4*)&Bh[bbase64 + kc];
    if (h0) bh0 = z4;
    if (btail) {
      bht = *(const uint4*)&Bh[bbaseT + kc];
      if (hT) bht = z4;
    }
  };

  LOADR(0);
  for (int kc = 0; kc < kcN; kc += 32) {
#pragma unroll
    for (int tp = 0; tp < 3; tp++)
      *(uint4*)&Ash[(tp * 64 + srow) * 40 + sseg] = ar[tp];
    *(uint4*)&Bsh[srow * 40 + sseg] = bh0;
    *(uint4*)&Bsh[(srow + 64) * 40 + sseg] = bh1;
    if (btail) *(uint4*)&Bsh[brow2 * 40 + sseg] = bht;
    __syncthreads();
    if (kc + 32 < kcN) LOADR(kc + 32);  // prefetch next chunk
#pragma unroll
    for (int tap = 0; tap < 3; tap++) {
      bf8v ah[4], bh2[2];
#pragma unroll
      for (int mf = 0; mf < 4; mf++)
        ah[mf] = *(bf8v*)&Ash[(tap * 64 + mf * 16 + r) * 40 + qd * 8];
#pragma unroll
      for (int nf = 0; nf < 2; nf++)
        bh2[nf] = *(bf8v*)&Bsh[(wn * 32 + nf * 16 + r + tap) * 40 + qd * 8];
#pragma unroll
      for (int mf = 0; mf < 4; mf++)
#pragma unroll
        for (int nf = 0; nf < 2; nf++)
          acc[mf][nf] = MFMA(ah[mf], bh2[nf], acc[mf][nf]);
    }
    __syncthreads();
  }

  // acc[mf][nf][e]: m = mf*16 + qd*4 + e, t = wn*32 + nf*16 + r
  if constexpr (EPI == 1) {
    float* Ds = (float*)smraw;  // [t 128][m 68]
#pragma unroll
    for (int mf = 0; mf < 4; mf++)
#pragma unroll
      for (int nf = 0; nf < 2; nf++) {
        int tl = wn * 32 + nf * 16 + r;
        int ml = mf * 16 + qd * 4;
        *(f4v*)&Ds[tl * 68 + ml] = acc[mf][nf];
      }
    __syncthreads();
    const int row = tid >> 1, half = (tid & 1) * 32;
    const int t = t0 + row;
    const float mv = mask[(size_t)b * Tz + t];
    u16 hs[32];
#pragma unroll
    for (int j = 0; j < 32; j += 4) {
      float4 dv = *(float4*)&Ds[row * 68 + half + j];
      float4 bb = *(const float4*)&bias[m0 + half + j];
      hs[j + 0] = bf_rne(fmaxf(dv.x + bb.x, 0.f) * mv);
      hs[j + 1] = bf_rne(fmaxf(dv.y + bb.y, 0.f) * mv);
      hs[j + 2] = bf_rne(fmaxf(dv.z + bb.z, 0.f) * mv);
      hs[j + 3] = bf_rne(fmaxf(dv.w + bb.w, 0.f) * mv);
    }
    size_t da = ((size_t)b * PROWS + t + 1) * M + m0 + half;
#pragma unroll
    for (int j = 0; j < 32; j += 8) *(uint4*)&ph[da + j] = *(uint4*)&hs[j];
  } else {
    float* Ds = (float*)smraw;  // [m 64][t 132]
#pragma unroll
    for (int mf = 0; mf < 4; mf++)
#pragma unroll
      for (int nf = 0; nf < 2; nf++) {
        int ml = mf * 16 + qd * 4;
        int nl = wn * 32 + nf * 16 + r;
#pragma unroll
        for (int e = 0; e < 4; e++) Ds[(ml + e) * 132 + nl] = acc[mf][nf][e];
      }
    __syncthreads();
    const int row = tid >> 2, seg = (tid & 3) * 32;
    size_t oa = ((size_t)b * Cz + m0 + row) * Tz + t0 + seg;
    u16 hs[32];
#pragma unroll
    for (int j = 0; j < 32; j++) hs[j] = bf_rne(Ds[row * 132 + seg + j]);
#pragma unroll
    for (int j = 0; j < 32; j += 8) *(uint4*)&outp[oa + j] = *(uint4*)&hs[j];
  }
}

// ---------------------------------------------------------------------------
// Barrier-free MFMA flash attention, fixed-max softmax, 32 q-rows/wave,
// j-split x4. Q,K,V,er single bf16: S 1-pass, PV 1-pass. Outputs bf16.
// grid 1024 = 16 bh x 4 splits x 16 i-blocks(64); 128 thr (2 waves).
// ---------------------------------------------------------------------------
__global__ __launch_bounds__(128, 2) void attn_mfma(
    const u16* __restrict__ Qh_, const u16* __restrict__ Kh_,
    const u16* __restrict__ Vh_, const float* __restrict__ mask,
    const u16* __restrict__ erkH, const u16* __restrict__ ervH,
    u16* __restrict__ O0, u16* __restrict__ O1, u16* __restrict__ O2,
    u16* __restrict__ O3, float* __restrict__ lp0, float* __restrict__ lp1,
    float* __restrict__ lp2, float* __restrict__ lp3) {
  __shared__ __align__(16) char smraw[2][14336];
  const int tid = threadIdx.x;
  const int lane = tid & 63, wid = tid >> 6;
  const int r = lane & 15, qd = lane >> 4;
  const int idx = blockIdx.x;
  const int bh = idx & 15;
  const int split = (idx >> 4) & 3;
  const int i0w = (idx >> 6) * 64 + wid * 32;
  const int b = bh >> 2;
  const float* mb = mask + (size_t)b * Tz;
  const size_t qkbase = (size_t)bh * Tz * KCz;
  const size_t vbase = (size_t)bh * KCz * Tz;
  u16* Op = split == 0 ? O0 : (split == 1 ? O1 : (split == 2 ? O2 : O3));
  float* lp = split == 0 ? lp0 : (split == 1 ? lp1 : (split == 2 ? lp2 : lp3));
  const int j0beg = split * 256;

  float* rqs = (float*)(smraw[wid]);      // [32][22]
  float* bands = rqs + 704;               // [32][22]
  u16* Pp = (u16*)(smraw[wid] + 5632);    // [32][72]; reused as Os f32

  bf8v qh[2][2];
#pragma unroll
  for (int rs = 0; rs < 2; rs++) {
    const size_t qrow = qkbase + (size_t)(i0w + rs * 16 + r) * KCz;
#pragma unroll
    for (int ks = 0; ks < 2; ks++)
      qh[rs][ks] = *(const bf8v*)&Qh_[qrow + ks * 32 + qd * 8];
  }
  for (int t = lane; t < 704; t += 64) bands[t] = -1e30f;

#pragma unroll
  for (int rs = 0; rs < 2; rs++) {
    f4v rc[2] = {(f4v)(0.f), (f4v)(0.f)};
#pragma unroll
    for (int nf = 0; nf < 2; nf++)
#pragma unroll
      for (int ks = 0; ks < 2; ks++) {
        bf8v eh = *(const bf8v*)&erkH[(16 * nf + r) * 64 + ks * 32 + qd * 8];
        rc[nf] = MFMA(qh[rs][ks], eh, rc[nf]);
      }
#pragma unroll
    for (int nf = 0; nf < 2; nf++) {
      int rr = 16 * nf + r;
      if (rr < NR) {
#pragma unroll
        for (int e = 0; e < 4; e++)
          rqs[(rs * 16 + 4 * qd + e) * 22 + rr] = rc[nf][e];
      }
    }
  }

  float qm[2][4];
#pragma unroll
  for (int rs = 0; rs < 2; rs++)
#pragma unroll
    for (int e = 0; e < 4; e++) qm[rs][e] = mb[i0w + rs * 16 + 4 * qd + e];

  float lacc[2][4] = {};
  f4v oacc[2][4];
#pragma unroll
  for (int rs = 0; rs < 2; rs++)
#pragma unroll
    for (int nf = 0; nf < 4; nf++) oacc[rs][nf] = (f4v)(0.f);

#pragma unroll 2
  for (int jt = 0; jt < 4; jt++) {
    const int j0 = j0beg + jt * 64;
    bf8v kh[4][2], vh[4][2];
#pragma unroll
    for (int nf = 0; nf < 4; nf++) {
      const size_t kr = qkbase + (size_t)(j0 + 16 * nf + r) * KCz;
      const size_t vr = vbase + (size_t)(16 * nf + r) * Tz + j0;
#pragma unroll
      for (int ks = 0; ks < 2; ks++) {
        kh[nf][ks] = *(const bf8v*)&Kh_[kr + ks * 32 + qd * 8];
        vh[nf][ks] = *(const bf8v*)&Vh_[vr + ks * 32 + qd * 8];
      }
    }
    float km4[4];
#pragma unroll
    for (int nf = 0; nf < 4; nf++) km4[nf] = mb[j0 + 16 * nf + r];

#pragma unroll
    for (int rs = 0; rs < 2; rs++) {
      f4v sa[4];
#pragma unroll
      for (int nf = 0; nf < 4; nf++) sa[nf] = (f4v)(0.f);
#pragma unroll
      for (int nf = 0; nf < 4; nf++)
#pragma unroll
        for (int ks = 0; ks < 2; ks++)
          sa[nf] = MFMA(qh[rs][ks], kh[nf][ks], sa[nf]);
      const int ibase = i0w + rs * 16;
      const bool diag = (j0 + 63 >= ibase - Wz) && (j0 <= ibase + 15 + Wz);
#pragma unroll
      for (int nf = 0; nf < 4; nf++)
#pragma unroll
        for (int e = 0; e < 4; e++) {
          const int iloc = rs * 16 + 4 * qd + e;
          float s = sa[nf][e];
          if (diag) {
            int dl = (j0 + 16 * nf + r) - (i0w + iloc);
            bool inb = (unsigned)(dl + Wz) <= 2u * Wz;
            if (inb) s += rqs[iloc * 22 + dl + Wz];
            if (qm[rs][e] * km4[nf] == 0.f) s = -1e4f;
            if (inb) bands[iloc * 22 + dl + Wz] = s;
          } else {
            if (qm[rs][e] * km4[nf] == 0.f) s = -1e4f;
          }
          float p = __expf(s - MFIX);
          lacc[rs][e] += p;
          Pp[iloc * 72 + 16 * nf + r] = bf_rne(p);
        }
    }
#pragma unroll
    for (int rs = 0; rs < 2; rs++)
#pragma unroll
      for (int ks = 0; ks < 2; ks++) {
        bf8v Ph = *(bf8v*)&Pp[(rs * 16 + r) * 72 + ks * 32 + qd * 8];
#pragma unroll
        for (int nf = 0; nf < 4; nf++)
          oacc[rs][nf] = MFMA(Ph, vh[nf][ks], oacc[rs][nf]);
      }
  }

  for (int t = lane; t < 32 * 32; t += 64) {
    int i = t >> 5, rr = t & 31;
    float p = (rr < NR) ? __expf(bands[i * 22 + rr] - MFIX) : 0.f;
    Pp[i * 72 + rr] = bf_rne(p);
  }
#pragma unroll
  for (int rs = 0; rs < 2; rs++) {
    bf8v Ph = *(bf8v*)&Pp[(rs * 16 + r) * 72 + qd * 8];
#pragma unroll
    for (int nf = 0; nf < 4; nf++) {
      bf8v eh = *(const bf8v*)&ervH[(16 * nf + r) * 32 + qd * 8];
      oacc[rs][nf] = MFMA(Ph, eh, oacc[rs][nf]);
    }
  }

#pragma unroll
  for (int off = 1; off < 16; off <<= 1)
#pragma unroll
    for (int rs = 0; rs < 2; rs++)
#pragma unroll
      for (int e = 0; e < 4; e++)
        lacc[rs][e] += __shfl_xor(lacc[rs][e], off, 16);
  if (r == 0) {
#pragma unroll
    for (int rs = 0; rs < 2; rs++)
#pragma unroll
      for (int e = 0; e < 4; e++)
        lp[(size_t)bh * Tz + i0w + rs * 16 + 4 * qd + e] = lacc[rs][e];
  }

  float* Os = (float*)Pp;  // [32][68]
#pragma unroll
  for (int rs = 0; rs < 2; rs++)
#pragma unroll
    for (int nf = 0; nf < 4; nf++)
#pragma unroll
      for (int e = 0; e < 4; e++)
        Os[(rs * 16 + 4 * qd + e) * 68 + 16 * nf + r] = oacc[rs][nf][e];
#pragma unroll
  for (int rs = 0; rs < 2; rs++) {
    const float* src = &Os[(rs * 16 + r) * 68 + qd * 16];
    u16 hs[16];
#pragma unroll
    for (int j = 0; j < 16; j++) hs[j] = bf_rne(src[j]);
    size_t oa = ((size_t)bh * Tz + i0w + rs * 16 + r) * KCz + qd * 16;
    *(uint4*)&Op[oa] = *(uint4*)&hs[0];
    *(uint4*)&Op[oa + 8] = *(uint4*)&hs[8];
  }
}

// ---------------------------------------------------------------------------
// Fused residual + channel LayerNorm + transpose-pack (bf16 partial inputs).
// 8 t-cols/block, grid (128, B) = 512 blocks (2/CU); wave-0 shfl reduce.
// VAR 1 (NP partials, mask): x = LN(x + (sum(parts) + cbias)*mask)  [conv2]
// VAR 2 (NP partials, no mask): x = LN(x + sum(parts) + cbias)      [wo]
// ---------------------------------------------------------------------------
template <int VAR, int NP>
__global__ __launch_bounds__(256) void fused_ln(
    float* __restrict__ x, const u16* __restrict__ y,
    const u16* __restrict__ p1, const u16* __restrict__ p2,
    const u16* __restrict__ p3, const float* __restrict__ cbias,
    const float* __restrict__ g, const float* __restrict__ bb,
    const float* __restrict__ mask, u16* __restrict__ dhi) {
  __shared__ float L[256 * 9];
  __shared__ float red[32][8], red2[32][8];
  __shared__ float ms[8], rs[8];
  const int tid = threadIdx.x;
  const int t0 = blockIdx.x * 8, b = blockIdx.y;
  const int tl = tid & 7, grp = tid >> 3;  // 32 c-groups of 8 t-cols
  const size_t bx = (size_t)b * Cz * TS + PADF + t0 + tl;
  const size_t by = (size_t)b * Cz * Tz + t0 + tl;
  const float mv = mask[(size_t)b * Tz + t0 + tl];
  float s = 0.f, sq = 0.f;
#pragma unroll
  for (int i = 0; i < 8; i++) {
    int c = grp + i * 32;
    float add =
        bf2f(y[by + (size_t)c * Tz]) + bf2f(p1[by + (size_t)c * Tz]) + cbias[c];
    if constexpr (NP == 4)
      add += bf2f(p2[by + (size_t)c * Tz]) + bf2f(p3[by + (size_t)c * Tz]);
    if constexpr (VAR == 1) add *= mv;
    float v = x[bx + (size_t)c * TS] + add;
    L[c * 9 + tl] = v;
    s += v;
    sq += v * v;
  }
  red[grp][tl] = s;
  red2[grp][tl] = sq;
  __syncthreads();
  if (tid < 64) {
    const int j = tid >> 3, tt = tid & 7;
    float su = red[j][tt] + red[j + 8][tt] + red[j + 16][tt] + red[j + 24][tt];
    float sqq =
        red2[j][tt] + red2[j + 8][tt] + red2[j + 16][tt] + red2[j + 24][tt];
    su += __shfl_xor(su, 8);
    su += __shfl_xor(su, 16);
    su += __shfl_xor(su, 32);
    sqq += __shfl_xor(sqq, 8);
    sqq += __shfl_xor(sqq, 16);
    sqq += __shfl_xor(sqq, 32);
    if (j == 0) {
      float m = su * (1.f / Cz);
      ms[tt] = m;
      rs[tt] = rsqrtf(sqq * (1.f / Cz) - m * m + 1e-5f);
    }
  }
  __syncthreads();
  const float m = ms[tl], r = rs[tl];
#pragma unroll
  for (int i = 0; i < 8; i++) {
    int c = grp + i * 32;
    float v = (L[c * 9 + tl] - m) * r * g[c] + bb[c];
    x[bx + (size_t)c * TS] = v;
    L[c * 9 + tl] = v * mv;
  }
  __syncthreads();
  const int tt = tid & 7, p = tid >> 3;  // 32 segs of 8 channels
  u16 hs[8];
#pragma unroll
  for (int j = 0; j < 8; j++) hs[j] = bf_rne(L[(p * 8 + j) * 9 + tt]);
  size_t da = ((size_t)b * PROWS + t0 + tt + 1) * Cz + p * 8;
  *(uint4*)&dhi[da] = *(uint4*)&hs[0];
}

// ---------------------------------------------------------------------------
extern "C" void kernel_launch(void* const* d_in, const int* in_sizes, int n_in,
                              void* d_out, int out_size, void* d_ws,
                              size_t ws_size, hipStream_t stream) {
  const float* x = (const float*)d_in[0];
  const float* xm = (const float*)d_in[1];
  const float* wq = (const float*)d_in[2];
  const float* bq = (const float*)d_in[3];
  const float* wk = (const float*)d_in[4];
  const float* bk = (const float*)d_in[5];
  const float* wv = (const float*)d_in[6];
  const float* bv = (const float*)d_in[7];
  const float* wo = (const float*)d_in[8];
  const float* bo = (const float*)d_in[9];
  const float* erk = (const float*)d_in[10];
  const float* erv = (const float*)d_in[11];
  const float* g1 = (const float*)d_in[12];
  const float* b1 = (const float*)d_in[13];
  const float* fw1 = (const float*)d_in[14];
  const float* fb1 = (const float*)d_in[15];
  const float* fw2 = (const float*)d_in[16];
  const float* fb2 = (const float*)d_in[17];
  const float* g2 = (const float*)d_in[18];
  const float* b2 = (const float*)d_in[19];

  const size_t NBC = (size_t)Bz * Cz * Tz;       // 1,048,576
  const size_t XBN = (size_t)Bz * Cz * TS;       // 1,056,768
  const size_t HP = (size_t)Bz * PROWS * FCz;    // 4,202,496 u16/array
  const size_t XP = (size_t)Bz * PROWS * Cz;     // 1,050,624 u16/array
  const size_t QS = (size_t)Bz * Hz * Tz * KCz;  // 1,048,576 u16/array

  float* ws = (float*)d_ws;
  float* xb = ws;
  float* yb = xb + XBN;   // partial region 0 (O0 / conv2 p0, bf16)
  float* p1 = yb + NBC;   // partial 1
  float* p2 = p1 + NBC;   // partial 2
  float* p3 = p2 + NBC;   // partial 3
  float* unf = p3 + NBC;  // union: Q/K/V packed OR wo outputs OR FFN hidden
  u16* hpH = (u16*)unf;   // single-bf16 hidden
  u16* Qh = (u16*)unf;
  u16* Kh = Qh + QS;
  u16* Vh = Kh + QS;
  u16* wo0 = (u16*)unf;        // wo k-half 0 (bf16, over dead Qh)
  u16* wo1 = (u16*)unf + NBC;  // wo k-half 1 (bf16, over dead Kh)
  float* xpf = unf + HP;
  u16* xpH = (u16*)xpf;  // single bf16
  float* qwf = xpf + XP;
  u16* qwAll = (u16*)qwf;  // 6 x 262144 u16
  float* w1f = qwf + 786432;
  u16* w1All = (u16*)w1f;  // 6 x 786432 u16
  float* w2f = w1f + 2359296;
  u16* w2All = (u16*)w2f;  // 6 x 786432 u16
  float* erf = w2f + 2359296;
  u16* ekAll = (u16*)erf;      // 6 x 2048 u16
  u16* evAll = ekAll + 12288;  // 6 x 2048 u16
  float* pbAll = erf + 12288;  // 6 x 1024 f32
  float* lb0 = pbAll + 6144;
  float* lb1 = lb0 + 16384;
  float* lb2 = lb1 + 16384;
  float* lb3 = lb2 + 16384;

  u16* O0 = (u16*)yb;  // attn partials / conv2 partials (bf16)
  u16* O1 = (u16*)p1;
  u16* O2 = (u16*)p2;
  u16* O3 = (u16*)p3;

  const int ntot = (int)NBC;
  pack_all<<<dim3(6 * 7184), 256, 0, stream>>>(
      wq, wk, wv, wo, bq, bk, bv, bo, erk, erv, fw1, fw2, qwAll, pbAll, ekAll,
      evAll, w1All, w2All);
  tpack<<<dim3(16, 4, 4), 256, 0, stream>>>(x, xm, xb, xpH, Cz);

  for (int l = 0; l < Lz; l++) {
    qkv_gemm<<<dim3(16, 12, 4), 256, 0, stream>>>(
        qwAll + (size_t)l * 262144, xpH, pbAll + l * 1024, Qh, Kh, Vh, 1024,
        Cz);
    attn_mfma<<<dim3(1024), 128, 0, stream>>>(
        Qh, Kh, Vh, xm, ekAll + l * 2048, evAll + l * 2048, O0, O1, O2, O3,
        lb0, lb1, lb2, lb3);
    // wo GEMM with fused combine (bf16 partials in/out): Q/K/V dead.
    wo_gemm<<<dim3(16, 8, 4), 256, 0, stream>>>(
        qwAll + (size_t)l * 262144, pbAll + l * 1024, wo0, wo1, O0, O1, O2,
        O3, lb0, lb1, lb2, lb3, 1024, Cz, 768);
    fused_ln<2, 2><<<dim3(128, 4), 256, 0, stream>>>(
        xb, wo0, wo1, nullptr, nullptr, bo + l * Cz, g1 + l * Cz, b1 + l * Cz,
        xm, xpH);
    conv_mfma<1><<<dim3(8, 16, 4), 256, 0, stream>>>(
        w1All + (size_t)l * 786432, xpH, fb1 + l * FCz, xm, hpH, nullptr,
        nullptr, nullptr, nullptr, FCz, Cz);
    conv_mfma<3><<<dim3(8, 16, 4), 256, 0, stream>>>(
        w2All + (size_t)l * 786432, hpH, nullptr, xm, nullptr, O0, O1, O2,
        O3, Cz, FCz);
    fused_ln<1, 4><<<dim3(128, 4), 256, 0, stream>>>(
        xb, O0, O1, O2, O3, fb2 + l * Cz, g2 + l * Cz, b2 + l * Cz, xm, xpH);
  }
  mask_out<<<dim3((ntot + 255) / 256), 256, 0, stream>>>(xb, xm,
                                                         (float*)d_out);
}